// Round 4
// baseline (334.325 us; speedup 1.0000x reference)
//
#include <hip/hip_runtime.h>

using u16 = unsigned short;
using u32 = unsigned int;

#define B_   2
#define N_   2048
#define DIM_ 1024
#define H_   16
#define D_   64
#define ROWS_ (B_*N_)   // 4096
#define E3_  3072       // q|k|v concatenated

typedef __attribute__((ext_vector_type(8))) short short8;
typedef __attribute__((ext_vector_type(4))) float f32x4;

__device__ __forceinline__ u16 f2bf(float f) {
  u32 u = __builtin_bit_cast(u32, f);
  u32 r = (u + 0x7FFFu + ((u >> 16) & 1u)) >> 16;
  return (u16)r;
}
__device__ __forceinline__ float bf2f(u16 h) {
  u32 u = ((u32)h) << 16;
  return __builtin_bit_cast(float, u);
}
__device__ __forceinline__ short8 ld8(const u16* p) { return *(const short8*)p; }
__device__ __forceinline__ f32x4 mfma16(short8 a, short8 b, f32x4 c) {
  return __builtin_amdgcn_mfma_f32_16x16x32_bf16(a, b, c, 0, 0, 0);
}
__device__ __forceinline__ void lds16(const u16* g, u16* l) {
  __builtin_amdgcn_global_load_lds(
      (const __attribute__((address_space(1))) void*)g,
      (__attribute__((address_space(3))) void*)l, 16, 0, 0);
}

// ---------------- LayerNorm: x fp32 [4096][1024] -> xn bf16 ----------------
__global__ __launch_bounds__(256) void k_layernorm(const float* __restrict__ x,
                                                   const float* __restrict__ gamma,
                                                   u16* __restrict__ xn) {
  int row = blockIdx.x, tid = threadIdx.x;
  const float4 xv = *(const float4*)(x + (size_t)row * DIM_ + tid * 4);
  float s = xv.x + xv.y + xv.z + xv.w;
  float q = xv.x*xv.x + xv.y*xv.y + xv.z*xv.z + xv.w*xv.w;
  for (int off = 32; off; off >>= 1) { s += __shfl_xor(s, off); q += __shfl_xor(q, off); }
  __shared__ float red[8];
  int wave = tid >> 6, lane = tid & 63;
  if (lane == 0) { red[wave] = s; red[4 + wave] = q; }
  __syncthreads();
  s = red[0] + red[1] + red[2] + red[3];
  q = red[4] + red[5] + red[6] + red[7];
  float mu  = s * (1.0f / DIM_);
  float var = q * (1.0f / DIM_) - mu * mu;
  float inv = rsqrtf(var + 1e-5f);
  const float4 gv = *(const float4*)(gamma + tid * 4);
  ushort4 ov;
  ov.x = f2bf((xv.x - mu) * inv * gv.x);
  ov.y = f2bf((xv.y - mu) * inv * gv.y);
  ov.z = f2bf((xv.z - mu) * inv * gv.z);
  ov.w = f2bf((xv.w - mu) * inv * gv.w);
  *(ushort4*)(xn + (size_t)row * DIM_ + tid * 4) = ov;
}

// ------------- transpose+cast: in fp32 [1024][ncols] -> out bf16 [ncols][1024]
__global__ __launch_bounds__(256) void k_tcast(const float* __restrict__ in,
                                               u16* __restrict__ out, int ncols) {
  __shared__ float tile[32][33];
  int tx = threadIdx.x, ty = threadIdx.y;
  int col  = blockIdx.x * 32 + tx;   // ncols dim
  int row0 = blockIdx.y * 32;        // K dim
  for (int j = 0; j < 32; j += 8)
    tile[ty + j][tx] = in[(size_t)(row0 + ty + j) * ncols + col];
  __syncthreads();
  int orow = blockIdx.x * 32 + ty;
  int ocol = row0 + tx;
  for (int j = 0; j < 32; j += 8)
    out[(size_t)(orow + j) * DIM_ + ocol] = f2bf(tile[tx][ty + j]);
}

// ------------- mask decode with dtype auto-detect -> additive bias ---------
__global__ void k_mask(const int* __restrict__ mraw, float* __restrict__ bias) {
  __shared__ int flag;
  int tid = threadIdx.x;
  if (tid == 0) flag = 0;
  __syncthreads();
  int v = mraw[tid];                 // 1024 ints: safe under bool(4096B) or int32(16384B)
  if (v != 0 && v != 1) atomicOr(&flag, 1);
  __syncthreads();
  bool bytemode = (flag != 0);
  const unsigned char* mb = (const unsigned char*)mraw;
  for (int j = tid; j < B_ * N_; j += 1024) {
    bool valid = bytemode ? (mb[j] != 0) : (mraw[j] != 0);
    bias[j] = valid ? 0.0f : -1e30f;
  }
}

// ------------- GEMM C = A @ Bt^T : A[M][K] bf16, Bt[N][K] bf16 -------------
template <bool OUT_BF16>
__global__ __launch_bounds__(256) void k_gemm_bt(const u16* __restrict__ A,
                                                 const u16* __restrict__ Bt,
                                                 void* __restrict__ Cv,
                                                 int M, int Ncols, int K) {
  __shared__ u16 As[128 * 32];
  __shared__ u16 Bs[128 * 32];
  const int tid = threadIdx.x;
  const int wave = tid >> 6, lane = tid & 63;
  const int g = lane >> 4, li = lane & 15;
  const int tm = blockIdx.x * 128, tn = blockIdx.y * 128;
  const int wm = (wave >> 1) * 64, wn = (wave & 1) * 64;
  const int srow = wave * 16 + (lane >> 2);
  const int scol = (lane & 3) * 8;

  f32x4 acc[4][4];
#pragma unroll
  for (int i = 0; i < 4; ++i)
#pragma unroll
    for (int j = 0; j < 4; ++j) acc[i][j] = (f32x4){0.f, 0.f, 0.f, 0.f};

  const u16* ag = A  + (size_t)(tm + srow) * K + scol;
  const u16* bg = Bt + (size_t)(tn + srow) * K + scol;

  for (int k0 = 0; k0 < K; k0 += 32) {
    __syncthreads();                           // previous reads done
#pragma unroll
    for (int p = 0; p < 2; ++p) {
      lds16(ag + (size_t)p * 64 * K + k0, As + p * 2048 + wave * 512);
      lds16(bg + (size_t)p * 64 * K + k0, Bs + p * 2048 + wave * 512);
    }
    __syncthreads();                           // drains vmcnt, staging visible
    short8 af[4], bfm[4];
#pragma unroll
    for (int m = 0; m < 4; ++m) af[m]  = ld8(As + (wm + m * 16 + li) * 32 + g * 8);
#pragma unroll
    for (int n = 0; n < 4; ++n) bfm[n] = ld8(Bs + (wn + n * 16 + li) * 32 + g * 8);
#pragma unroll
    for (int m = 0; m < 4; ++m)
#pragma unroll
      for (int n = 0; n < 4; ++n)
        acc[m][n] = mfma16(af[m], bfm[n], acc[m][n]);
  }
#pragma unroll
  for (int m = 0; m < 4; ++m)
#pragma unroll
    for (int n = 0; n < 4; ++n) {
      int row = tm + wm + m * 16 + g * 4;
      int col = tn + wn + n * 16 + li;
#pragma unroll
      for (int r = 0; r < 4; ++r) {
        float v = acc[m][n][r];
        if (OUT_BF16) ((u16*)Cv)[(size_t)(row + r) * Ncols + col] = f2bf(v);
        else          ((float*)Cv)[(size_t)(row + r) * Ncols + col] = v;
      }
    }
}

// ------------- RMS qk-norm: Cq bf16 [4096][3072] -> q,k bf16 [b,h,n,d] -----
__global__ __launch_bounds__(256) void k_rms_qk(const u16* __restrict__ Cq,
                                                const float* __restrict__ gq,
                                                const float* __restrict__ gk,
                                                u16* __restrict__ qo,
                                                u16* __restrict__ ko) {
  int gid  = blockIdx.x * 4 + (threadIdx.x >> 6);   // 0..131071
  int lane = threadIdx.x & 63;
  int hh  = gid & 31;           // 0-15: q heads, 16-31: k heads
  int row = gid >> 5;           // 0..4095
  int b = row >> 11, n = row & 2047;
  bool isq = hh < 16;
  int h = hh & 15;
  int col = (isq ? 0 : 1024) + h * 64 + lane;
  float v = bf2f(Cq[(size_t)row * E3_ + col]);
  float ss = v * v;
  for (int off = 32; off; off >>= 1) ss += __shfl_xor(ss, off);
  float nrm = sqrtf(ss);
  float scale = 8.0f / fmaxf(nrm, 1e-12f);   // sqrt(64)=8
  const float* gam = isq ? gq : gk;
  float outv = v * scale * gam[h * 64 + lane];
  u16* dst = isq ? qo : ko;
  dst[(((size_t)(b * H_ + h)) * N_ + n) * 64 + lane] = f2bf(outv);
}

// ------------- V relayout: Cq[.,2048+h*64+d] -> vT [b*h][d][n] -------------
__global__ __launch_bounds__(256) void k_vt(const u16* __restrict__ Cq,
                                            u16* __restrict__ vT) {
  __shared__ float tile[64][65];
  int bh = blockIdx.y;
  int b = bh >> 4, h = bh & 15;
  int n0 = blockIdx.x * 64;
  int tx = threadIdx.x, ty = threadIdx.y;
  for (int i = 0; i < 64; i += 4) {
    int n = n0 + ty + i;
    tile[ty + i][tx] = bf2f(Cq[((size_t)(b * N_ + n)) * E3_ + 2048 + h * 64 + tx]);
  }
  __syncthreads();
  u16* dst = vT + (size_t)bh * 64 * N_;
  for (int i = 0; i < 64; i += 4) {
    int d = ty + i;
    dst[(size_t)d * N_ + n0 + tx] = f2bf(tile[tx][d]);
  }
}

// ---- one k-tile body: issue cur-V + next-K loads, fence, QK^T, softmax, PV.
__device__ __forceinline__ void attn_body(
    const u16* __restrict__ Kh, const u16* __restrict__ Vh,
    const float* __restrict__ bias_s, int kb_cur, int kb_nxt,
    int li, int g, int lo2, int hi2,
    short8 (&ck)[4][2], short8 (&nk)[4][2], short8 (&vf)[4][2],
    short8 aq0, short8 aq1, f32x4 (&oT)[4], float& m, float& l) {
  // issue current-tile V loads (consumed after softmax -> latency hidden)
#pragma unroll
  for (int dc = 0; dc < 4; ++dc) {
    const u16* vp = Vh + (size_t)(dc * 16 + li) * N_ + kb_cur + g * 8;
    vf[dc][0] = ld8(vp);
    vf[dc][1] = ld8(vp + 32);
  }
  // issue next-tile K loads (consumed next body -> fully hidden)
#pragma unroll
  for (int c = 0; c < 4; ++c) {
    const u16* kp = Kh + (size_t)(kb_nxt + c * 16 + li) * 64 + g * 8;
    nk[c][0] = ld8(kp);
    nk[c][1] = ld8(kp + 32);
  }
  // scheduling fence: loads above may NOT sink below this point
  asm volatile("" ::: "memory");
  // ---- S^T[c] = mfma(K,Q): rows k_local=g*4+r, col q=li ----
  f32x4 st[4];
#pragma unroll
  for (int c = 0; c < 4; ++c) {
    f32x4 z = (f32x4){0.f, 0.f, 0.f, 0.f};
    z = mfma16(ck[c][0], aq0, z);
    st[c] = mfma16(ck[c][1], aq1, z);
  }
  // ---- bias + tile max (tree in-lane over 16 k, then 2 shfl) ----
  float pv[4][4], cm[4];
#pragma unroll
  for (int c = 0; c < 4; ++c) {
    float4 bb = *(const float4*)&bias_s[kb_cur + c * 16 + g * 4];
    pv[c][0] = st[c][0] + bb.x;
    pv[c][1] = st[c][1] + bb.y;
    pv[c][2] = st[c][2] + bb.z;
    pv[c][3] = st[c][3] + bb.w;
    cm[c] = fmaxf(fmaxf(pv[c][0], pv[c][1]), fmaxf(pv[c][2], pv[c][3]));
  }
  float tmax = fmaxf(fmaxf(cm[0], cm[1]), fmaxf(cm[2], cm[3]));
  tmax = fmaxf(tmax, __shfl_xor(tmax, 16));
  tmax = fmaxf(tmax, __shfl_xor(tmax, 32));
  float mn = fmaxf(m, tmax);
  float sc = __expf(m - mn);
  m = mn;
  float cs[4];
#pragma unroll
  for (int c = 0; c < 4; ++c) {
#pragma unroll
    for (int r = 0; r < 4; ++r) pv[c][r] = __expf(pv[c][r] - mn);
    cs[c] = (pv[c][0] + pv[c][1]) + (pv[c][2] + pv[c][3]);
  }
  float rs = (cs[0] + cs[1]) + (cs[2] + cs[3]);
  rs += __shfl_xor(rs, 16);
  rs += __shfl_xor(rs, 32);
  l = l * sc + rs;
#pragma unroll
  for (int dc = 0; dc < 4; ++dc) oT[dc] *= sc;            // lane-scalar rescale
  // ---- pack P to bf16 pairs: w[c][rp] = P[li][c*16+g*4+2rp, +2rp+1] ----
  u32 w[4][2];
#pragma unroll
  for (int c = 0; c < 4; ++c)
#pragma unroll
    for (int rp = 0; rp < 2; ++rp)
      w[c][rp] = (u32)f2bf(pv[c][2 * rp]) | ((u32)f2bf(pv[c][2 * rp + 1]) << 16);
  // ---- lane exchange: build B-frags W[kh][t] = P[li][kh*32+g*8+2t,+2t+1] --
  u32 W[2][4];
#pragma unroll
  for (int kh = 0; kh < 2; ++kh)
#pragma unroll
    for (int rp = 0; rp < 2; ++rp) {
      u32 f[2], s2[2];
#pragma unroll
      for (int cc = 0; cc < 2; ++cc) {
        u32 x = w[kh * 2 + cc][rp];
        u32 y = __shfl_xor(x, 16);   // lane g^1
        u32 u = __shfl_xor(x, 32);   // lane g^2
        u32 v = __shfl_xor(y, 32);   // lane g^3
        f[cc]  = lo2 ? (hi2 ? y : v) : (hi2 ? u : x);
        s2[cc] = lo2 ? (hi2 ? x : u) : (hi2 ? v : y);
      }
      W[kh][rp]     = hi2 ? f[1]  : f[0];
      W[kh][rp + 2] = hi2 ? s2[1] : s2[0];
    }
  union { u32 u4[4]; short8 s8; } cv0, cv1;
#pragma unroll
  for (int t = 0; t < 4; ++t) { cv0.u4[t] = W[0][t]; cv1.u4[t] = W[1][t]; }
  // ---- PV: O^T += V^T @ P^T (V waits are counted vmcnt, mostly complete) --
#pragma unroll
  for (int dc = 0; dc < 4; ++dc) {
    oT[dc] = mfma16(vf[dc][0], cv0.s8, oT[dc]);
    oT[dc] = mfma16(vf[dc][1], cv1.s8, oT[dc]);
  }
}

// ------------- flash attention (XCD-swizzled, double-buffered K) -----------
// 1D grid of 1024 blocks. Swizzle: xcd = wg&7 -> bh in {4*xcd..4*xcd+3} so
// each XCD's L2 holds only 4 heads' K/V (2 MB < 4 MB). K fragments are
// double-buffered across k-tiles (prefetch next while computing current);
// V issued at body start, consumed after softmax.
__global__ __launch_bounds__(256, 2) void k_attn(const u16* __restrict__ Q,
                                                 const u16* __restrict__ K,
                                                 const u16* __restrict__ Vt,
                                                 const float* __restrict__ bias,
                                                 u16* __restrict__ Out) {
  __shared__ float bias_s[N_];          // 8 KB
  int wg = blockIdx.x;
  int xcd = wg & 7, slot = wg >> 3;
  int bh = xcd * 4 + (slot & 3);        // bijective: 8 xcd x 4 bh x 32 qb
  int qb = (slot >> 2) * 64;
  int b = bh >> 4, h = bh & 15;
  int tid = threadIdx.x, wave = tid >> 6, lane = tid & 63;
  int g = lane >> 4, li = lane & 15;
  int lo2 = g & 1, hi2 = g >> 1;
  const u16* Qh = Q  + (size_t)bh * N_ * 64;
  const u16* Kh = K  + (size_t)bh * N_ * 64;
  const u16* Vh = Vt + (size_t)bh * 64 * N_;

  for (int j = tid; j < N_; j += 256) bias_s[j] = bias[b * N_ + j];
  __syncthreads();

  int qr = qb + wave * 16 + li;
  short8 aq0 = ld8(Qh + (size_t)qr * 64 + g * 8);        // B-frag: Q[q=li][d g*8..]
  short8 aq1 = ld8(Qh + (size_t)qr * 64 + 32 + g * 8);

  f32x4 oT[4];                                            // O^T[d=dc*16+g*4+r][q=li]
#pragma unroll
  for (int dc = 0; dc < 4; ++dc) oT[dc] = (f32x4){0.f, 0.f, 0.f, 0.f};
  float m = -3e38f, l = 0.f;

  short8 k0[4][2], k1[4][2], vf[4][2];
  // prologue: issue K loads for tile 0
#pragma unroll
  for (int c = 0; c < 4; ++c) {
    const u16* kp = Kh + (size_t)(c * 16 + li) * 64 + g * 8;
    k0[c][0] = ld8(kp);
    k0[c][1] = ld8(kp + 32);
  }
  asm volatile("" ::: "memory");

  for (int kt = 0; kt < 32; kt += 2) {
    attn_body(Kh, Vh, bias_s, kt * 64,       kt * 64 + 64,  li, g, lo2, hi2,
              k0, k1, vf, aq0, aq1, oT, m, l);
    attn_body(Kh, Vh, bias_s, kt * 64 + 64,  kt * 64 + 128, li, g, lo2, hi2,
              k1, k0, vf, aq0, aq1, oT, m, l);   // last nxt over-reads 8KB: in-ws
  }

  float inv = 1.0f / l;
#pragma unroll
  for (int dc = 0; dc < 4; ++dc) {
    ushort4 ov;
    ov.x = f2bf(oT[dc][0] * inv);
    ov.y = f2bf(oT[dc][1] * inv);
    ov.z = f2bf(oT[dc][2] * inv);
    ov.w = f2bf(oT[dc][3] * inv);
    *(ushort4*)&Out[((size_t)(b * N_ + qr)) * DIM_ + h * 64 + dc * 16 + g * 4] = ov;
  }
}

// ---------------------------------------------------------------------------
extern "C" void kernel_launch(void* const* d_in, const int* in_sizes, int n_in,
                              void* d_out, int out_size, void* d_ws, size_t ws_size,
                              hipStream_t stream) {
  const float* x    = (const float*)d_in[0];
  const int*   mask = (const int*)d_in[1];
  const float* g_ln = (const float*)d_in[2];
  const float* g_q  = (const float*)d_in[3];
  const float* g_k  = (const float*)d_in[4];
  const float* Wq   = (const float*)d_in[5];
  const float* Wkv  = (const float*)d_in[6];
  const float* Wo   = (const float*)d_in[7];
  float* out = (float*)d_out;

  char* ws = (char*)d_ws;
  u16*   xn   = (u16*)(ws);                         // 8 MB
  u16*   Wt   = (u16*)(ws + 8388608);               // 6 MB  (Wq^T | Wkv^T) [3072][1024]
  u16*   Wot  = (u16*)(ws + 14680064);              // 2 MB  Wo^T [1024][1024]
  float* bias = (float*)(ws + 16777216);            // 16 KB
  u16*   Cq   = (u16*)(ws + 16793600);              // 24 MB [4096][3072]
  u16*   qb   = (u16*)(ws + 41959424);              // 8 MB [b,h,n,d]
  u16*   kb   = (u16*)(ws + 41959424 + 8388608);    // 8 MB
  u16*   vT   = (u16*)(ws + 41959424 + 2*8388608);  // 8 MB [b*h][d][n]
  u16*   ao   = (u16*)(ws + 41959424 + 3*8388608);  // 8 MB [4096][1024]

  k_layernorm<<<ROWS_, 256, 0, stream>>>(x, g_ln, xn);
  dim3 tcb(32, 8);
  k_tcast<<<dim3(32, 32), tcb, 0, stream>>>(Wq,  Wt,               1024);
  k_tcast<<<dim3(64, 32), tcb, 0, stream>>>(Wkv, Wt + 1024 * 1024, 2048);
  k_tcast<<<dim3(32, 32), tcb, 0, stream>>>(Wo,  Wot,              1024);
  k_mask<<<1, 1024, 0, stream>>>(mask, bias);
  k_gemm_bt<true><<<dim3(32, 24), 256, 0, stream>>>(xn, Wt, Cq, ROWS_, E3_, DIM_);
  k_rms_qk<<<32768, 256, 0, stream>>>(Cq, g_q, g_k, qb, kb);
  k_vt<<<dim3(32, 32), dim3(64, 4), 0, stream>>>(Cq, vT);
  k_attn<<<1024, 256, 0, stream>>>(qb, kb, vT, bias, ao);
  k_gemm_bt<false><<<dim3(32, 8), 256, 0, stream>>>(ao, Wot, out, ROWS_, DIM_, DIM_);
}

// Round 6
// 197.505 us; speedup vs baseline: 1.6927x; 1.6927x over previous
//
#include <hip/hip_runtime.h>

using u16 = unsigned short;
using u32 = unsigned int;

#define B_   2
#define N_   2048
#define DIM_ 1024
#define H_   16
#define D_   64
#define ROWS_ (B_*N_)   // 4096
#define E3_  3072       // q|k|v concatenated

typedef __attribute__((ext_vector_type(8))) short short8;
typedef __attribute__((ext_vector_type(4))) float f32x4;

__device__ __forceinline__ u16 f2bf(float f) {
  u32 u = __builtin_bit_cast(u32, f);
  u32 r = (u + 0x7FFFu + ((u >> 16) & 1u)) >> 16;
  return (u16)r;
}
__device__ __forceinline__ float bf2f(u16 h) {
  u32 u = ((u32)h) << 16;
  return __builtin_bit_cast(float, u);
}
__device__ __forceinline__ short8 ld8(const u16* p) { return *(const short8*)p; }
__device__ __forceinline__ f32x4 mfma16(short8 a, short8 b, f32x4 c) {
  return __builtin_amdgcn_mfma_f32_16x16x32_bf16(a, b, c, 0, 0, 0);
}
__device__ __forceinline__ void lds16(const u16* g, u16* l) {
  __builtin_amdgcn_global_load_lds(
      (const __attribute__((address_space(1))) void*)g,
      (__attribute__((address_space(3))) void*)l, 16, 0, 0);
}
// byte-level XOR swizzle: flips bits 4-6 (16B chunk idx) by row&7; involution.
__device__ __forceinline__ u32 swzb(u32 L) { return L ^ (((L >> 7) & 7) << 4); }

// ---------------- LayerNorm: x fp32 [4096][1024] -> xn bf16 ----------------
__global__ __launch_bounds__(256) void k_layernorm(const float* __restrict__ x,
                                                   const float* __restrict__ gamma,
                                                   u16* __restrict__ xn) {
  int row = blockIdx.x, tid = threadIdx.x;
  const float4 xv = *(const float4*)(x + (size_t)row * DIM_ + tid * 4);
  float s = xv.x + xv.y + xv.z + xv.w;
  float q = xv.x*xv.x + xv.y*xv.y + xv.z*xv.z + xv.w*xv.w;
  for (int off = 32; off; off >>= 1) { s += __shfl_xor(s, off); q += __shfl_xor(q, off); }
  __shared__ float red[8];
  int wave = tid >> 6, lane = tid & 63;
  if (lane == 0) { red[wave] = s; red[4 + wave] = q; }
  __syncthreads();
  s = red[0] + red[1] + red[2] + red[3];
  q = red[4] + red[5] + red[6] + red[7];
  float mu  = s * (1.0f / DIM_);
  float var = q * (1.0f / DIM_) - mu * mu;
  float inv = rsqrtf(var + 1e-5f);
  const float4 gv = *(const float4*)(gamma + tid * 4);
  ushort4 ov;
  ov.x = f2bf((xv.x - mu) * inv * gv.x);
  ov.y = f2bf((xv.y - mu) * inv * gv.y);
  ov.z = f2bf((xv.z - mu) * inv * gv.z);
  ov.w = f2bf((xv.w - mu) * inv * gv.w);
  *(ushort4*)(xn + (size_t)row * DIM_ + tid * 4) = ov;
}

// ------------- transpose+cast: in fp32 [1024][ncols] -> out bf16 [ncols][1024]
__global__ __launch_bounds__(256) void k_tcast(const float* __restrict__ in,
                                               u16* __restrict__ out, int ncols) {
  __shared__ float tile[32][33];
  int tx = threadIdx.x, ty = threadIdx.y;
  int col  = blockIdx.x * 32 + tx;   // ncols dim
  int row0 = blockIdx.y * 32;        // K dim
  for (int j = 0; j < 32; j += 8)
    tile[ty + j][tx] = in[(size_t)(row0 + ty + j) * ncols + col];
  __syncthreads();
  int orow = blockIdx.x * 32 + ty;
  int ocol = row0 + tx;
  for (int j = 0; j < 32; j += 8)
    out[(size_t)(orow + j) * DIM_ + ocol] = f2bf(tile[tx][ty + j]);
}

// ------------- mask decode with dtype auto-detect -> additive bias ---------
__global__ void k_mask(const int* __restrict__ mraw, float* __restrict__ bias) {
  __shared__ int flag;
  int tid = threadIdx.x;
  if (tid == 0) flag = 0;
  __syncthreads();
  int v = mraw[tid];                 // 1024 ints: safe under bool(4096B) or int32(16384B)
  if (v != 0 && v != 1) atomicOr(&flag, 1);
  __syncthreads();
  bool bytemode = (flag != 0);
  const unsigned char* mb = (const unsigned char*)mraw;
  for (int j = tid; j < B_ * N_; j += 1024) {
    bool valid = bytemode ? (mb[j] != 0) : (mraw[j] != 0);
    bias[j] = valid ? 0.0f : -1e30f;
  }
}

// ------------- GEMM C = A @ Bt^T : A[M][K] bf16, Bt[N][K] bf16 -------------
template <bool OUT_BF16>
__global__ __launch_bounds__(256) void k_gemm_bt(const u16* __restrict__ A,
                                                 const u16* __restrict__ Bt,
                                                 void* __restrict__ Cv,
                                                 int M, int Ncols, int K) {
  __shared__ u16 As[128 * 32];
  __shared__ u16 Bs[128 * 32];
  const int tid = threadIdx.x;
  const int wave = tid >> 6, lane = tid & 63;
  const int g = lane >> 4, li = lane & 15;
  const int tm = blockIdx.x * 128, tn = blockIdx.y * 128;
  const int wm = (wave >> 1) * 64, wn = (wave & 1) * 64;
  const int srow = wave * 16 + (lane >> 2);
  const int scol = (lane & 3) * 8;

  f32x4 acc[4][4];
#pragma unroll
  for (int i = 0; i < 4; ++i)
#pragma unroll
    for (int j = 0; j < 4; ++j) acc[i][j] = (f32x4){0.f, 0.f, 0.f, 0.f};

  const u16* ag = A  + (size_t)(tm + srow) * K + scol;
  const u16* bg = Bt + (size_t)(tn + srow) * K + scol;

  for (int k0 = 0; k0 < K; k0 += 32) {
    __syncthreads();                           // previous reads done
#pragma unroll
    for (int p = 0; p < 2; ++p) {
      lds16(ag + (size_t)p * 64 * K + k0, As + p * 2048 + wave * 512);
      lds16(bg + (size_t)p * 64 * K + k0, Bs + p * 2048 + wave * 512);
    }
    __syncthreads();                           // drains vmcnt, staging visible
    short8 af[4], bfm[4];
#pragma unroll
    for (int m = 0; m < 4; ++m) af[m]  = ld8(As + (wm + m * 16 + li) * 32 + g * 8);
#pragma unroll
    for (int n = 0; n < 4; ++n) bfm[n] = ld8(Bs + (wn + n * 16 + li) * 32 + g * 8);
#pragma unroll
    for (int m = 0; m < 4; ++m)
#pragma unroll
      for (int n = 0; n < 4; ++n)
        acc[m][n] = mfma16(af[m], bfm[n], acc[m][n]);
  }
#pragma unroll
  for (int m = 0; m < 4; ++m)
#pragma unroll
    for (int n = 0; n < 4; ++n) {
      int row = tm + wm + m * 16 + g * 4;
      int col = tn + wn + n * 16 + li;
#pragma unroll
      for (int r = 0; r < 4; ++r) {
        float v = acc[m][n][r];
        if (OUT_BF16) ((u16*)Cv)[(size_t)(row + r) * Ncols + col] = f2bf(v);
        else          ((float*)Cv)[(size_t)(row + r) * Ncols + col] = v;
      }
    }
}

// ------------- RMS qk-norm: Cq bf16 [4096][3072] -> q,k bf16 [b,h,n,d] -----
__global__ __launch_bounds__(256) void k_rms_qk(const u16* __restrict__ Cq,
                                                const float* __restrict__ gq,
                                                const float* __restrict__ gk,
                                                u16* __restrict__ qo,
                                                u16* __restrict__ ko) {
  int gid  = blockIdx.x * 4 + (threadIdx.x >> 6);   // 0..131071
  int lane = threadIdx.x & 63;
  int hh  = gid & 31;           // 0-15: q heads, 16-31: k heads
  int row = gid >> 5;           // 0..4095
  int b = row >> 11, n = row & 2047;
  bool isq = hh < 16;
  int h = hh & 15;
  int col = (isq ? 0 : 1024) + h * 64 + lane;
  float v = bf2f(Cq[(size_t)row * E3_ + col]);
  float ss = v * v;
  for (int off = 32; off; off >>= 1) ss += __shfl_xor(ss, off);
  float nrm = sqrtf(ss);
  float scale = 8.0f / fmaxf(nrm, 1e-12f);   // sqrt(64)=8
  const float* gam = isq ? gq : gk;
  float outv = v * scale * gam[h * 64 + lane];
  u16* dst = isq ? qo : ko;
  dst[(((size_t)(b * H_ + h)) * N_ + n) * 64 + lane] = f2bf(outv);
}

// ------------- V relayout: Cq[.,2048+h*64+d] -> vT [b*h][d][n] -------------
__global__ __launch_bounds__(256) void k_vt(const u16* __restrict__ Cq,
                                            u16* __restrict__ vT) {
  __shared__ float tile[64][65];
  int bh = blockIdx.y;
  int b = bh >> 4, h = bh & 15;
  int n0 = blockIdx.x * 64;
  int tx = threadIdx.x, ty = threadIdx.y;
  for (int i = 0; i < 64; i += 4) {
    int n = n0 + ty + i;
    tile[ty + i][tx] = bf2f(Cq[((size_t)(b * N_ + n)) * E3_ + 2048 + h * 64 + tx]);
  }
  __syncthreads();
  u16* dst = vT + (size_t)bh * 64 * N_;
  for (int i = 0; i < 64; i += 4) {
    int d = ty + i;
    dst[(size_t)d * N_ + n0 + tx] = f2bf(tile[tx][d]);
  }
}

// ------------- flash attention: LDS-staged K/V, double-buffered ------------
// Per block: one (b,h), 64 q-rows, 4 waves x 16 q. K (8KB) and V^T (8KB)
// tiles staged via global_load_lds (async, no VGPRs, coalesced; global src
// pre-inverse-swizzled, LDS dest linear), double-buffered, one barrier per
// k-tile. Fragment reads use chunk^=(row&7) XOR swizzle. NOTE: orig chunk
// g+4 lives at swizzled chunk (g^(row&7))^4 -> second read is fsw^32 u16,
// NOT fsw+32 (R5's NaN bug: +32 walks out of the row for li&4).
__global__ __launch_bounds__(256, 3) void k_attn(const u16* __restrict__ Q,
                                                 const u16* __restrict__ K,
                                                 const u16* __restrict__ Vt,
                                                 const float* __restrict__ bias,
                                                 u16* __restrict__ Out) {
  __shared__ u16 Ks[2][4096];           // 16 KB: [buf][64 rows x 64 d] swizzled
  __shared__ u16 Vs[2][4096];           // 16 KB: [buf][64 d x 64 k] swizzled
  __shared__ float bias_s[N_];          // 8 KB
  int wg = blockIdx.x;
  int xcd = wg & 7, slot = wg >> 3;
  int bh = xcd * 4 + (slot & 3);        // bijective: 8 xcd x 4 bh x 32 qb
  int qb = (slot >> 2) * 64;
  int b = bh >> 4, h = bh & 15;
  int tid = threadIdx.x, wave = tid >> 6, lane = tid & 63;
  int g = lane >> 4, li = lane & 15;
  int lo2 = g & 1, hi2 = g >> 1;
  const u16* Qh = Q  + (size_t)bh * N_ * 64;
  const u16* Kh = K  + (size_t)bh * N_ * 64;
  const u16* Vh = Vt + (size_t)bh * 64 * N_;

  for (int j = tid; j < N_; j += 256) bias_s[j] = bias[b * N_ + j];

  // staging addresses for this thread (two 16B chunks per tile per buffer)
  const u32 L0 = tid * 16, L1 = tid * 16 + 4096;      // LDS byte offsets in tile
  const u32 kS0 = swzb(L0) >> 1, kS1 = swzb(L1) >> 1; // K src u16 offset in tile
  const u32 vR0 = L0 >> 7, vR1 = L1 >> 7;             // V src row (d index)
  const u32 vC0 = (swzb(L0) & 127) >> 1, vC1 = (swzb(L1) & 127) >> 1;

  int qr = qb + wave * 16 + li;
  short8 aq0 = ld8(Qh + (size_t)qr * 64 + g * 8);     // B-frag: Q[q=li][d g*8..]
  short8 aq1 = ld8(Qh + (size_t)qr * 64 + 32 + g * 8);

  f32x4 oT[4];                                        // O^T[d=dc*16+g*4+r][q=li]
#pragma unroll
  for (int dc = 0; dc < 4; ++dc) oT[dc] = (f32x4){0.f, 0.f, 0.f, 0.f};
  float m = -3e38f, l = 0.f;

  // swizzled fragment chunk offsets (u16): orig chunk g and g+4 of row li
  const int fsw  = 8 * (g ^ (li & 7));
  const int fsw2 = fsw ^ 32;

  // prologue: stage tile 0 into buffer 0
  lds16(Kh + kS0, &Ks[0][0] + (L0 >> 1));
  lds16(Kh + kS1, &Ks[0][0] + (L1 >> 1));
  lds16(Vh + (size_t)vR0 * N_ + vC0, &Vs[0][0] + (L0 >> 1));
  lds16(Vh + (size_t)vR1 * N_ + vC1, &Vs[0][0] + (L1 >> 1));
  __syncthreads();

  for (int kt = 0; kt < 32; ++kt) {
    int cur = kt & 1;
    int kbase = kt * 64;
    if (kt < 31) {                       // stage next tile (async, no regs)
      int nxt = cur ^ 1;
      int nb = kbase + 64;
      lds16(Kh + (size_t)nb * 64 + kS0, &Ks[nxt][0] + (L0 >> 1));
      lds16(Kh + (size_t)nb * 64 + kS1, &Ks[nxt][0] + (L1 >> 1));
      lds16(Vh + (size_t)vR0 * N_ + nb + vC0, &Vs[nxt][0] + (L0 >> 1));
      lds16(Vh + (size_t)vR1 * N_ + nb + vC1, &Vs[nxt][0] + (L1 >> 1));
    }
    const u16* Kb = &Ks[cur][0];
    const u16* Vb = &Vs[cur][0];
    // ---- S^T[c] = mfma(K,Q): K-frags from LDS (swizzled, conflict-free) --
    f32x4 st[4];
#pragma unroll
    for (int c = 0; c < 4; ++c) {
      int rb = (c * 16 + li) * 64;
      short8 kf0 = ld8(Kb + rb + fsw);
      short8 kf1 = ld8(Kb + rb + fsw2);
      f32x4 z = (f32x4){0.f, 0.f, 0.f, 0.f};
      z = mfma16(kf0, aq0, z);
      st[c] = mfma16(kf1, aq1, z);
    }
    // ---- V-frag reads issued now; consumed after softmax (lgkm-hidden) ---
    short8 vfr[4][2];
#pragma unroll
    for (int dc = 0; dc < 4; ++dc) {
      int rb = (dc * 16 + li) * 64;
      vfr[dc][0] = ld8(Vb + rb + fsw);
      vfr[dc][1] = ld8(Vb + rb + fsw2);
    }
    // ---- bias + tile max (tree in-lane over 16 k, then 2 shfl) ----------
    float pv[4][4], cm[4];
#pragma unroll
    for (int c = 0; c < 4; ++c) {
      float4 bb = *(const float4*)&bias_s[kbase + c * 16 + g * 4];
      pv[c][0] = st[c][0] + bb.x;
      pv[c][1] = st[c][1] + bb.y;
      pv[c][2] = st[c][2] + bb.z;
      pv[c][3] = st[c][3] + bb.w;
      cm[c] = fmaxf(fmaxf(pv[c][0], pv[c][1]), fmaxf(pv[c][2], pv[c][3]));
    }
    float tmax = fmaxf(fmaxf(cm[0], cm[1]), fmaxf(cm[2], cm[3]));
    tmax = fmaxf(tmax, __shfl_xor(tmax, 16));
    tmax = fmaxf(tmax, __shfl_xor(tmax, 32));
    float mn = fmaxf(m, tmax);
    float sc = __expf(m - mn);
    m = mn;
    float cs[4];
#pragma unroll
    for (int c = 0; c < 4; ++c) {
#pragma unroll
      for (int r = 0; r < 4; ++r) pv[c][r] = __expf(pv[c][r] - mn);
      cs[c] = (pv[c][0] + pv[c][1]) + (pv[c][2] + pv[c][3]);
    }
    float rs = (cs[0] + cs[1]) + (cs[2] + cs[3]);
    rs += __shfl_xor(rs, 16);
    rs += __shfl_xor(rs, 32);
    l = l * sc + rs;
#pragma unroll
    for (int dc = 0; dc < 4; ++dc) oT[dc] *= sc;      // lane-scalar rescale
    // ---- pack P to bf16 pairs: w[c][rp] = P[li][c*16+g*4+2rp, +2rp+1] ----
    u32 w[4][2];
#pragma unroll
    for (int c = 0; c < 4; ++c)
#pragma unroll
      for (int rp = 0; rp < 2; ++rp)
        w[c][rp] = (u32)f2bf(pv[c][2 * rp]) | ((u32)f2bf(pv[c][2 * rp + 1]) << 16);
    // ---- lane exchange: build B-frags W[kh][t] = P[li][kh*32+g*8+2t,+2t+1]
    u32 W[2][4];
#pragma unroll
    for (int kh = 0; kh < 2; ++kh)
#pragma unroll
      for (int rp = 0; rp < 2; ++rp) {
        u32 f[2], s2[2];
#pragma unroll
        for (int cc = 0; cc < 2; ++cc) {
          u32 x = w[kh * 2 + cc][rp];
          u32 y = __shfl_xor(x, 16);   // lane g^1
          u32 u = __shfl_xor(x, 32);   // lane g^2
          u32 v = __shfl_xor(y, 32);   // lane g^3
          f[cc]  = lo2 ? (hi2 ? y : v) : (hi2 ? u : x);
          s2[cc] = lo2 ? (hi2 ? x : u) : (hi2 ? v : y);
        }
        W[kh][rp]     = hi2 ? f[1]  : f[0];
        W[kh][rp + 2] = hi2 ? s2[1] : s2[0];
      }
    union { u32 u4[4]; short8 s8; } cv0, cv1;
#pragma unroll
    for (int t = 0; t < 4; ++t) { cv0.u4[t] = W[0][t]; cv1.u4[t] = W[1][t]; }
    // ---- PV: O^T += V^T @ P^T ------------------------------------------
#pragma unroll
    for (int dc = 0; dc < 4; ++dc) {
      oT[dc] = mfma16(vfr[dc][0], cv0.s8, oT[dc]);
      oT[dc] = mfma16(vfr[dc][1], cv1.s8, oT[dc]);
    }
    __syncthreads();                    // next-tile staging complete + buf free
  }

  float inv = 1.0f / l;
#pragma unroll
  for (int dc = 0; dc < 4; ++dc) {
    ushort4 ov;
    ov.x = f2bf(oT[dc][0] * inv);
    ov.y = f2bf(oT[dc][1] * inv);
    ov.z = f2bf(oT[dc][2] * inv);
    ov.w = f2bf(oT[dc][3] * inv);
    *(ushort4*)&Out[((size_t)(b * N_ + qr)) * DIM_ + h * 64 + dc * 16 + g * 4] = ov;
  }
}

// ---------------------------------------------------------------------------
extern "C" void kernel_launch(void* const* d_in, const int* in_sizes, int n_in,
                              void* d_out, int out_size, void* d_ws, size_t ws_size,
                              hipStream_t stream) {
  const float* x    = (const float*)d_in[0];
  const int*   mask = (const int*)d_in[1];
  const float* g_ln = (const float*)d_in[2];
  const float* g_q  = (const float*)d_in[3];
  const float* g_k  = (const float*)d_in[4];
  const float* Wq   = (const float*)d_in[5];
  const float* Wkv  = (const float*)d_in[6];
  const float* Wo   = (const float*)d_in[7];
  float* out = (float*)d_out;

  char* ws = (char*)d_ws;
  u16*   xn   = (u16*)(ws);                         // 8 MB
  u16*   Wt   = (u16*)(ws + 8388608);               // 6 MB  (Wq^T | Wkv^T) [3072][1024]
  u16*   Wot  = (u16*)(ws + 14680064);              // 2 MB  Wo^T [1024][1024]
  float* bias = (float*)(ws + 16777216);            // 16 KB
  u16*   Cq   = (u16*)(ws + 16793600);              // 24 MB [4096][3072]
  u16*   qb   = (u16*)(ws + 41959424);              // 8 MB [b,h,n,d]
  u16*   kb   = (u16*)(ws + 41959424 + 8388608);    // 8 MB
  u16*   vT   = (u16*)(ws + 41959424 + 2*8388608);  // 8 MB [b*h][d][n]
  u16*   ao   = (u16*)(ws + 41959424 + 3*8388608);  // 8 MB [4096][1024]

  k_layernorm<<<ROWS_, 256, 0, stream>>>(x, g_ln, xn);
  dim3 tcb(32, 8);
  k_tcast<<<dim3(32, 32), tcb, 0, stream>>>(Wq,  Wt,               1024);
  k_tcast<<<dim3(64, 32), tcb, 0, stream>>>(Wkv, Wt + 1024 * 1024, 2048);
  k_tcast<<<dim3(32, 32), tcb, 0, stream>>>(Wo,  Wot,              1024);
  k_mask<<<1, 1024, 0, stream>>>(mask, bias);
  k_gemm_bt<true><<<dim3(32, 24), 256, 0, stream>>>(xn, Wt, Cq, ROWS_, E3_, DIM_);
  k_rms_qk<<<32768, 256, 0, stream>>>(Cq, g_q, g_k, qb, kb);
  k_vt<<<dim3(32, 32), dim3(64, 4), 0, stream>>>(Cq, vT);
  k_attn<<<1024, 256, 0, stream>>>(qb, kb, vT, bias, ao);
  k_gemm_bt<false><<<dim3(32, 8), 256, 0, stream>>>(ao, Wot, out, ROWS_, DIM_, DIM_);
}

// Round 7
// 191.158 us; speedup vs baseline: 1.7489x; 1.0332x over previous
//
#include <hip/hip_runtime.h>

using u16 = unsigned short;
using u32 = unsigned int;

#define B_   2
#define N_   2048
#define DIM_ 1024
#define H_   16
#define D_   64
#define ROWS_ (B_*N_)   // 4096
#define E3_  3072       // q|k|v concatenated

typedef __attribute__((ext_vector_type(8))) short short8;
typedef __attribute__((ext_vector_type(4))) float f32x4;

__device__ __forceinline__ u16 f2bf(float f) {
  u32 u = __builtin_bit_cast(u32, f);
  u32 r = (u + 0x7FFFu + ((u >> 16) & 1u)) >> 16;
  return (u16)r;
}
__device__ __forceinline__ float bf2f(u16 h) {
  u32 u = ((u32)h) << 16;
  return __builtin_bit_cast(float, u);
}
__device__ __forceinline__ short8 ld8(const u16* p) { return *(const short8*)p; }
__device__ __forceinline__ f32x4 mfma16(short8 a, short8 b, f32x4 c) {
  return __builtin_amdgcn_mfma_f32_16x16x32_bf16(a, b, c, 0, 0, 0);
}
__device__ __forceinline__ void lds16(const u16* g, u16* l) {
  __builtin_amdgcn_global_load_lds(
      (const __attribute__((address_space(1))) void*)g,
      (__attribute__((address_space(3))) void*)l, 16, 0, 0);
}
// byte-level XOR swizzle: flips bits 4-6 (16B chunk idx) by row&7; involution.
__device__ __forceinline__ u32 swzb(u32 L) { return L ^ (((L >> 7) & 7) << 4); }

// ---------------- LayerNorm: x fp32 [4096][1024] -> xn bf16 ----------------
__global__ __launch_bounds__(256) void k_layernorm(const float* __restrict__ x,
                                                   const float* __restrict__ gamma,
                                                   u16* __restrict__ xn) {
  int row = blockIdx.x, tid = threadIdx.x;
  const float4 xv = *(const float4*)(x + (size_t)row * DIM_ + tid * 4);
  float s = xv.x + xv.y + xv.z + xv.w;
  float q = xv.x*xv.x + xv.y*xv.y + xv.z*xv.z + xv.w*xv.w;
  for (int off = 32; off; off >>= 1) { s += __shfl_xor(s, off); q += __shfl_xor(q, off); }
  __shared__ float red[8];
  int wave = tid >> 6, lane = tid & 63;
  if (lane == 0) { red[wave] = s; red[4 + wave] = q; }
  __syncthreads();
  s = red[0] + red[1] + red[2] + red[3];
  q = red[4] + red[5] + red[6] + red[7];
  float mu  = s * (1.0f / DIM_);
  float var = q * (1.0f / DIM_) - mu * mu;
  float inv = rsqrtf(var + 1e-5f);
  const float4 gv = *(const float4*)(gamma + tid * 4);
  ushort4 ov;
  ov.x = f2bf((xv.x - mu) * inv * gv.x);
  ov.y = f2bf((xv.y - mu) * inv * gv.y);
  ov.z = f2bf((xv.z - mu) * inv * gv.z);
  ov.w = f2bf((xv.w - mu) * inv * gv.w);
  *(ushort4*)(xn + (size_t)row * DIM_ + tid * 4) = ov;
}

// ------------- transpose+cast: in fp32 [1024][ncols] -> out bf16 [ncols][1024]
__global__ __launch_bounds__(256) void k_tcast(const float* __restrict__ in,
                                               u16* __restrict__ out, int ncols) {
  __shared__ float tile[32][33];
  int tx = threadIdx.x, ty = threadIdx.y;
  int col  = blockIdx.x * 32 + tx;   // ncols dim
  int row0 = blockIdx.y * 32;        // K dim
  for (int j = 0; j < 32; j += 8)
    tile[ty + j][tx] = in[(size_t)(row0 + ty + j) * ncols + col];
  __syncthreads();
  int orow = blockIdx.x * 32 + ty;
  int ocol = row0 + tx;
  for (int j = 0; j < 32; j += 8)
    out[(size_t)(orow + j) * DIM_ + ocol] = f2bf(tile[tx][ty + j]);
}

// ------------- mask decode with dtype auto-detect -> additive bias ---------
// 8 blocks: each recomputes the dtype flag (redundant, cheap) and writes
// its 512-entry slice of the 4096-entry bias.
__global__ void k_mask(const int* __restrict__ mraw, float* __restrict__ bias) {
  __shared__ int flag;
  int tid = threadIdx.x;
  if (tid == 0) flag = 0;
  __syncthreads();
  int v = mraw[tid];                 // 1024 ints: safe under bool(4096B) or int32(16384B)
  if (v != 0 && v != 1) atomicOr(&flag, 1);
  __syncthreads();
  bool bytemode = (flag != 0);
  const unsigned char* mb = (const unsigned char*)mraw;
  if (tid < 512) {
    int j = blockIdx.x * 512 + tid;
    bool valid = bytemode ? (mb[j] != 0) : (mraw[j] != 0);
    bias[j] = valid ? 0.0f : -1e30f;
  }
}

// ------------- GEMM C = A @ Bt^T : A[M][K] bf16, Bt[N][K] bf16 -------------
// NF = n-fragments per wave; tile = 128 x (NF*32). NF=4 -> 128x128 (QKV),
// NF=2 -> 128x64 (out-proj: 2x grid => 2 blocks/CU instead of 1).
// T1 XCD swizzle: grid must be % 8 == 0 (768 and 512 both are).
template <int NF, bool OUT_BF16>
__global__ __launch_bounds__(256) void k_gemm_bt(const u16* __restrict__ A,
                                                 const u16* __restrict__ Bt,
                                                 void* __restrict__ Cv,
                                                 int M, int Ncols, int K) {
  constexpr int BN = NF * 32;
  __shared__ u16 As[128 * 32];
  __shared__ u16 Bs[BN * 32];
  const int tid = threadIdx.x;
  const int wave = tid >> 6, lane = tid & 63;
  const int g = lane >> 4, li = lane & 15;
  // XCD-aware block swizzle: XCD x gets a contiguous chunk of tile-space
  const int gx = gridDim.x;
  const int wg = blockIdx.y * gx + blockIdx.x;
  const int per = (gx * gridDim.y) >> 3;
  const int swz = (wg & 7) * per + (wg >> 3);
  const int tm = (swz % gx) * 128, tn = (swz / gx) * BN;
  const int wm = (wave >> 1) * 64, wn = (wave & 1) * (NF * 16);
  const int srow = wave * 16 + (lane >> 2);
  const int scol = (lane & 3) * 8;

  f32x4 acc[4][NF];
#pragma unroll
  for (int i = 0; i < 4; ++i)
#pragma unroll
    for (int j = 0; j < NF; ++j) acc[i][j] = (f32x4){0.f, 0.f, 0.f, 0.f};

  const u16* ag = A  + (size_t)(tm + srow) * K + scol;
  const u16* bg = Bt + (size_t)(tn + srow) * K + scol;

  for (int k0 = 0; k0 < K; k0 += 32) {
    __syncthreads();                           // previous reads done
#pragma unroll
    for (int p = 0; p < 2; ++p)
      lds16(ag + (size_t)p * 64 * K + k0, As + p * 2048 + wave * 512);
#pragma unroll
    for (int p = 0; p < NF / 2; ++p)
      lds16(bg + (size_t)p * 64 * K + k0, Bs + p * 2048 + wave * 512);
    __syncthreads();                           // drains vmcnt, staging visible
    short8 af[4], bfm[NF];
#pragma unroll
    for (int m = 0; m < 4; ++m) af[m]  = ld8(As + (wm + m * 16 + li) * 32 + g * 8);
#pragma unroll
    for (int n = 0; n < NF; ++n) bfm[n] = ld8(Bs + (wn + n * 16 + li) * 32 + g * 8);
#pragma unroll
    for (int m = 0; m < 4; ++m)
#pragma unroll
      for (int n = 0; n < NF; ++n)
        acc[m][n] = mfma16(af[m], bfm[n], acc[m][n]);
  }
#pragma unroll
  for (int m = 0; m < 4; ++m)
#pragma unroll
    for (int n = 0; n < NF; ++n) {
      int row = tm + wm + m * 16 + g * 4;
      int col = tn + wn + n * 16 + li;
#pragma unroll
      for (int r = 0; r < 4; ++r) {
        float v = acc[m][n][r];
        if (OUT_BF16) ((u16*)Cv)[(size_t)(row + r) * Ncols + col] = f2bf(v);
        else          ((float*)Cv)[(size_t)(row + r) * Ncols + col] = v;
      }
    }
}

// ------------- RMS qk-norm: Cq bf16 [4096][3072] -> q,k bf16 [b,h,n,d] -----
__global__ __launch_bounds__(256) void k_rms_qk(const u16* __restrict__ Cq,
                                                const float* __restrict__ gq,
                                                const float* __restrict__ gk,
                                                u16* __restrict__ qo,
                                                u16* __restrict__ ko) {
  int gid  = blockIdx.x * 4 + (threadIdx.x >> 6);   // 0..131071
  int lane = threadIdx.x & 63;
  int hh  = gid & 31;           // 0-15: q heads, 16-31: k heads
  int row = gid >> 5;           // 0..4095
  int b = row >> 11, n = row & 2047;
  bool isq = hh < 16;
  int h = hh & 15;
  int col = (isq ? 0 : 1024) + h * 64 + lane;
  float v = bf2f(Cq[(size_t)row * E3_ + col]);
  float ss = v * v;
  for (int off = 32; off; off >>= 1) ss += __shfl_xor(ss, off);
  float nrm = sqrtf(ss);
  float scale = 8.0f / fmaxf(nrm, 1e-12f);   // sqrt(64)=8
  const float* gam = isq ? gq : gk;
  float outv = v * scale * gam[h * 64 + lane];
  u16* dst = isq ? qo : ko;
  dst[(((size_t)(b * H_ + h)) * N_ + n) * 64 + lane] = f2bf(outv);
}

// ------------- V relayout: Cq[.,2048+h*64+d] -> vT [b*h][d][n] -------------
__global__ __launch_bounds__(256) void k_vt(const u16* __restrict__ Cq,
                                            u16* __restrict__ vT) {
  __shared__ float tile[64][65];
  int bh = blockIdx.y;
  int b = bh >> 4, h = bh & 15;
  int n0 = blockIdx.x * 64;
  int tx = threadIdx.x, ty = threadIdx.y;
  for (int i = 0; i < 64; i += 4) {
    int n = n0 + ty + i;
    tile[ty + i][tx] = bf2f(Cq[((size_t)(b * N_ + n)) * E3_ + 2048 + h * 64 + tx]);
  }
  __syncthreads();
  u16* dst = vT + (size_t)bh * 64 * N_;
  for (int i = 0; i < 64; i += 4) {
    int d = ty + i;
    dst[(size_t)d * N_ + n0 + tx] = f2bf(tile[tx][d]);
  }
}

// ------------- flash attention: LDS-staged K/V, double-buffered ------------
// Per block: one (b,h), 64 q-rows, 4 waves x 16 q. K (8KB) and V^T (8KB)
// tiles staged via global_load_lds (async, no VGPRs, coalesced; global src
// pre-inverse-swizzled, LDS dest linear), double-buffered, one barrier per
// k-tile. Fragment reads use chunk^=(row&7) XOR swizzle; second chunk is
// fsw^32 (orig chunk g+4 -> swizzled (g^(row&7))^4). This round: P->bf16
// pack via v_cvt_pk_bf16_f32 (RTNE, bit-identical to f2bf; 64 VALU -> 8)
// and T5 setprio(1) around both MFMA clusters.
__global__ __launch_bounds__(256, 4) void k_attn(const u16* __restrict__ Q,
                                                 const u16* __restrict__ K,
                                                 const u16* __restrict__ Vt,
                                                 const float* __restrict__ bias,
                                                 u16* __restrict__ Out) {
  __shared__ u16 Ks[2][4096];           // 16 KB: [buf][64 rows x 64 d] swizzled
  __shared__ u16 Vs[2][4096];           // 16 KB: [buf][64 d x 64 k] swizzled
  __shared__ float bias_s[N_];          // 8 KB
  int wg = blockIdx.x;
  int xcd = wg & 7, slot = wg >> 3;
  int bh = xcd * 4 + (slot & 3);        // bijective: 8 xcd x 4 bh x 32 qb
  int qb = (slot >> 2) * 64;
  int b = bh >> 4, h = bh & 15;
  int tid = threadIdx.x, wave = tid >> 6, lane = tid & 63;
  int g = lane >> 4, li = lane & 15;
  int lo2 = g & 1, hi2 = g >> 1;
  const u16* Qh = Q  + (size_t)bh * N_ * 64;
  const u16* Kh = K  + (size_t)bh * N_ * 64;
  const u16* Vh = Vt + (size_t)bh * 64 * N_;

  for (int j = tid; j < N_; j += 256) bias_s[j] = bias[b * N_ + j];

  // staging addresses for this thread (two 16B chunks per tile per buffer)
  const u32 L0 = tid * 16, L1 = tid * 16 + 4096;      // LDS byte offsets in tile
  const u32 kS0 = swzb(L0) >> 1, kS1 = swzb(L1) >> 1; // K src u16 offset in tile
  const u32 vR0 = L0 >> 7, vR1 = L1 >> 7;             // V src row (d index)
  const u32 vC0 = (swzb(L0) & 127) >> 1, vC1 = (swzb(L1) & 127) >> 1;

  int qr = qb + wave * 16 + li;
  short8 aq0 = ld8(Qh + (size_t)qr * 64 + g * 8);     // B-frag: Q[q=li][d g*8..]
  short8 aq1 = ld8(Qh + (size_t)qr * 64 + 32 + g * 8);

  f32x4 oT[4];                                        // O^T[d=dc*16+g*4+r][q=li]
#pragma unroll
  for (int dc = 0; dc < 4; ++dc) oT[dc] = (f32x4){0.f, 0.f, 0.f, 0.f};
  float m = -3e38f, l = 0.f;

  // swizzled fragment chunk offsets (u16): orig chunk g and g+4 of row li
  const int fsw  = 8 * (g ^ (li & 7));
  const int fsw2 = fsw ^ 32;

  // prologue: stage tile 0 into buffer 0
  lds16(Kh + kS0, &Ks[0][0] + (L0 >> 1));
  lds16(Kh + kS1, &Ks[0][0] + (L1 >> 1));
  lds16(Vh + (size_t)vR0 * N_ + vC0, &Vs[0][0] + (L0 >> 1));
  lds16(Vh + (size_t)vR1 * N_ + vC1, &Vs[0][0] + (L1 >> 1));
  __syncthreads();

  for (int kt = 0; kt < 32; ++kt) {
    int cur = kt & 1;
    int kbase = kt * 64;
    if (kt < 31) {                       // stage next tile (async, no regs)
      int nxt = cur ^ 1;
      int nb = kbase + 64;
      lds16(Kh + (size_t)nb * 64 + kS0, &Ks[nxt][0] + (L0 >> 1));
      lds16(Kh + (size_t)nb * 64 + kS1, &Ks[nxt][0] + (L1 >> 1));
      lds16(Vh + (size_t)vR0 * N_ + nb + vC0, &Vs[nxt][0] + (L0 >> 1));
      lds16(Vh + (size_t)vR1 * N_ + nb + vC1, &Vs[nxt][0] + (L1 >> 1));
    }
    const u16* Kb = &Ks[cur][0];
    const u16* Vb = &Vs[cur][0];
    // ---- S^T[c] = mfma(K,Q): K-frags from LDS (swizzled, conflict-free) --
    f32x4 st[4];
    __builtin_amdgcn_s_setprio(1);
#pragma unroll
    for (int c = 0; c < 4; ++c) {
      int rb = (c * 16 + li) * 64;
      short8 kf0 = ld8(Kb + rb + fsw);
      short8 kf1 = ld8(Kb + rb + fsw2);
      f32x4 z = (f32x4){0.f, 0.f, 0.f, 0.f};
      z = mfma16(kf0, aq0, z);
      st[c] = mfma16(kf1, aq1, z);
    }
    __builtin_amdgcn_s_setprio(0);
    // ---- V-frag reads issued now; consumed after softmax (lgkm-hidden) ---
    short8 vfr[4][2];
#pragma unroll
    for (int dc = 0; dc < 4; ++dc) {
      int rb = (dc * 16 + li) * 64;
      vfr[dc][0] = ld8(Vb + rb + fsw);
      vfr[dc][1] = ld8(Vb + rb + fsw2);
    }
    // ---- bias + tile max (tree in-lane over 16 k, then 2 shfl) ----------
    float pv[4][4], cm[4];
#pragma unroll
    for (int c = 0; c < 4; ++c) {
      float4 bb = *(const float4*)&bias_s[kbase + c * 16 + g * 4];
      pv[c][0] = st[c][0] + bb.x;
      pv[c][1] = st[c][1] + bb.y;
      pv[c][2] = st[c][2] + bb.z;
      pv[c][3] = st[c][3] + bb.w;
      cm[c] = fmaxf(fmaxf(pv[c][0], pv[c][1]), fmaxf(pv[c][2], pv[c][3]));
    }
    float tmax = fmaxf(fmaxf(cm[0], cm[1]), fmaxf(cm[2], cm[3]));
    tmax = fmaxf(tmax, __shfl_xor(tmax, 16));
    tmax = fmaxf(tmax, __shfl_xor(tmax, 32));
    float mn = fmaxf(m, tmax);
    float sc = __expf(m - mn);
    m = mn;
    float cs[4];
#pragma unroll
    for (int c = 0; c < 4; ++c) {
#pragma unroll
      for (int r = 0; r < 4; ++r) pv[c][r] = __expf(pv[c][r] - mn);
      cs[c] = (pv[c][0] + pv[c][1]) + (pv[c][2] + pv[c][3]);
    }
    float rs = (cs[0] + cs[1]) + (cs[2] + cs[3]);
    rs += __shfl_xor(rs, 16);
    rs += __shfl_xor(rs, 32);
    l = l * sc + rs;
#pragma unroll
    for (int dc = 0; dc < 4; ++dc) oT[dc] *= sc;      // lane-scalar rescale
    // ---- pack P to bf16 pairs via v_cvt_pk_bf16_f32 (RTNE == f2bf) ------
    // w[c][rp] = {lo: bf16(pv[c][2rp]), hi: bf16(pv[c][2rp+1])}
    u32 w[4][2];
#pragma unroll
    for (int c = 0; c < 4; ++c) {
      asm("v_cvt_pk_bf16_f32 %0, %1, %2" : "=v"(w[c][0]) : "v"(pv[c][0]), "v"(pv[c][1]));
      asm("v_cvt_pk_bf16_f32 %0, %1, %2" : "=v"(w[c][1]) : "v"(pv[c][2]), "v"(pv[c][3]));
    }
    // ---- lane exchange: build B-frags W[kh][t] = P[li][kh*32+g*8+2t,+2t+1]
    u32 W[2][4];
#pragma unroll
    for (int kh = 0; kh < 2; ++kh)
#pragma unroll
      for (int rp = 0; rp < 2; ++rp) {
        u32 f[2], s2[2];
#pragma unroll
        for (int cc = 0; cc < 2; ++cc) {
          u32 x = w[kh * 2 + cc][rp];
          u32 y = __shfl_xor(x, 16);   // lane g^1
          u32 u = __shfl_xor(x, 32);   // lane g^2
          u32 v = __shfl_xor(y, 32);   // lane g^3
          f[cc]  = lo2 ? (hi2 ? y : v) : (hi2 ? u : x);
          s2[cc] = lo2 ? (hi2 ? x : u) : (hi2 ? v : y);
        }
        W[kh][rp]     = hi2 ? f[1]  : f[0];
        W[kh][rp + 2] = hi2 ? s2[1] : s2[0];
      }
    union { u32 u4[4]; short8 s8; } cv0, cv1;
#pragma unroll
    for (int t = 0; t < 4; ++t) { cv0.u4[t] = W[0][t]; cv1.u4[t] = W[1][t]; }
    // ---- PV: O^T += V^T @ P^T ------------------------------------------
    __builtin_amdgcn_s_setprio(1);
#pragma unroll
    for (int dc = 0; dc < 4; ++dc) {
      oT[dc] = mfma16(vfr[dc][0], cv0.s8, oT[dc]);
      oT[dc] = mfma16(vfr[dc][1], cv1.s8, oT[dc]);
    }
    __builtin_amdgcn_s_setprio(0);
    __syncthreads();                    // next-tile staging complete + buf free
  }

  float inv = 1.0f / l;
#pragma unroll
  for (int dc = 0; dc < 4; ++dc) {
    ushort4 ov;
    ov.x = f2bf(oT[dc][0] * inv);
    ov.y = f2bf(oT[dc][1] * inv);
    ov.z = f2bf(oT[dc][2] * inv);
    ov.w = f2bf(oT[dc][3] * inv);
    *(ushort4*)&Out[((size_t)(b * N_ + qr)) * DIM_ + h * 64 + dc * 16 + g * 4] = ov;
  }
}

// ---------------------------------------------------------------------------
extern "C" void kernel_launch(void* const* d_in, const int* in_sizes, int n_in,
                              void* d_out, int out_size, void* d_ws, size_t ws_size,
                              hipStream_t stream) {
  const float* x    = (const float*)d_in[0];
  const int*   mask = (const int*)d_in[1];
  const float* g_ln = (const float*)d_in[2];
  const float* g_q  = (const float*)d_in[3];
  const float* g_k  = (const float*)d_in[4];
  const float* Wq   = (const float*)d_in[5];
  const float* Wkv  = (const float*)d_in[6];
  const float* Wo   = (const float*)d_in[7];
  float* out = (float*)d_out;

  char* ws = (char*)d_ws;
  u16*   xn   = (u16*)(ws);                         // 8 MB
  u16*   Wt   = (u16*)(ws + 8388608);               // 6 MB  (Wq^T | Wkv^T) [3072][1024]
  u16*   Wot  = (u16*)(ws + 14680064);              // 2 MB  Wo^T [1024][1024]
  float* bias = (float*)(ws + 16777216);            // 16 KB
  u16*   Cq   = (u16*)(ws + 16793600);              // 24 MB [4096][3072]
  u16*   qb   = (u16*)(ws + 41959424);              // 8 MB [b,h,n,d]
  u16*   kb   = (u16*)(ws + 41959424 + 8388608);    // 8 MB
  u16*   vT   = (u16*)(ws + 41959424 + 2*8388608);  // 8 MB [b*h][d][n]
  u16*   ao   = (u16*)(ws + 41959424 + 3*8388608);  // 8 MB [4096][1024]

  k_layernorm<<<ROWS_, 256, 0, stream>>>(x, g_ln, xn);
  dim3 tcb(32, 8);
  k_tcast<<<dim3(32, 32), tcb, 0, stream>>>(Wq,  Wt,               1024);
  k_tcast<<<dim3(64, 32), tcb, 0, stream>>>(Wkv, Wt + 1024 * 1024, 2048);
  k_tcast<<<dim3(32, 32), tcb, 0, stream>>>(Wo,  Wot,              1024);
  k_mask<<<8, 1024, 0, stream>>>(mask, bias);
  k_gemm_bt<4, true><<<dim3(32, 24), 256, 0, stream>>>(xn, Wt, Cq, ROWS_, E3_, DIM_);
  k_rms_qk<<<32768, 256, 0, stream>>>(Cq, g_q, g_k, qb, kb);
  k_vt<<<dim3(32, 32), dim3(64, 4), 0, stream>>>(Cq, vT);
  k_attn<<<1024, 256, 0, stream>>>(qb, kb, vT, bias, ao);
  k_gemm_bt<2, false><<<dim3(32, 16), 256, 0, stream>>>(ao, Wot, out, ROWS_, DIM_, DIM_);
}

// Round 9
// 161.106 us; speedup vs baseline: 2.0752x; 1.1865x over previous
//
#include <hip/hip_runtime.h>

using u16 = unsigned short;
using u32 = unsigned int;

#define B_   2
#define N_   2048
#define DIM_ 1024
#define H_   16
#define D_   64
#define ROWS_ (B_*N_)   // 4096
#define E3_  3072       // q|k|v concatenated

typedef __attribute__((ext_vector_type(8))) short short8;
typedef __attribute__((ext_vector_type(4))) short short4v;
typedef __attribute__((ext_vector_type(4))) float f32x4;

__device__ __forceinline__ u16 f2bf(float f) {
  u32 u = __builtin_bit_cast(u32, f);
  u32 r = (u + 0x7FFFu + ((u >> 16) & 1u)) >> 16;
  return (u16)r;
}
__device__ __forceinline__ float bf2f(u16 h) {
  u32 u = ((u32)h) << 16;
  return __builtin_bit_cast(float, u);
}
__device__ __forceinline__ short8 ld8(const u16* p) { return *(const short8*)p; }
__device__ __forceinline__ f32x4 mfma16(short8 a, short8 b, f32x4 c) {
  return __builtin_amdgcn_mfma_f32_16x16x32_bf16(a, b, c, 0, 0, 0);
}
// K=16 bf16 MFMA: B-layout B[k=g*4+j][col=li] matches softmax's in-lane P
// layout directly -> no cross-lane exchange needed for PV.
// Guard order: (1) host pass -> inert stub (host never executes device code;
// R8's failure was __has_builtin evaluating false in the HOST pass);
// (2) device with the gfx90a-lineage _1k builtin (instruction exists on
// gfx950 per ISA §10); (3) device fallback: zero-padded K=32 MFMA -- placing
// V at slot j (k_eff=g*8+j, j<4) of A and P at the same slots of B makes the
// contraction identical (empty slots contribute 0 on both sides).
__device__ __forceinline__ f32x4 mfma16k16(short4v a, short4v b, f32x4 c) {
#if !defined(__HIP_DEVICE_COMPILE__)
  (void)a; (void)b;
  return c;
#elif __has_builtin(__builtin_amdgcn_mfma_f32_16x16x16bf16_1k)
  return __builtin_amdgcn_mfma_f32_16x16x16bf16_1k(a, b, c, 0, 0, 0);
#else
  short8 a8 = (short8){a[0], a[1], a[2], a[3], 0, 0, 0, 0};
  short8 b8 = (short8){b[0], b[1], b[2], b[3], 0, 0, 0, 0};
  return __builtin_amdgcn_mfma_f32_16x16x32_bf16(a8, b8, c, 0, 0, 0);
#endif
}
__device__ __forceinline__ void lds16(const u16* g, u16* l) {
  __builtin_amdgcn_global_load_lds(
      (const __attribute__((address_space(1))) void*)g,
      (__attribute__((address_space(3))) void*)l, 16, 0, 0);
}
// byte-level XOR swizzle: flips bits 4-6 (16B chunk idx) by row&7; involution.
__device__ __forceinline__ u32 swzb(u32 L) { return L ^ (((L >> 7) & 7) << 4); }

// ---------------- LayerNorm: x fp32 [4096][1024] -> xn bf16 ----------------
__global__ __launch_bounds__(256) void k_layernorm(const float* __restrict__ x,
                                                   const float* __restrict__ gamma,
                                                   u16* __restrict__ xn) {
  int row = blockIdx.x, tid = threadIdx.x;
  const float4 xv = *(const float4*)(x + (size_t)row * DIM_ + tid * 4);
  float s = xv.x + xv.y + xv.z + xv.w;
  float q = xv.x*xv.x + xv.y*xv.y + xv.z*xv.z + xv.w*xv.w;
  for (int off = 32; off; off >>= 1) { s += __shfl_xor(s, off); q += __shfl_xor(q, off); }
  __shared__ float red[8];
  int wave = tid >> 6, lane = tid & 63;
  if (lane == 0) { red[wave] = s; red[4 + wave] = q; }
  __syncthreads();
  s = red[0] + red[1] + red[2] + red[3];
  q = red[4] + red[5] + red[6] + red[7];
  float mu  = s * (1.0f / DIM_);
  float var = q * (1.0f / DIM_) - mu * mu;
  float inv = rsqrtf(var + 1e-5f);
  const float4 gv = *(const float4*)(gamma + tid * 4);
  ushort4 ov;
  ov.x = f2bf((xv.x - mu) * inv * gv.x);
  ov.y = f2bf((xv.y - mu) * inv * gv.y);
  ov.z = f2bf((xv.z - mu) * inv * gv.z);
  ov.w = f2bf((xv.w - mu) * inv * gv.w);
  *(ushort4*)(xn + (size_t)row * DIM_ + tid * 4) = ov;
}

// ------------- transpose+cast: in fp32 [1024][ncols] -> out bf16 [ncols][1024]
__global__ __launch_bounds__(256) void k_tcast(const float* __restrict__ in,
                                               u16* __restrict__ out, int ncols) {
  __shared__ float tile[32][33];
  int tx = threadIdx.x, ty = threadIdx.y;
  int col  = blockIdx.x * 32 + tx;   // ncols dim
  int row0 = blockIdx.y * 32;        // K dim
  for (int j = 0; j < 32; j += 8)
    tile[ty + j][tx] = in[(size_t)(row0 + ty + j) * ncols + col];
  __syncthreads();
  int orow = blockIdx.x * 32 + ty;
  int ocol = row0 + tx;
  for (int j = 0; j < 32; j += 8)
    out[(size_t)(orow + j) * DIM_ + ocol] = f2bf(tile[tx][ty + j]);
}

// ------------- mask decode with dtype auto-detect -> additive bias ---------
__global__ void k_mask(const int* __restrict__ mraw, float* __restrict__ bias) {
  __shared__ int flag;
  int tid = threadIdx.x;
  if (tid == 0) flag = 0;
  __syncthreads();
  int v = mraw[tid];                 // 1024 ints: safe under bool(4096B) or int32(16384B)
  if (v != 0 && v != 1) atomicOr(&flag, 1);
  __syncthreads();
  bool bytemode = (flag != 0);
  const unsigned char* mb = (const unsigned char*)mraw;
  if (tid < 512) {
    int j = blockIdx.x * 512 + tid;
    bool valid = bytemode ? (mb[j] != 0) : (mraw[j] != 0);
    bias[j] = valid ? 0.0f : -1e30f;
  }
}

// ------------- GEMM C = A @ Bt^T : A[M][K] bf16, Bt[N][K] bf16 -------------
template <int NF, bool OUT_BF16>
__global__ __launch_bounds__(256) void k_gemm_bt(const u16* __restrict__ A,
                                                 const u16* __restrict__ Bt,
                                                 void* __restrict__ Cv,
                                                 int M, int Ncols, int K) {
  constexpr int BN = NF * 32;
  __shared__ u16 As[128 * 32];
  __shared__ u16 Bs[BN * 32];
  const int tid = threadIdx.x;
  const int wave = tid >> 6, lane = tid & 63;
  const int g = lane >> 4, li = lane & 15;
  const int gx = gridDim.x;
  const int wg = blockIdx.y * gx + blockIdx.x;
  const int per = (gx * gridDim.y) >> 3;
  const int swz = (wg & 7) * per + (wg >> 3);
  const int tm = (swz % gx) * 128, tn = (swz / gx) * BN;
  const int wm = (wave >> 1) * 64, wn = (wave & 1) * (NF * 16);
  const int srow = wave * 16 + (lane >> 2);
  const int scol = (lane & 3) * 8;

  f32x4 acc[4][NF];
#pragma unroll
  for (int i = 0; i < 4; ++i)
#pragma unroll
    for (int j = 0; j < NF; ++j) acc[i][j] = (f32x4){0.f, 0.f, 0.f, 0.f};

  const u16* ag = A  + (size_t)(tm + srow) * K + scol;
  const u16* bg = Bt + (size_t)(tn + srow) * K + scol;

  for (int k0 = 0; k0 < K; k0 += 32) {
    __syncthreads();
#pragma unroll
    for (int p = 0; p < 2; ++p)
      lds16(ag + (size_t)p * 64 * K + k0, As + p * 2048 + wave * 512);
#pragma unroll
    for (int p = 0; p < NF / 2; ++p)
      lds16(bg + (size_t)p * 64 * K + k0, Bs + p * 2048 + wave * 512);
    __syncthreads();
    short8 af[4], bfm[NF];
#pragma unroll
    for (int m = 0; m < 4; ++m) af[m]  = ld8(As + (wm + m * 16 + li) * 32 + g * 8);
#pragma unroll
    for (int n = 0; n < NF; ++n) bfm[n] = ld8(Bs + (wn + n * 16 + li) * 32 + g * 8);
#pragma unroll
    for (int m = 0; m < 4; ++m)
#pragma unroll
      for (int n = 0; n < NF; ++n)
        acc[m][n] = mfma16(af[m], bfm[n], acc[m][n]);
  }
#pragma unroll
  for (int m = 0; m < 4; ++m)
#pragma unroll
    for (int n = 0; n < NF; ++n) {
      int row = tm + wm + m * 16 + g * 4;
      int col = tn + wn + n * 16 + li;
#pragma unroll
      for (int r = 0; r < 4; ++r) {
        float v = acc[m][n][r];
        if (OUT_BF16) ((u16*)Cv)[(size_t)(row + r) * Ncols + col] = f2bf(v);
        else          ((float*)Cv)[(size_t)(row + r) * Ncols + col] = v;
      }
    }
}

// ------------- RMS qk-norm (vectorized): Cq -> q,k bf16 [b,h,n,d] ----------
// 8 lanes per (row,head): each lane owns 8 contiguous bf16; 3-shfl reduce.
__global__ __launch_bounds__(256) void k_rms_qk(const u16* __restrict__ Cq,
                                                const float* __restrict__ gq,
                                                const float* __restrict__ gk,
                                                u16* __restrict__ qo,
                                                u16* __restrict__ ko) {
  int gid = blockIdx.x * 32 + (threadIdx.x >> 3);   // 0..131071 row-head id
  int sub = threadIdx.x & 7;
  int hh  = gid & 31;           // 0-15: q heads, 16-31: k heads
  int row = gid >> 5;           // 0..4095
  int b = row >> 11, n = row & 2047;
  bool isq = hh < 16;
  int h = hh & 15;
  int col = (isq ? 0 : 1024) + h * 64 + sub * 8;
  short8 v8 = ld8(Cq + (size_t)row * E3_ + col);
  float f[8], ss = 0.f;
#pragma unroll
  for (int j = 0; j < 8; ++j) { f[j] = bf2f((u16)v8[j]); ss += f[j] * f[j]; }
  ss += __shfl_xor(ss, 1);
  ss += __shfl_xor(ss, 2);
  ss += __shfl_xor(ss, 4);
  float scale = 8.0f / fmaxf(sqrtf(ss), 1e-12f);   // sqrt(64)=8
  const float* gam = (isq ? gq : gk) + h * 64 + sub * 8;
  ushort4 o0, o1;
  o0.x = f2bf(f[0] * scale * gam[0]); o0.y = f2bf(f[1] * scale * gam[1]);
  o0.z = f2bf(f[2] * scale * gam[2]); o0.w = f2bf(f[3] * scale * gam[3]);
  o1.x = f2bf(f[4] * scale * gam[4]); o1.y = f2bf(f[5] * scale * gam[5]);
  o1.z = f2bf(f[6] * scale * gam[6]); o1.w = f2bf(f[7] * scale * gam[7]);
  u16* dst = (isq ? qo : ko) + (((size_t)(b * H_ + h)) * N_ + n) * 64 + sub * 8;
  *(ushort4*)dst = o0;
  *(ushort4*)(dst + 4) = o1;
}

// ------------- V relayout: Cq[.,2048+h*64+d] -> vT [b*h][d][n] -------------
__global__ __launch_bounds__(256) void k_vt(const u16* __restrict__ Cq,
                                            u16* __restrict__ vT) {
  __shared__ float tile[64][65];
  int bh = blockIdx.y;
  int b = bh >> 4, h = bh & 15;
  int n0 = blockIdx.x * 64;
  int tx = threadIdx.x, ty = threadIdx.y;
  for (int i = 0; i < 64; i += 4) {
    int n = n0 + ty + i;
    tile[ty + i][tx] = bf2f(Cq[((size_t)(b * N_ + n)) * E3_ + 2048 + h * 64 + tx]);
  }
  __syncthreads();
  u16* dst = vT + (size_t)bh * 64 * N_;
  for (int i = 0; i < 64; i += 4) {
    int d = ty + i;
    dst[(size_t)d * N_ + n0 + tx] = f2bf(tile[tx][d]);
  }
}

// ------------- flash attention: LDS-staged K/V, exchange-free PV -----------
// Per block: one (b,h), 64 q-rows, 4 waves x 16 q. K/V^T tiles staged via
// global_load_lds (double-buffered, XOR-swizzled). QK^T: 16x16x32 MFMA with
// the mask bias folded into the C operand. PV: 16x16x16 MFMA whose B-layout
// (k = g*4+j) matches softmax's in-lane P layout -> R7's 24-shuffle/56-select
// lane exchange is gone. V read as swizzled ds_read_b64 (addresses
// loop-invariant).
__global__ __launch_bounds__(256, 4) void k_attn(const u16* __restrict__ Q,
                                                 const u16* __restrict__ K,
                                                 const u16* __restrict__ Vt,
                                                 const float* __restrict__ bias,
                                                 u16* __restrict__ Out) {
  __shared__ u16 Ks[2][4096];           // 16 KB: [buf][64 rows x 64 d] swizzled
  __shared__ u16 Vs[2][4096];           // 16 KB: [buf][64 d x 64 k] swizzled
  __shared__ float bias_s[N_];          // 8 KB
  int wg = blockIdx.x;
  int xcd = wg & 7, slot = wg >> 3;
  int bh = xcd * 4 + (slot & 3);        // bijective: 8 xcd x 4 bh x 32 qb
  int qb = (slot >> 2) * 64;
  int b = bh >> 4, h = bh & 15;
  int tid = threadIdx.x, wave = tid >> 6, lane = tid & 63;
  int g = lane >> 4, li = lane & 15;
  const u16* Qh = Q  + (size_t)bh * N_ * 64;
  const u16* Kh = K  + (size_t)bh * N_ * 64;
  const u16* Vh = Vt + (size_t)bh * 64 * N_;

  for (int j = tid; j < N_; j += 256) bias_s[j] = bias[b * N_ + j];

  // staging addresses (two 16B chunks per tile per thread)
  const u32 L0 = tid * 16, L1 = tid * 16 + 4096;      // LDS byte offsets in tile
  const u32 kS0 = swzb(L0) >> 1, kS1 = swzb(L1) >> 1; // K src u16 offset in tile
  const u32 vR0 = L0 >> 7, vR1 = L1 >> 7;             // V src row (d index)
  const u32 vC0 = (swzb(L0) & 127) >> 1, vC1 = (swzb(L1) & 127) >> 1;

  int qr = qb + wave * 16 + li;
  short8 aq0 = ld8(Qh + (size_t)qr * 64 + g * 8);     // B-frag: Q[q=li][d g*8..]
  short8 aq1 = ld8(Qh + (size_t)qr * 64 + 32 + g * 8);

  f32x4 oT[4];                                        // O^T[d=dc*16+g*4+r][q=li]
#pragma unroll
  for (int dc = 0; dc < 4; ++dc) oT[dc] = (f32x4){0.f, 0.f, 0.f, 0.f};
  float m = -3e38f, l = 0.f;

  // K-frag swizzled chunk offsets (u16): orig chunk g and g^4 of row li
  const int fsw  = 8 * (g ^ (li & 7));
  const int fsw2 = fsw ^ 32;
  // V-frag (b64) swizzled offsets, loop-invariant:
  // V^T[dc*16+li][c*16+g*4+j] -> u16 off dc*1024 + li*64 + ((2c+(g>>1))^(li&7))*8 + (g&1)*4
  const int vbl = li * 64 + (g & 1) * 4;              // u16 units
  int vsw[4];
#pragma unroll
  for (int c = 0; c < 4; ++c)
    vsw[c] = (((2 * c + (g >> 1)) ^ (li & 7)) << 3);  // u16 units

  // prologue: stage tile 0 into buffer 0
  lds16(Kh + kS0, &Ks[0][0] + (L0 >> 1));
  lds16(Kh + kS1, &Ks[0][0] + (L1 >> 1));
  lds16(Vh + (size_t)vR0 * N_ + vC0, &Vs[0][0] + (L0 >> 1));
  lds16(Vh + (size_t)vR1 * N_ + vC1, &Vs[0][0] + (L1 >> 1));
  __syncthreads();

  for (int kt = 0; kt < 32; ++kt) {
    int cur = kt & 1;
    int kbase = kt * 64;
    if (kt < 31) {                       // stage next tile (async, no regs)
      int nxt = cur ^ 1;
      int nb = kbase + 64;
      lds16(Kh + (size_t)nb * 64 + kS0, &Ks[nxt][0] + (L0 >> 1));
      lds16(Kh + (size_t)nb * 64 + kS1, &Ks[nxt][0] + (L1 >> 1));
      lds16(Vh + (size_t)vR0 * N_ + nb + vC0, &Vs[nxt][0] + (L0 >> 1));
      lds16(Vh + (size_t)vR1 * N_ + nb + vC1, &Vs[nxt][0] + (L1 >> 1));
    }
    const u16* Kb = &Ks[cur][0];
    const u16* Vb = &Vs[cur][0];
    // ---- S^T[c] = mfma(K, Q, C=bias): bias add folded into MFMA ---------
    f32x4 st[4];
    __builtin_amdgcn_s_setprio(1);
#pragma unroll
    for (int c = 0; c < 4; ++c) {
      int rb = (c * 16 + li) * 64;
      short8 kf0 = ld8(Kb + rb + fsw);
      short8 kf1 = ld8(Kb + rb + fsw2);
      float4 bb = *(const float4*)&bias_s[kbase + c * 16 + g * 4];
      f32x4 z = (f32x4){bb.x, bb.y, bb.z, bb.w};
      z = mfma16(kf0, aq0, z);
      st[c] = mfma16(kf1, aq1, z);
    }
    __builtin_amdgcn_s_setprio(0);
    // ---- V-frags (b64, swizzled) issued now; consumed after softmax -----
    short4v vf16[4][4];
#pragma unroll
    for (int dc = 0; dc < 4; ++dc)
#pragma unroll
      for (int c = 0; c < 4; ++c)
        vf16[dc][c] = *(const short4v*)(Vb + dc * 1024 + vbl + vsw[c]);
    // ---- tile max (tree in-lane over 16 k, then 2 shfl) -----------------
    float cm[4];
#pragma unroll
    for (int c = 0; c < 4; ++c)
      cm[c] = fmaxf(fmaxf(st[c][0], st[c][1]), fmaxf(st[c][2], st[c][3]));
    float tmax = fmaxf(fmaxf(cm[0], cm[1]), fmaxf(cm[2], cm[3]));
    tmax = fmaxf(tmax, __shfl_xor(tmax, 16));
    tmax = fmaxf(tmax, __shfl_xor(tmax, 32));
    float mn = fmaxf(m, tmax);
    float sc = __expf(m - mn);
    m = mn;
    float pv[4][4], cs[4];
#pragma unroll
    for (int c = 0; c < 4; ++c) {
#pragma unroll
      for (int r = 0; r < 4; ++r) pv[c][r] = __expf(st[c][r] - mn);
      cs[c] = (pv[c][0] + pv[c][1]) + (pv[c][2] + pv[c][3]);
    }
    float rs = (cs[0] + cs[1]) + (cs[2] + cs[3]);
    rs += __shfl_xor(rs, 16);
    rs += __shfl_xor(rs, 32);
    l = l * sc + rs;
#pragma unroll
    for (int dc = 0; dc < 4; ++dc) oT[dc] *= sc;      // lane-scalar rescale
    // ---- pack P in-lane: pb[c] = bf16x4 of P[q=li][k=c*16+g*4+0..3] ------
    union { u32 u2[2]; short4v s4; } pb[4];
#pragma unroll
    for (int c = 0; c < 4; ++c) {
      asm("v_cvt_pk_bf16_f32 %0, %1, %2" : "=v"(pb[c].u2[0]) : "v"(pv[c][0]), "v"(pv[c][1]));
      asm("v_cvt_pk_bf16_f32 %0, %1, %2" : "=v"(pb[c].u2[1]) : "v"(pv[c][2]), "v"(pv[c][3]));
    }
    // ---- PV: O^T += V^T @ P^T via K=16 MFMA (exchange-free) -------------
    __builtin_amdgcn_s_setprio(1);
#pragma unroll
    for (int dc = 0; dc < 4; ++dc)
#pragma unroll
      for (int c = 0; c < 4; ++c)
        oT[dc] = mfma16k16(vf16[dc][c], pb[c].s4, oT[dc]);
    __builtin_amdgcn_s_setprio(0);
    __syncthreads();                    // next-tile staging complete + buf free
  }

  float inv = 1.0f / l;
#pragma unroll
  for (int dc = 0; dc < 4; ++dc) {
    ushort4 ov;
    ov.x = f2bf(oT[dc][0] * inv);
    ov.y = f2bf(oT[dc][1] * inv);
    ov.z = f2bf(oT[dc][2] * inv);
    ov.w = f2bf(oT[dc][3] * inv);
    *(ushort4*)&Out[((size_t)(b * N_ + qr)) * DIM_ + h * 64 + dc * 16 + g * 4] = ov;
  }
}

// ---------------------------------------------------------------------------
extern "C" void kernel_launch(void* const* d_in, const int* in_sizes, int n_in,
                              void* d_out, int out_size, void* d_ws, size_t ws_size,
                              hipStream_t stream) {
  const float* x    = (const float*)d_in[0];
  const int*   mask = (const int*)d_in[1];
  const float* g_ln = (const float*)d_in[2];
  const float* g_q  = (const float*)d_in[3];
  const float* g_k  = (const float*)d_in[4];
  const float* Wq   = (const float*)d_in[5];
  const float* Wkv  = (const float*)d_in[6];
  const float* Wo   = (const float*)d_in[7];
  float* out = (float*)d_out;

  char* ws = (char*)d_ws;
  u16*   xn   = (u16*)(ws);                         // 8 MB
  u16*   Wt   = (u16*)(ws + 8388608);               // 6 MB  (Wq^T | Wkv^T) [3072][1024]
  u16*   Wot  = (u16*)(ws + 14680064);              // 2 MB  Wo^T [1024][1024]
  float* bias = (float*)(ws + 16777216);            // 16 KB
  u16*   Cq   = (u16*)(ws + 16793600);              // 24 MB [4096][3072]
  u16*   qb   = (u16*)(ws + 41959424);              // 8 MB [b,h,n,d]
  u16*   kb   = (u16*)(ws + 41959424 + 8388608);    // 8 MB
  u16*   vT   = (u16*)(ws + 41959424 + 2*8388608);  // 8 MB [b*h][d][n]
  u16*   ao   = (u16*)(ws + 41959424 + 3*8388608);  // 8 MB [4096][1024]

  k_layernorm<<<ROWS_, 256, 0, stream>>>(x, g_ln, xn);
  dim3 tcb(32, 8);
  k_tcast<<<dim3(32, 32), tcb, 0, stream>>>(Wq,  Wt,               1024);
  k_tcast<<<dim3(64, 32), tcb, 0, stream>>>(Wkv, Wt + 1024 * 1024, 2048);
  k_tcast<<<dim3(32, 32), tcb, 0, stream>>>(Wo,  Wot,              1024);
  k_mask<<<8, 1024, 0, stream>>>(mask, bias);
  k_gemm_bt<4, true><<<dim3(32, 24), 256, 0, stream>>>(xn, Wt, Cq, ROWS_, E3_, DIM_);
  k_rms_qk<<<4096, 256, 0, stream>>>(Cq, g_q, g_k, qb, kb);
  k_vt<<<dim3(32, 32), dim3(64, 4), 0, stream>>>(Cq, vT);
  k_attn<<<1024, 256, 0, stream>>>(qb, kb, vT, bias, ao);
  k_gemm_bt<2, false><<<dim3(32, 16), 256, 0, stream>>>(ao, Wot, out, ROWS_, DIM_, DIM_);
}

// Round 12
// 161.027 us; speedup vs baseline: 2.0762x; 1.0005x over previous
//
#include <hip/hip_runtime.h>

using u16 = unsigned short;
using u32 = unsigned int;

#define B_   2
#define N_   2048
#define DIM_ 1024
#define H_   16
#define D_   64
#define ROWS_ (B_*N_)   // 4096
#define E3_  3072       // q|k|v concatenated

typedef __attribute__((ext_vector_type(8))) short short8;
typedef __attribute__((ext_vector_type(4))) short short4v;
typedef __attribute__((ext_vector_type(4))) float f32x4;

__device__ __forceinline__ u16 f2bf(float f) {
  u32 u = __builtin_bit_cast(u32, f);
  u32 r = (u + 0x7FFFu + ((u >> 16) & 1u)) >> 16;
  return (u16)r;
}
__device__ __forceinline__ float bf2f(u16 h) {
  u32 u = ((u32)h) << 16;
  return __builtin_bit_cast(float, u);
}
__device__ __forceinline__ short8 ld8(const u16* p) { return *(const short8*)p; }
__device__ __forceinline__ f32x4 mfma16(short8 a, short8 b, f32x4 c) {
  return __builtin_amdgcn_mfma_f32_16x16x32_bf16(a, b, c, 0, 0, 0);
}
// K=16 bf16 MFMA (R9-verified): B[k=g*4+j][col=li] == softmax's in-lane P.
__device__ __forceinline__ f32x4 mfma16k16(short4v a, short4v b, f32x4 c) {
#if !defined(__HIP_DEVICE_COMPILE__)
  (void)a; (void)b;
  return c;
#elif __has_builtin(__builtin_amdgcn_mfma_f32_16x16x16bf16_1k)
  return __builtin_amdgcn_mfma_f32_16x16x16bf16_1k(a, b, c, 0, 0, 0);
#else
  short8 a8 = (short8){a[0], a[1], a[2], a[3], 0, 0, 0, 0};
  short8 b8 = (short8){b[0], b[1], b[2], b[3], 0, 0, 0, 0};
  return __builtin_amdgcn_mfma_f32_16x16x32_bf16(a8, b8, c, 0, 0, 0);
#endif
}
__device__ __forceinline__ void lds16(const u16* g, u16* l) {
  __builtin_amdgcn_global_load_lds(
      (const __attribute__((address_space(1))) void*)g,
      (__attribute__((address_space(3))) void*)l, 16, 0, 0);
}
// byte-level XOR swizzle: flips bits 4-6 (16B chunk idx) by row&7; involution.
__device__ __forceinline__ u32 swzb(u32 L) { return L ^ (((L >> 7) & 7) << 4); }

// ---------------- LayerNorm: x fp32 [4096][1024] -> xn bf16 ----------------
__global__ __launch_bounds__(256) void k_layernorm(const float* __restrict__ x,
                                                   const float* __restrict__ gamma,
                                                   u16* __restrict__ xn) {
  int row = blockIdx.x, tid = threadIdx.x;
  const float4 xv = *(const float4*)(x + (size_t)row * DIM_ + tid * 4);
  float s = xv.x + xv.y + xv.z + xv.w;
  float q = xv.x*xv.x + xv.y*xv.y + xv.z*xv.z + xv.w*xv.w;
  for (int off = 32; off; off >>= 1) { s += __shfl_xor(s, off); q += __shfl_xor(q, off); }
  __shared__ float red[8];
  int wave = tid >> 6, lane = tid & 63;
  if (lane == 0) { red[wave] = s; red[4 + wave] = q; }
  __syncthreads();
  s = red[0] + red[1] + red[2] + red[3];
  q = red[4] + red[5] + red[6] + red[7];
  float mu  = s * (1.0f / DIM_);
  float var = q * (1.0f / DIM_) - mu * mu;
  float inv = rsqrtf(var + 1e-5f);
  const float4 gv = *(const float4*)(gamma + tid * 4);
  ushort4 ov;
  ov.x = f2bf((xv.x - mu) * inv * gv.x);
  ov.y = f2bf((xv.y - mu) * inv * gv.y);
  ov.z = f2bf((xv.z - mu) * inv * gv.z);
  ov.w = f2bf((xv.w - mu) * inv * gv.w);
  *(ushort4*)(xn + (size_t)row * DIM_ + tid * 4) = ov;
}

// ---- transpose+cast, all 3 weights in one launch: saves 2 dispatches ------
// bx in [0,32): Wq -> Wt[0..]; [32,96): Wkv -> Wt[1M..]; [96,128): Wo -> Wot.
__global__ __launch_bounds__(256) void k_tcast_all(const float* __restrict__ Wq,
                                                   const float* __restrict__ Wkv,
                                                   const float* __restrict__ Wo,
                                                   u16* __restrict__ Wt,
                                                   u16* __restrict__ Wot) {
  __shared__ float tile[32][33];
  int bx = blockIdx.x;
  const float* in; u16* out; int ncols, cb;
  if (bx < 32)      { in = Wq;  out = Wt;               ncols = 1024; cb = bx; }
  else if (bx < 96) { in = Wkv; out = Wt + 1024 * 1024; ncols = 2048; cb = bx - 32; }
  else              { in = Wo;  out = Wot;              ncols = 1024; cb = bx - 96; }
  int tx = threadIdx.x, ty = threadIdx.y;
  int col  = cb * 32 + tx;
  int row0 = blockIdx.y * 32;
  for (int j = 0; j < 32; j += 8)
    tile[ty + j][tx] = in[(size_t)(row0 + ty + j) * ncols + col];
  __syncthreads();
  int orow = cb * 32 + ty;
  int ocol = row0 + tx;
  for (int j = 0; j < 32; j += 8)
    out[(size_t)(orow + j) * DIM_ + ocol] = f2bf(tile[tx][ty + j]);
}

// ------------- mask decode with dtype auto-detect -> additive bias ---------
__global__ void k_mask(const int* __restrict__ mraw, float* __restrict__ bias) {
  __shared__ int flag;
  int tid = threadIdx.x;
  if (tid == 0) flag = 0;
  __syncthreads();
  int v = mraw[tid];                 // 1024 ints: safe under bool(4096B) or int32(16384B)
  if (v != 0 && v != 1) atomicOr(&flag, 1);
  __syncthreads();
  bool bytemode = (flag != 0);
  const unsigned char* mb = (const unsigned char*)mraw;
  if (tid < 512) {
    int j = blockIdx.x * 512 + tid;
    bool valid = bytemode ? (mb[j] != 0) : (mraw[j] != 0);
    bias[j] = valid ? 0.0f : -1e30f;
  }
}

// ------------- GEMM C = A @ Bt^T : A[M][K] bf16, Bt[N][K] bf16 -------------
template <int NF, bool OUT_BF16>
__global__ __launch_bounds__(256) void k_gemm_bt(const u16* __restrict__ A,
                                                 const u16* __restrict__ Bt,
                                                 void* __restrict__ Cv,
                                                 int M, int Ncols, int K) {
  constexpr int BN = NF * 32;
  __shared__ u16 As[128 * 32];
  __shared__ u16 Bs[BN * 32];
  const int tid = threadIdx.x;
  const int wave = tid >> 6, lane = tid & 63;
  const int g = lane >> 4, li = lane & 15;
  const int gx = gridDim.x;
  const int wg = blockIdx.y * gx + blockIdx.x;
  const int per = (gx * gridDim.y) >> 3;
  const int swz = (wg & 7) * per + (wg >> 3);
  const int tm = (swz % gx) * 128, tn = (swz / gx) * BN;
  const int wm = (wave >> 1) * 64, wn = (wave & 1) * (NF * 16);
  const int srow = wave * 16 + (lane >> 2);
  const int scol = (lane & 3) * 8;

  f32x4 acc[4][NF];
#pragma unroll
  for (int i = 0; i < 4; ++i)
#pragma unroll
    for (int j = 0; j < NF; ++j) acc[i][j] = (f32x4){0.f, 0.f, 0.f, 0.f};

  const u16* ag = A  + (size_t)(tm + srow) * K + scol;
  const u16* bg = Bt + (size_t)(tn + srow) * K + scol;

  for (int k0 = 0; k0 < K; k0 += 32) {
    __syncthreads();
#pragma unroll
    for (int p = 0; p < 2; ++p)
      lds16(ag + (size_t)p * 64 * K + k0, As + p * 2048 + wave * 512);
#pragma unroll
    for (int p = 0; p < NF / 2; ++p)
      lds16(bg + (size_t)p * 64 * K + k0, Bs + p * 2048 + wave * 512);
    __syncthreads();
    short8 af[4], bfm[NF];
#pragma unroll
    for (int m = 0; m < 4; ++m) af[m]  = ld8(As + (wm + m * 16 + li) * 32 + g * 8);
#pragma unroll
    for (int n = 0; n < NF; ++n) bfm[n] = ld8(Bs + (wn + n * 16 + li) * 32 + g * 8);
#pragma unroll
    for (int m = 0; m < 4; ++m)
#pragma unroll
      for (int n = 0; n < NF; ++n)
        acc[m][n] = mfma16(af[m], bfm[n], acc[m][n]);
  }
#pragma unroll
  for (int m = 0; m < 4; ++m)
#pragma unroll
    for (int n = 0; n < NF; ++n) {
      int row = tm + wm + m * 16 + g * 4;
      int col = tn + wn + n * 16 + li;
#pragma unroll
      for (int r = 0; r < 4; ++r) {
        float v = acc[m][n][r];
        if (OUT_BF16) ((u16*)Cv)[(size_t)(row + r) * Ncols + col] = f2bf(v);
        else          ((float*)Cv)[(size_t)(row + r) * Ncols + col] = v;
      }
    }
}

// ------------- RMS qk-norm (vectorized): Cq -> q,k bf16 [b,h,n,d] ----------
__global__ __launch_bounds__(256) void k_rms_qk(const u16* __restrict__ Cq,
                                                const float* __restrict__ gq,
                                                const float* __restrict__ gk,
                                                u16* __restrict__ qo,
                                                u16* __restrict__ ko) {
  int gid = blockIdx.x * 32 + (threadIdx.x >> 3);   // 0..131071 row-head id
  int sub = threadIdx.x & 7;
  int hh  = gid & 31;           // 0-15: q heads, 16-31: k heads
  int row = gid >> 5;           // 0..4095
  int b = row >> 11, n = row & 2047;
  bool isq = hh < 16;
  int h = hh & 15;
  int col = (isq ? 0 : 1024) + h * 64 + sub * 8;
  short8 v8 = ld8(Cq + (size_t)row * E3_ + col);
  float f[8], ss = 0.f;
#pragma unroll
  for (int j = 0; j < 8; ++j) { f[j] = bf2f((u16)v8[j]); ss += f[j] * f[j]; }
  ss += __shfl_xor(ss, 1);
  ss += __shfl_xor(ss, 2);
  ss += __shfl_xor(ss, 4);
  float scale = 8.0f / fmaxf(sqrtf(ss), 1e-12f);   // sqrt(64)=8
  const float* gam = (isq ? gq : gk) + h * 64 + sub * 8;
  ushort4 o0, o1;
  o0.x = f2bf(f[0] * scale * gam[0]); o0.y = f2bf(f[1] * scale * gam[1]);
  o0.z = f2bf(f[2] * scale * gam[2]); o0.w = f2bf(f[3] * scale * gam[3]);
  o1.x = f2bf(f[4] * scale * gam[4]); o1.y = f2bf(f[5] * scale * gam[5]);
  o1.z = f2bf(f[6] * scale * gam[6]); o1.w = f2bf(f[7] * scale * gam[7]);
  u16* dst = (isq ? qo : ko) + (((size_t)(b * H_ + h)) * N_ + n) * 64 + sub * 8;
  *(ushort4*)dst = o0;
  *(ushort4*)(dst + 4) = o1;
}

// ------------- V relayout (R9-exact, identity cols): -> vT [b*h][d][n] -----
__global__ __launch_bounds__(256) void k_vt(const u16* __restrict__ Cq,
                                            u16* __restrict__ vT) {
  __shared__ float tile[64][65];
  int bh = blockIdx.y;
  int b = bh >> 4, h = bh & 15;
  int n0 = blockIdx.x * 64;
  int tx = threadIdx.x, ty = threadIdx.y;
  for (int i = 0; i < 64; i += 4) {
    int n = n0 + ty + i;
    tile[ty + i][tx] = bf2f(Cq[((size_t)(b * N_ + n)) * E3_ + 2048 + h * 64 + tx]);
  }
  __syncthreads();
  u16* dst = vT + (size_t)bh * 64 * N_;
  for (int i = 0; i < 64; i += 4) {
    int d = ty + i;
    dst[(size_t)d * N_ + n0 + tx] = f2bf(tile[tx][d]);
  }
}

// ------------- flash attention: R9 V-path, 2 q-subgroups per wave ----------
// 128-thread blocks (2 waves x 32 q = 64 q), grid 1024 (same XCD swizzle as
// R9). Per k-tile, K/V/bias LDS reads are q-independent -> serving 2 q-groups
// per wave HALVES LDS-pipe demand per unit work (R9's binding resource: 28
// LDS ops x 16 waves/CU ~ 80% of the per-iter wall). K-frag, V-frag (b64,
// R9-exact incl. its 4-way conflict), staging involution, softmax, K=16 PV
// all verbatim R9 -- only duplicated per q-group. Staging: 4x16B chunks per
// thread (128 thr x 64B = 8KB tile).
__global__ __launch_bounds__(128, 2) void k_attn(const u16* __restrict__ Q,
                                                 const u16* __restrict__ K,
                                                 const u16* __restrict__ Vt,
                                                 const float* __restrict__ bias,
                                                 u16* __restrict__ Out) {
  __shared__ u16 Ks[2][4096];           // 16 KB
  __shared__ u16 Vs[2][4096];           // 16 KB
  __shared__ float bias_s[N_];          // 8 KB
  int wg = blockIdx.x;
  int xcd = wg & 7, slot = wg >> 3;
  int bh = xcd * 4 + (slot & 3);        // bijective: 8 xcd x 4 bh x 32 qb
  int qb = (slot >> 2) * 64;
  int b = bh >> 4, h = bh & 15;
  int tid = threadIdx.x, wave = tid >> 6, lane = tid & 63;
  int g = lane >> 4, li = lane & 15;
  const u16* Qh = Q  + (size_t)bh * N_ * 64;
  const u16* Kh = K  + (size_t)bh * N_ * 64;
  const u16* Vh = Vt + (size_t)bh * 64 * N_;

  for (int j = tid; j < N_; j += 128) bias_s[j] = bias[b * N_ + j];

  // staging addresses: 4 chunks of 16B per tile per thread
  u32 Ls[4], kS[4], vR[4], vC[4];
#pragma unroll
  for (int s = 0; s < 4; ++s) {
    Ls[s] = tid * 16 + s * 2048;
    kS[s] = swzb(Ls[s]) >> 1;
    vR[s] = Ls[s] >> 7;
    vC[s] = (swzb(Ls[s]) & 127) >> 1;
  }

  int qr0 = qb + wave * 32 + li;        // q-subgroup A
  int qr1 = qr0 + 16;                   // q-subgroup B
  short8 aqA0 = ld8(Qh + (size_t)qr0 * 64 + g * 8);
  short8 aqA1 = ld8(Qh + (size_t)qr0 * 64 + 32 + g * 8);
  short8 aqB0 = ld8(Qh + (size_t)qr1 * 64 + g * 8);
  short8 aqB1 = ld8(Qh + (size_t)qr1 * 64 + 32 + g * 8);

  f32x4 oTA[4], oTB[4];
#pragma unroll
  for (int dc = 0; dc < 4; ++dc) {
    oTA[dc] = (f32x4){0.f, 0.f, 0.f, 0.f};
    oTB[dc] = (f32x4){0.f, 0.f, 0.f, 0.f};
  }
  float mA = -3e38f, lA = 0.f, mB = -3e38f, lB = 0.f;

  // K-frag swizzled chunk offsets (u16): orig chunk g and g^4 of row li
  const int fsw  = 8 * (g ^ (li & 7));
  const int fsw2 = fsw ^ 32;
  // V-frag (b64) swizzled offsets (R9-exact)
  const int vbl = li * 64 + (g & 1) * 4;
  int vsw[4];
#pragma unroll
  for (int c = 0; c < 4; ++c)
    vsw[c] = (((2 * c + (g >> 1)) ^ (li & 7)) << 3);

  // prologue: stage tile 0 into buffer 0
#pragma unroll
  for (int s = 0; s < 4; ++s) {
    lds16(Kh + kS[s], &Ks[0][0] + (Ls[s] >> 1));
    lds16(Vh + (size_t)vR[s] * N_ + vC[s], &Vs[0][0] + (Ls[s] >> 1));
  }
  __syncthreads();

  for (int kt = 0; kt < 32; ++kt) {
    int cur = kt & 1;
    int kbase = kt * 64;
    if (kt < 31) {                       // stage next tile (async, no regs)
      int nxt = cur ^ 1;
      int nb = kbase + 64;
#pragma unroll
      for (int s = 0; s < 4; ++s) {
        lds16(Kh + (size_t)nb * 64 + kS[s], &Ks[nxt][0] + (Ls[s] >> 1));
        lds16(Vh + (size_t)vR[s] * N_ + nb + vC[s], &Vs[nxt][0] + (Ls[s] >> 1));
      }
    }
    const u16* Kb = &Ks[cur][0];
    const u16* Vb = &Vs[cur][0];
    // ---- S^T = mfma(K, Q, C=bias) for both q-groups (K-frags shared) ----
    f32x4 stA[4], stB[4];
    __builtin_amdgcn_s_setprio(1);
#pragma unroll
    for (int c = 0; c < 4; ++c) {
      int rb = (c * 16 + li) * 64;
      short8 kf0 = ld8(Kb + rb + fsw);
      short8 kf1 = ld8(Kb + rb + fsw2);
      float4 bb = *(const float4*)&bias_s[kbase + c * 16 + g * 4];
      f32x4 z = (f32x4){bb.x, bb.y, bb.z, bb.w};
      stA[c] = mfma16(kf1, aqA1, mfma16(kf0, aqA0, z));
      stB[c] = mfma16(kf1, aqB1, mfma16(kf0, aqB0, z));
    }
    __builtin_amdgcn_s_setprio(0);
    // ---- V-frags (R9-exact b64 reads), shared by both q-groups ----------
    short4v vf16[4][4];
#pragma unroll
    for (int dc = 0; dc < 4; ++dc)
#pragma unroll
      for (int c = 0; c < 4; ++c)
        vf16[dc][c] = *(const short4v*)(Vb + dc * 1024 + vbl + vsw[c]);
    // ---- softmax group A -------------------------------------------------
    float cmA[4];
#pragma unroll
    for (int c = 0; c < 4; ++c)
      cmA[c] = fmaxf(fmaxf(stA[c][0], stA[c][1]), fmaxf(stA[c][2], stA[c][3]));
    float tmaxA = fmaxf(fmaxf(cmA[0], cmA[1]), fmaxf(cmA[2], cmA[3]));
    tmaxA = fmaxf(tmaxA, __shfl_xor(tmaxA, 16));
    tmaxA = fmaxf(tmaxA, __shfl_xor(tmaxA, 32));
    float mnA = fmaxf(mA, tmaxA);
    float scA = __expf(mA - mnA);
    mA = mnA;
    float pvA[4][4], csA[4];
#pragma unroll
    for (int c = 0; c < 4; ++c) {
#pragma unroll
      for (int r = 0; r < 4; ++r) pvA[c][r] = __expf(stA[c][r] - mnA);
      csA[c] = (pvA[c][0] + pvA[c][1]) + (pvA[c][2] + pvA[c][3]);
    }
    float rsA = (csA[0] + csA[1]) + (csA[2] + csA[3]);
    rsA += __shfl_xor(rsA, 16);
    rsA += __shfl_xor(rsA, 32);
    lA = lA * scA + rsA;
#pragma unroll
    for (int dc = 0; dc < 4; ++dc) oTA[dc] *= scA;
    // ---- softmax group B -------------------------------------------------
    float cmB[4];
#pragma unroll
    for (int c = 0; c < 4; ++c)
      cmB[c] = fmaxf(fmaxf(stB[c][0], stB[c][1]), fmaxf(stB[c][2], stB[c][3]));
    float tmaxB = fmaxf(fmaxf(cmB[0], cmB[1]), fmaxf(cmB[2], cmB[3]));
    tmaxB = fmaxf(tmaxB, __shfl_xor(tmaxB, 16));
    tmaxB = fmaxf(tmaxB, __shfl_xor(tmaxB, 32));
    float mnB = fmaxf(mB, tmaxB);
    float scB = __expf(mB - mnB);
    mB = mnB;
    float pvB[4][4], csB[4];
#pragma unroll
    for (int c = 0; c < 4; ++c) {
#pragma unroll
      for (int r = 0; r < 4; ++r) pvB[c][r] = __expf(stB[c][r] - mnB);
      csB[c] = (pvB[c][0] + pvB[c][1]) + (pvB[c][2] + pvB[c][3]);
    }
    float rsB = (csB[0] + csB[1]) + (csB[2] + csB[3]);
    rsB += __shfl_xor(rsB, 16);
    rsB += __shfl_xor(rsB, 32);
    lB = lB * scB + rsB;
#pragma unroll
    for (int dc = 0; dc < 4; ++dc) oTB[dc] *= scB;
    // ---- pack P (both groups) via v_cvt_pk_bf16_f32 ----------------------
    union { u32 u2[2]; short4v s4; } pbA[4], pbB[4];
#pragma unroll
    for (int c = 0; c < 4; ++c) {
      asm("v_cvt_pk_bf16_f32 %0, %1, %2" : "=v"(pbA[c].u2[0]) : "v"(pvA[c][0]), "v"(pvA[c][1]));
      asm("v_cvt_pk_bf16_f32 %0, %1, %2" : "=v"(pbA[c].u2[1]) : "v"(pvA[c][2]), "v"(pvA[c][3]));
      asm("v_cvt_pk_bf16_f32 %0, %1, %2" : "=v"(pbB[c].u2[0]) : "v"(pvB[c][0]), "v"(pvB[c][1]));
      asm("v_cvt_pk_bf16_f32 %0, %1, %2" : "=v"(pbB[c].u2[1]) : "v"(pvB[c][2]), "v"(pvB[c][3]));
    }
    // ---- PV: V-frag (A operand) shared, B operand per q-group -----------
    __builtin_amdgcn_s_setprio(1);
#pragma unroll
    for (int dc = 0; dc < 4; ++dc)
#pragma unroll
      for (int c = 0; c < 4; ++c) {
        oTA[dc] = mfma16k16(vf16[dc][c], pbA[c].s4, oTA[dc]);
        oTB[dc] = mfma16k16(vf16[dc][c], pbB[c].s4, oTB[dc]);
      }
    __builtin_amdgcn_s_setprio(0);
    __syncthreads();                    // next-tile staging complete + buf free
  }

  float invA = 1.0f / lA, invB = 1.0f / lB;
#pragma unroll
  for (int dc = 0; dc < 4; ++dc) {
    ushort4 ovA, ovB;
    ovA.x = f2bf(oTA[dc][0] * invA); ovA.y = f2bf(oTA[dc][1] * invA);
    ovA.z = f2bf(oTA[dc][2] * invA); ovA.w = f2bf(oTA[dc][3] * invA);
    ovB.x = f2bf(oTB[dc][0] * invB); ovB.y = f2bf(oTB[dc][1] * invB);
    ovB.z = f2bf(oTB[dc][2] * invB); ovB.w = f2bf(oTB[dc][3] * invB);
    *(ushort4*)&Out[((size_t)(b * N_ + qr0)) * DIM_ + h * 64 + dc * 16 + g * 4] = ovA;
    *(ushort4*)&Out[((size_t)(b * N_ + qr1)) * DIM_ + h * 64 + dc * 16 + g * 4] = ovB;
  }
}

// ---------------------------------------------------------------------------
extern "C" void kernel_launch(void* const* d_in, const int* in_sizes, int n_in,
                              void* d_out, int out_size, void* d_ws, size_t ws_size,
                              hipStream_t stream) {
  const float* x    = (const float*)d_in[0];
  const int*   mask = (const int*)d_in[1];
  const float* g_ln = (const float*)d_in[2];
  const float* g_q  = (const float*)d_in[3];
  const float* g_k  = (const float*)d_in[4];
  const float* Wq   = (const float*)d_in[5];
  const float* Wkv  = (const float*)d_in[6];
  const float* Wo   = (const float*)d_in[7];
  float* out = (float*)d_out;

  char* ws = (char*)d_ws;
  u16*   xn   = (u16*)(ws);                         // 8 MB
  u16*   Wt   = (u16*)(ws + 8388608);               // 6 MB  (Wq^T | Wkv^T) [3072][1024]
  u16*   Wot  = (u16*)(ws + 14680064);              // 2 MB  Wo^T [1024][1024]
  float* bias = (float*)(ws + 16777216);            // 16 KB
  u16*   Cq   = (u16*)(ws + 16793600);              // 24 MB [4096][3072]
  u16*   qb   = (u16*)(ws + 41959424);              // 8 MB [b,h,n,d]
  u16*   kb   = (u16*)(ws + 41959424 + 8388608);    // 8 MB
  u16*   vT   = (u16*)(ws + 41959424 + 2*8388608);  // 8 MB [b*h][d][n]
  u16*   ao   = (u16*)(ws + 41959424 + 3*8388608);  // 8 MB [4096][1024]

  k_layernorm<<<ROWS_, 256, 0, stream>>>(x, g_ln, xn);
  k_tcast_all<<<dim3(128, 32), dim3(32, 8), 0, stream>>>(Wq, Wkv, Wo, Wt, Wot);
  k_mask<<<8, 1024, 0, stream>>>(mask, bias);
  k_gemm_bt<4, true><<<dim3(32, 24), 256, 0, stream>>>(xn, Wt, Cq, ROWS_, E3_, DIM_);
  k_rms_qk<<<4096, 256, 0, stream>>>(Cq, g_q, g_k, qb, kb);
  k_vt<<<dim3(32, 32), dim3(64, 4), 0, stream>>>(Cq, vT);
  k_attn<<<1024, 128, 0, stream>>>(qb, kb, vT, bias, ao);
  k_gemm_bt<2, false><<<dim3(32, 16), 256, 0, stream>>>(ao, Wot, out, ROWS_, DIM_, DIM_);
}

// Round 16
// 159.527 us; speedup vs baseline: 2.0957x; 1.0094x over previous
//
#include <hip/hip_runtime.h>

using u16 = unsigned short;
using u32 = unsigned int;

#define B_   2
#define N_   2048
#define DIM_ 1024
#define H_   16
#define D_   64
#define ROWS_ (B_*N_)   // 4096
#define E3_  3072       // q|k|v concatenated

typedef __attribute__((ext_vector_type(8))) short short8;
typedef __attribute__((ext_vector_type(4))) short short4v;
typedef __attribute__((ext_vector_type(4))) float f32x4;

__device__ __forceinline__ u16 f2bf(float f) {
  u32 u = __builtin_bit_cast(u32, f);
  u32 r = (u + 0x7FFFu + ((u >> 16) & 1u)) >> 16;
  return (u16)r;
}
__device__ __forceinline__ float bf2f(u16 h) {
  u32 u = ((u32)h) << 16;
  return __builtin_bit_cast(float, u);
}
__device__ __forceinline__ short8 ld8(const u16* p) { return *(const short8*)p; }
__device__ __forceinline__ f32x4 mfma16(short8 a, short8 b, f32x4 c) {
  return __builtin_amdgcn_mfma_f32_16x16x32_bf16(a, b, c, 0, 0, 0);
}
// K=16 bf16 MFMA (R9-verified): B[k=g*4+j][col=li] == softmax's in-lane P.
__device__ __forceinline__ f32x4 mfma16k16(short4v a, short4v b, f32x4 c) {
#if !defined(__HIP_DEVICE_COMPILE__)
  (void)a; (void)b;
  return c;
#elif __has_builtin(__builtin_amdgcn_mfma_f32_16x16x16bf16_1k)
  return __builtin_amdgcn_mfma_f32_16x16x16bf16_1k(a, b, c, 0, 0, 0);
#else
  short8 a8 = (short8){a[0], a[1], a[2], a[3], 0, 0, 0, 0};
  short8 b8 = (short8){b[0], b[1], b[2], b[3], 0, 0, 0, 0};
  return __builtin_amdgcn_mfma_f32_16x16x32_bf16(a8, b8, c, 0, 0, 0);
#endif
}
__device__ __forceinline__ void lds16(const u16* g, u16* l) {
  __builtin_amdgcn_global_load_lds(
      (const __attribute__((address_space(1))) void*)g,
      (__attribute__((address_space(3))) void*)l, 16, 0, 0);
}
// byte-level XOR swizzle: flips bits 4-6 (16B chunk idx) by row&7; involution.
__device__ __forceinline__ u32 swzb(u32 L) { return L ^ (((L >> 7) & 7) << 4); }

// ---------------- LayerNorm: x fp32 [4096][1024] -> xn bf16 ----------------
__global__ __launch_bounds__(256) void k_layernorm(const float* __restrict__ x,
                                                   const float* __restrict__ gamma,
                                                   u16* __restrict__ xn) {
  int row = blockIdx.x, tid = threadIdx.x;
  const float4 xv = *(const float4*)(x + (size_t)row * DIM_ + tid * 4);
  float s = xv.x + xv.y + xv.z + xv.w;
  float q = xv.x*xv.x + xv.y*xv.y + xv.z*xv.z + xv.w*xv.w;
  for (int off = 32; off; off >>= 1) { s += __shfl_xor(s, off); q += __shfl_xor(q, off); }
  __shared__ float red[8];
  int wave = tid >> 6, lane = tid & 63;
  if (lane == 0) { red[wave] = s; red[4 + wave] = q; }
  __syncthreads();
  s = red[0] + red[1] + red[2] + red[3];
  q = red[4] + red[5] + red[6] + red[7];
  float mu  = s * (1.0f / DIM_);
  float var = q * (1.0f / DIM_) - mu * mu;
  float inv = rsqrtf(var + 1e-5f);
  const float4 gv = *(const float4*)(gamma + tid * 4);
  ushort4 ov;
  ov.x = f2bf((xv.x - mu) * inv * gv.x);
  ov.y = f2bf((xv.y - mu) * inv * gv.y);
  ov.z = f2bf((xv.z - mu) * inv * gv.z);
  ov.w = f2bf((xv.w - mu) * inv * gv.w);
  *(ushort4*)(xn + (size_t)row * DIM_ + tid * 4) = ov;
}

// ---- transpose+cast, all 3 weights in one launch --------------------------
__global__ __launch_bounds__(256) void k_tcast_all(const float* __restrict__ Wq,
                                                   const float* __restrict__ Wkv,
                                                   const float* __restrict__ Wo,
                                                   u16* __restrict__ Wt,
                                                   u16* __restrict__ Wot) {
  __shared__ float tile[32][33];
  int bx = blockIdx.x;
  const float* in; u16* out; int ncols, cb;
  if (bx < 32)      { in = Wq;  out = Wt;               ncols = 1024; cb = bx; }
  else if (bx < 96) { in = Wkv; out = Wt + 1024 * 1024; ncols = 2048; cb = bx - 32; }
  else              { in = Wo;  out = Wot;              ncols = 1024; cb = bx - 96; }
  int tx = threadIdx.x, ty = threadIdx.y;
  int col  = cb * 32 + tx;
  int row0 = blockIdx.y * 32;
  for (int j = 0; j < 32; j += 8)
    tile[ty + j][tx] = in[(size_t)(row0 + ty + j) * ncols + col];
  __syncthreads();
  int orow = cb * 32 + ty;
  int ocol = row0 + tx;
  for (int j = 0; j < 32; j += 8)
    out[(size_t)(orow + j) * DIM_ + ocol] = f2bf(tile[tx][ty + j]);
}

// ------------- mask decode with dtype auto-detect -> additive bias ---------
__global__ void k_mask(const int* __restrict__ mraw, float* __restrict__ bias) {
  __shared__ int flag;
  int tid = threadIdx.x;
  if (tid == 0) flag = 0;
  __syncthreads();
  int v = mraw[tid];                 // 1024 ints: safe under bool(4096B) or int32(16384B)
  if (v != 0 && v != 1) atomicOr(&flag, 1);
  __syncthreads();
  bool bytemode = (flag != 0);
  const unsigned char* mb = (const unsigned char*)mraw;
  if (tid < 512) {
    int j = blockIdx.x * 512 + tid;
    bool valid = bytemode ? (mb[j] != 0) : (mraw[j] != 0);
    bias[j] = valid ? 0.0f : -1e30f;
  }
}

// ------------- GEMM C = A @ Bt^T : A[M][K] bf16, Bt[N][K] bf16 -------------
template <int NF, bool OUT_BF16>
__global__ __launch_bounds__(256) void k_gemm_bt(const u16* __restrict__ A,
                                                 const u16* __restrict__ Bt,
                                                 void* __restrict__ Cv,
                                                 int M, int Ncols, int K) {
  constexpr int BN = NF * 32;
  __shared__ u16 As[128 * 32];
  __shared__ u16 Bs[BN * 32];
  const int tid = threadIdx.x;
  const int wave = tid >> 6, lane = tid & 63;
  const int g = lane >> 4, li = lane & 15;
  const int gx = gridDim.x;
  const int wg = blockIdx.y * gx + blockIdx.x;
  const int per = (gx * gridDim.y) >> 3;
  const int swz = (wg & 7) * per + (wg >> 3);
  const int tm = (swz % gx) * 128, tn = (swz / gx) * BN;
  const int wm = (wave >> 1) * 64, wn = (wave & 1) * (NF * 16);
  const int srow = wave * 16 + (lane >> 2);
  const int scol = (lane & 3) * 8;

  f32x4 acc[4][NF];
#pragma unroll
  for (int i = 0; i < 4; ++i)
#pragma unroll
    for (int j = 0; j < NF; ++j) acc[i][j] = (f32x4){0.f, 0.f, 0.f, 0.f};

  const u16* ag = A  + (size_t)(tm + srow) * K + scol;
  const u16* bg = Bt + (size_t)(tn + srow) * K + scol;

  for (int k0 = 0; k0 < K; k0 += 32) {
    __syncthreads();
#pragma unroll
    for (int p = 0; p < 2; ++p)
      lds16(ag + (size_t)p * 64 * K + k0, As + p * 2048 + wave * 512);
#pragma unroll
    for (int p = 0; p < NF / 2; ++p)
      lds16(bg + (size_t)p * 64 * K + k0, Bs + p * 2048 + wave * 512);
    __syncthreads();
    short8 af[4], bfm[NF];
#pragma unroll
    for (int m = 0; m < 4; ++m) af[m]  = ld8(As + (wm + m * 16 + li) * 32 + g * 8);
#pragma unroll
    for (int n = 0; n < NF; ++n) bfm[n] = ld8(Bs + (wn + n * 16 + li) * 32 + g * 8);
#pragma unroll
    for (int m = 0; m < 4; ++m)
#pragma unroll
      for (int n = 0; n < NF; ++n)
        acc[m][n] = mfma16(af[m], bfm[n], acc[m][n]);
  }
#pragma unroll
  for (int m = 0; m < 4; ++m)
#pragma unroll
    for (int n = 0; n < NF; ++n) {
      int row = tm + wm + m * 16 + g * 4;
      int col = tn + wn + n * 16 + li;
#pragma unroll
      for (int r = 0; r < 4; ++r) {
        float v = acc[m][n][r];
        if (OUT_BF16) ((u16*)Cv)[(size_t)(row + r) * Ncols + col] = f2bf(v);
        else          ((float*)Cv)[(size_t)(row + r) * Ncols + col] = v;
      }
    }
}

// ------------- RMS qk-norm (vectorized): Cq -> q,k bf16 [b,h,n,d] ----------
__global__ __launch_bounds__(256) void k_rms_qk(const u16* __restrict__ Cq,
                                                const float* __restrict__ gq,
                                                const float* __restrict__ gk,
                                                u16* __restrict__ qo,
                                                u16* __restrict__ ko) {
  int gid = blockIdx.x * 32 + (threadIdx.x >> 3);   // 0..131071 row-head id
  int sub = threadIdx.x & 7;
  int hh  = gid & 31;           // 0-15: q heads, 16-31: k heads
  int row = gid >> 5;           // 0..4095
  int b = row >> 11, n = row & 2047;
  bool isq = hh < 16;
  int h = hh & 15;
  int col = (isq ? 0 : 1024) + h * 64 + sub * 8;
  short8 v8 = ld8(Cq + (size_t)row * E3_ + col);
  float f[8], ss = 0.f;
#pragma unroll
  for (int j = 0; j < 8; ++j) { f[j] = bf2f((u16)v8[j]); ss += f[j] * f[j]; }
  ss += __shfl_xor(ss, 1);
  ss += __shfl_xor(ss, 2);
  ss += __shfl_xor(ss, 4);
  float scale = 8.0f / fmaxf(sqrtf(ss), 1e-12f);   // sqrt(64)=8
  const float* gam = (isq ? gq : gk) + h * 64 + sub * 8;
  ushort4 o0, o1;
  o0.x = f2bf(f[0] * scale * gam[0]); o0.y = f2bf(f[1] * scale * gam[1]);
  o0.z = f2bf(f[2] * scale * gam[2]); o0.w = f2bf(f[3] * scale * gam[3]);
  o1.x = f2bf(f[4] * scale * gam[4]); o1.y = f2bf(f[5] * scale * gam[5]);
  o1.z = f2bf(f[6] * scale * gam[6]); o1.w = f2bf(f[7] * scale * gam[7]);
  u16* dst = (isq ? qo : ko) + (((size_t)(b * H_ + h)) * N_ + n) * 64 + sub * 8;
  *(ushort4*)dst = o0;
  *(ushort4*)(dst + 4) = o1;
}

// ------------- V relayout (identity cols): -> vT [b*h][d][n] ---------------
__global__ __launch_bounds__(256) void k_vt(const u16* __restrict__ Cq,
                                            u16* __restrict__ vT) {
  __shared__ float tile[64][65];
  int bh = blockIdx.y;
  int b = bh >> 4, h = bh & 15;
  int n0 = blockIdx.x * 64;
  int tx = threadIdx.x, ty = threadIdx.y;
  for (int i = 0; i < 64; i += 4) {
    int n = n0 + ty + i;
    tile[ty + i][tx] = bf2f(Cq[((size_t)(b * N_ + n)) * E3_ + 2048 + h * 64 + tx]);
  }
  __syncthreads();
  u16* dst = vT + (size_t)bh * 64 * N_;
  for (int i = 0; i < 64; i += 4) {
    int d = ty + i;
    dst[(size_t)d * N_ + n0 + tx] = f2bf(tile[tx][d]);
  }
}

// ------------- flash attention: R12-exact + bias-from-global ONLY ----------
// BISECTION round 3: R15 proved skip-rescale alone NaNs (dropped forever;
// rescale below is R12's unconditional form, verbatim). This round tests
// the OTHER R14 change alone: bias_s LDS buffer removed -> LDS 40->32KB.
// R12 measured Occupancy 18.9% = 3 blocks/CU; at 32KB, 5 blocks/CU fit
// exactly (5x32=160KB), attacking the R12-diagnosed overlap limit. Bias is
// read per-tile from the L2-resident 16KB array: 4 broadcast float4 loads
// (16 lanes share each address), latency covered by TLP.
__global__ __launch_bounds__(128, 2) void k_attn(const u16* __restrict__ Q,
                                                 const u16* __restrict__ K,
                                                 const u16* __restrict__ Vt,
                                                 const float* __restrict__ bias,
                                                 u16* __restrict__ Out) {
  __shared__ u16 Ks[2][4096];           // 16 KB
  __shared__ u16 Vs[2][4096];           // 16 KB
  int wg = blockIdx.x;
  int xcd = wg & 7, slot = wg >> 3;
  int bh = xcd * 4 + (slot & 3);        // bijective: 8 xcd x 4 bh x 32 qb
  int qb = (slot >> 2) * 64;
  int b = bh >> 4, h = bh & 15;
  int tid = threadIdx.x, wave = tid >> 6, lane = tid & 63;
  int g = lane >> 4, li = lane & 15;
  const u16* Qh = Q  + (size_t)bh * N_ * 64;
  const u16* Kh = K  + (size_t)bh * N_ * 64;
  const u16* Vh = Vt + (size_t)bh * 64 * N_;
  const float* bg = bias + b * N_;

  // staging addresses: 4 chunks of 16B per tile per thread
  u32 Ls[4], kS[4], vR[4], vC[4];
#pragma unroll
  for (int s = 0; s < 4; ++s) {
    Ls[s] = tid * 16 + s * 2048;
    kS[s] = swzb(Ls[s]) >> 1;
    vR[s] = Ls[s] >> 7;
    vC[s] = (swzb(Ls[s]) & 127) >> 1;
  }

  int qr0 = qb + wave * 32 + li;        // q-subgroup A
  int qr1 = qr0 + 16;                   // q-subgroup B
  short8 aqA0 = ld8(Qh + (size_t)qr0 * 64 + g * 8);
  short8 aqA1 = ld8(Qh + (size_t)qr0 * 64 + 32 + g * 8);
  short8 aqB0 = ld8(Qh + (size_t)qr1 * 64 + g * 8);
  short8 aqB1 = ld8(Qh + (size_t)qr1 * 64 + 32 + g * 8);

  f32x4 oTA[4], oTB[4];
#pragma unroll
  for (int dc = 0; dc < 4; ++dc) {
    oTA[dc] = (f32x4){0.f, 0.f, 0.f, 0.f};
    oTB[dc] = (f32x4){0.f, 0.f, 0.f, 0.f};
  }
  float mA = -3e38f, lA = 0.f, mB = -3e38f, lB = 0.f;

  const int fsw  = 8 * (g ^ (li & 7));
  const int fsw2 = fsw ^ 32;
  const int vbl = li * 64 + (g & 1) * 4;
  int vsw[4];
#pragma unroll
  for (int c = 0; c < 4; ++c)
    vsw[c] = (((2 * c + (g >> 1)) ^ (li & 7)) << 3);

  // prologue: stage tile 0 into buffer 0
#pragma unroll
  for (int s = 0; s < 4; ++s) {
    lds16(Kh + kS[s], &Ks[0][0] + (Ls[s] >> 1));
    lds16(Vh + (size_t)vR[s] * N_ + vC[s], &Vs[0][0] + (Ls[s] >> 1));
  }
  __syncthreads();

  for (int kt = 0; kt < 32; ++kt) {
    int cur = kt & 1;
    int kbase = kt * 64;
    if (kt < 31) {                       // stage next tile (async, no regs)
      int nxt = cur ^ 1;
      int nb = kbase + 64;
#pragma unroll
      for (int s = 0; s < 4; ++s) {
        lds16(Kh + (size_t)nb * 64 + kS[s], &Ks[nxt][0] + (Ls[s] >> 1));
        lds16(Vh + (size_t)vR[s] * N_ + nb + vC[s], &Vs[nxt][0] + (Ls[s] >> 1));
      }
    }
    // bias for current tile: 4x broadcast float4 from L2-resident global
    float4 bbc[4];
#pragma unroll
    for (int c = 0; c < 4; ++c)
      bbc[c] = *(const float4*)&bg[kbase + c * 16 + g * 4];
    const u16* Kb = &Ks[cur][0];
    const u16* Vb = &Vs[cur][0];
    // ---- S^T = mfma(K, Q, C=bias) for both q-groups (K-frags shared) ----
    f32x4 stA[4], stB[4];
    __builtin_amdgcn_s_setprio(1);
#pragma unroll
    for (int c = 0; c < 4; ++c) {
      int rb = (c * 16 + li) * 64;
      short8 kf0 = ld8(Kb + rb + fsw);
      short8 kf1 = ld8(Kb + rb + fsw2);
      f32x4 z = (f32x4){bbc[c].x, bbc[c].y, bbc[c].z, bbc[c].w};
      stA[c] = mfma16(kf1, aqA1, mfma16(kf0, aqA0, z));
      stB[c] = mfma16(kf1, aqB1, mfma16(kf0, aqB0, z));
    }
    __builtin_amdgcn_s_setprio(0);
    // ---- V-frags (b64 reads), shared by both q-groups -------------------
    short4v vf16[4][4];
#pragma unroll
    for (int dc = 0; dc < 4; ++dc)
#pragma unroll
      for (int c = 0; c < 4; ++c)
        vf16[dc][c] = *(const short4v*)(Vb + dc * 1024 + vbl + vsw[c]);
    // ---- softmax group A (R12 unconditional form, verbatim) -------------
    float cmA[4];
#pragma unroll
    for (int c = 0; c < 4; ++c)
      cmA[c] = fmaxf(fmaxf(stA[c][0], stA[c][1]), fmaxf(stA[c][2], stA[c][3]));
    float tmaxA = fmaxf(fmaxf(cmA[0], cmA[1]), fmaxf(cmA[2], cmA[3]));
    tmaxA = fmaxf(tmaxA, __shfl_xor(tmaxA, 16));
    tmaxA = fmaxf(tmaxA, __shfl_xor(tmaxA, 32));
    float mnA = fmaxf(mA, tmaxA);
    float scA = __expf(mA - mnA);
    mA = mnA;
    float pvA[4][4], csA[4];
#pragma unroll
    for (int c = 0; c < 4; ++c) {
#pragma unroll
      for (int r = 0; r < 4; ++r) pvA[c][r] = __expf(stA[c][r] - mnA);
      csA[c] = (pvA[c][0] + pvA[c][1]) + (pvA[c][2] + pvA[c][3]);
    }
    float rsA = (csA[0] + csA[1]) + (csA[2] + csA[3]);
    rsA += __shfl_xor(rsA, 16);
    rsA += __shfl_xor(rsA, 32);
    lA = lA * scA + rsA;
#pragma unroll
    for (int dc = 0; dc < 4; ++dc) oTA[dc] *= scA;
    // ---- softmax group B -------------------------------------------------
    float cmB[4];
#pragma unroll
    for (int c = 0; c < 4; ++c)
      cmB[c] = fmaxf(fmaxf(stB[c][0], stB[c][1]), fmaxf(stB[c][2], stB[c][3]));
    float tmaxB = fmaxf(fmaxf(cmB[0], cmB[1]), fmaxf(cmB[2], cmB[3]));
    tmaxB = fmaxf(tmaxB, __shfl_xor(tmaxB, 16));
    tmaxB = fmaxf(tmaxB, __shfl_xor(tmaxB, 32));
    float mnB = fmaxf(mB, tmaxB);
    float scB = __expf(mB - mnB);
    mB = mnB;
    float pvB[4][4], csB[4];
#pragma unroll
    for (int c = 0; c < 4; ++c) {
#pragma unroll
      for (int r = 0; r < 4; ++r) pvB[c][r] = __expf(stB[c][r] - mnB);
      csB[c] = (pvB[c][0] + pvB[c][1]) + (pvB[c][2] + pvB[c][3]);
    }
    float rsB = (csB[0] + csB[1]) + (csB[2] + csB[3]);
    rsB += __shfl_xor(rsB, 16);
    rsB += __shfl_xor(rsB, 32);
    lB = lB * scB + rsB;
#pragma unroll
    for (int dc = 0; dc < 4; ++dc) oTB[dc] *= scB;
    // ---- pack P (both groups) via v_cvt_pk_bf16_f32 ----------------------
    union { u32 u2[2]; short4v s4; } pbA[4], pbB[4];
#pragma unroll
    for (int c = 0; c < 4; ++c) {
      asm("v_cvt_pk_bf16_f32 %0, %1, %2" : "=v"(pbA[c].u2[0]) : "v"(pvA[c][0]), "v"(pvA[c][1]));
      asm("v_cvt_pk_bf16_f32 %0, %1, %2" : "=v"(pbA[c].u2[1]) : "v"(pvA[c][2]), "v"(pvA[c][3]));
      asm("v_cvt_pk_bf16_f32 %0, %1, %2" : "=v"(pbB[c].u2[0]) : "v"(pvB[c][0]), "v"(pvB[c][1]));
      asm("v_cvt_pk_bf16_f32 %0, %1, %2" : "=v"(pbB[c].u2[1]) : "v"(pvB[c][2]), "v"(pvB[c][3]));
    }
    // ---- PV: V-frag (A operand) shared, B operand per q-group -----------
    __builtin_amdgcn_s_setprio(1);
#pragma unroll
    for (int dc = 0; dc < 4; ++dc)
#pragma unroll
      for (int c = 0; c < 4; ++c) {
        oTA[dc] = mfma16k16(vf16[dc][c], pbA[c].s4, oTA[dc]);
        oTB[dc] = mfma16k16(vf16[dc][c], pbB[c].s4, oTB[dc]);
      }
    __builtin_amdgcn_s_setprio(0);
    __syncthreads();                    // next-tile staging complete + buf free
  }

  float invA = 1.0f / lA, invB = 1.0f / lB;
#pragma unroll
  for (int dc = 0; dc < 4; ++dc) {
    ushort4 ovA, ovB;
    ovA.x = f2bf(oTA[dc][0] * invA); ovA.y = f2bf(oTA[dc][1] * invA);
    ovA.z = f2bf(oTA[dc][2] * invA); ovA.w = f2bf(oTA[dc][3] * invA);
    ovB.x = f2bf(oTB[dc][0] * invB); ovB.y = f2bf(oTB[dc][1] * invB);
    ovB.z = f2bf(oTB[dc][2] * invB); ovB.w = f2bf(oTB[dc][3] * invB);
    *(ushort4*)&Out[((size_t)(b * N_ + qr0)) * DIM_ + h * 64 + dc * 16 + g * 4] = ovA;
    *(ushort4*)&Out[((size_t)(b * N_ + qr1)) * DIM_ + h * 64 + dc * 16 + g * 4] = ovB;
  }
}

// ---------------------------------------------------------------------------
extern "C" void kernel_launch(void* const* d_in, const int* in_sizes, int n_in,
                              void* d_out, int out_size, void* d_ws, size_t ws_size,
                              hipStream_t stream) {
  const float* x    = (const float*)d_in[0];
  const int*   mask = (const int*)d_in[1];
  const float* g_ln = (const float*)d_in[2];
  const float* g_q  = (const float*)d_in[3];
  const float* g_k  = (const float*)d_in[4];
  const float* Wq   = (const float*)d_in[5];
  const float* Wkv  = (const float*)d_in[6];
  const float* Wo   = (const float*)d_in[7];
  float* out = (float*)d_out;

  char* ws = (char*)d_ws;
  u16*   xn   = (u16*)(ws);                         // 8 MB
  u16*   Wt   = (u16*)(ws + 8388608);               // 6 MB  (Wq^T | Wkv^T) [3072][1024]
  u16*   Wot  = (u16*)(ws + 14680064);              // 2 MB  Wo^T [1024][1024]
  float* bias = (float*)(ws + 16777216);            // 16 KB
  u16*   Cq   = (u16*)(ws + 16793600);              // 24 MB [4096][3072]
  u16*   qb   = (u16*)(ws + 41959424);              // 8 MB [b,h,n,d]
  u16*   kb   = (u16*)(ws + 41959424 + 8388608);    // 8 MB
  u16*   vT   = (u16*)(ws + 41959424 + 2*8388608);  // 8 MB [b*h][d][n]
  u16*   ao   = (u16*)(ws + 41959424 + 3*8388608);  // 8 MB [4096][1024]

  k_layernorm<<<ROWS_, 256, 0, stream>>>(x, g_ln, xn);
  k_tcast_all<<<dim3(128, 32), dim3(32, 8), 0, stream>>>(Wq, Wkv, Wo, Wt, Wot);
  k_mask<<<8, 1024, 0, stream>>>(mask, bias);
  k_gemm_bt<4, true><<<dim3(32, 24), 256, 0, stream>>>(xn, Wt, Cq, ROWS_, E3_, DIM_);
  k_rms_qk<<<4096, 256, 0, stream>>>(Cq, g_q, g_k, qb, kb);
  k_vt<<<dim3(32, 32), dim3(64, 4), 0, stream>>>(Cq, vT);
  k_attn<<<1024, 128, 0, stream>>>(qb, kb, vT, bias, ao);
  k_gemm_bt<2, false><<<dim3(32, 16), 256, 0, stream>>>(ao, Wot, out, ROWS_, DIM_, DIM_);
}

// Round 17
// 156.770 us; speedup vs baseline: 2.1326x; 1.0176x over previous
//
#include <hip/hip_runtime.h>

using u16 = unsigned short;
using u32 = unsigned int;

#define B_   2
#define N_   2048
#define DIM_ 1024
#define H_   16
#define D_   64
#define ROWS_ (B_*N_)   // 4096
#define E3_  3072       // q|k|v concatenated

typedef __attribute__((ext_vector_type(8))) short short8;
typedef __attribute__((ext_vector_type(4))) short short4v;
typedef __attribute__((ext_vector_type(4))) float f32x4;

__device__ __forceinline__ u16 f2bf(float f) {
  u32 u = __builtin_bit_cast(u32, f);
  u32 r = (u + 0x7FFFu + ((u >> 16) & 1u)) >> 16;
  return (u16)r;
}
__device__ __forceinline__ float bf2f(u16 h) {
  u32 u = ((u32)h) << 16;
  return __builtin_bit_cast(float, u);
}
__device__ __forceinline__ short8 ld8(const u16* p) { return *(const short8*)p; }
__device__ __forceinline__ f32x4 mfma16(short8 a, short8 b, f32x4 c) {
  return __builtin_amdgcn_mfma_f32_16x16x32_bf16(a, b, c, 0, 0, 0);
}
// K=16 bf16 MFMA (R9-verified): B[k=g*4+j][col=li] == softmax's in-lane P.
__device__ __forceinline__ f32x4 mfma16k16(short4v a, short4v b, f32x4 c) {
#if !defined(__HIP_DEVICE_COMPILE__)
  (void)a; (void)b;
  return c;
#elif __has_builtin(__builtin_amdgcn_mfma_f32_16x16x16bf16_1k)
  return __builtin_amdgcn_mfma_f32_16x16x16bf16_1k(a, b, c, 0, 0, 0);
#else
  short8 a8 = (short8){a[0], a[1], a[2], a[3], 0, 0, 0, 0};
  short8 b8 = (short8){b[0], b[1], b[2], b[3], 0, 0, 0, 0};
  return __builtin_amdgcn_mfma_f32_16x16x32_bf16(a8, b8, c, 0, 0, 0);
#endif
}
__device__ __forceinline__ void lds16(const u16* g, u16* l) {
  __builtin_amdgcn_global_load_lds(
      (const __attribute__((address_space(1))) void*)g,
      (__attribute__((address_space(3))) void*)l, 16, 0, 0);
}
// byte-level XOR swizzle: flips bits 4-6 (16B chunk idx) by row&7; involution.
__device__ __forceinline__ u32 swzb(u32 L) { return L ^ (((L >> 7) & 7) << 4); }

// ---------------- LayerNorm: x fp32 [4096][1024] -> xn bf16 ----------------
__global__ __launch_bounds__(256) void k_layernorm(const float* __restrict__ x,
                                                   const float* __restrict__ gamma,
                                                   u16* __restrict__ xn) {
  int row = blockIdx.x, tid = threadIdx.x;
  const float4 xv = *(const float4*)(x + (size_t)row * DIM_ + tid * 4);
  float s = xv.x + xv.y + xv.z + xv.w;
  float q = xv.x*xv.x + xv.y*xv.y + xv.z*xv.z + xv.w*xv.w;
  for (int off = 32; off; off >>= 1) { s += __shfl_xor(s, off); q += __shfl_xor(q, off); }
  __shared__ float red[8];
  int wave = tid >> 6, lane = tid & 63;
  if (lane == 0) { red[wave] = s; red[4 + wave] = q; }
  __syncthreads();
  s = red[0] + red[1] + red[2] + red[3];
  q = red[4] + red[5] + red[6] + red[7];
  float mu  = s * (1.0f / DIM_);
  float var = q * (1.0f / DIM_) - mu * mu;
  float inv = rsqrtf(var + 1e-5f);
  const float4 gv = *(const float4*)(gamma + tid * 4);
  ushort4 ov;
  ov.x = f2bf((xv.x - mu) * inv * gv.x);
  ov.y = f2bf((xv.y - mu) * inv * gv.y);
  ov.z = f2bf((xv.z - mu) * inv * gv.z);
  ov.w = f2bf((xv.w - mu) * inv * gv.w);
  *(ushort4*)(xn + (size_t)row * DIM_ + tid * 4) = ov;
}

// ---- transpose+cast, all 3 weights in one launch --------------------------
__global__ __launch_bounds__(256) void k_tcast_all(const float* __restrict__ Wq,
                                                   const float* __restrict__ Wkv,
                                                   const float* __restrict__ Wo,
                                                   u16* __restrict__ Wt,
                                                   u16* __restrict__ Wot) {
  __shared__ float tile[32][33];
  int bx = blockIdx.x;
  const float* in; u16* out; int ncols, cb;
  if (bx < 32)      { in = Wq;  out = Wt;               ncols = 1024; cb = bx; }
  else if (bx < 96) { in = Wkv; out = Wt + 1024 * 1024; ncols = 2048; cb = bx - 32; }
  else              { in = Wo;  out = Wot;              ncols = 1024; cb = bx - 96; }
  int tx = threadIdx.x, ty = threadIdx.y;
  int col  = cb * 32 + tx;
  int row0 = blockIdx.y * 32;
  for (int j = 0; j < 32; j += 8)
    tile[ty + j][tx] = in[(size_t)(row0 + ty + j) * ncols + col];
  __syncthreads();
  int orow = cb * 32 + ty;
  int ocol = row0 + tx;
  for (int j = 0; j < 32; j += 8)
    out[(size_t)(orow + j) * DIM_ + ocol] = f2bf(tile[tx][ty + j]);
}

// ------------- mask decode with dtype auto-detect -> additive bias ---------
__global__ void k_mask(const int* __restrict__ mraw, float* __restrict__ bias) {
  __shared__ int flag;
  int tid = threadIdx.x;
  if (tid == 0) flag = 0;
  __syncthreads();
  int v = mraw[tid];                 // 1024 ints: safe under bool(4096B) or int32(16384B)
  if (v != 0 && v != 1) atomicOr(&flag, 1);
  __syncthreads();
  bool bytemode = (flag != 0);
  const unsigned char* mb = (const unsigned char*)mraw;
  if (tid < 512) {
    int j = blockIdx.x * 512 + tid;
    bool valid = bytemode ? (mb[j] != 0) : (mraw[j] != 0);
    bias[j] = valid ? 0.0f : -1e30f;
  }
}

// ------------- GEMM C = A @ Bt^T, optionally fused RMS qk-norm -------------
// FUSE (QKV GEMM only; tested ALONE this round -- R13 bundled it with the
// proven-poison skip-rescale): a wave's 64 output cols are exactly one head
// of q/k/v (tn mult of 128, wn in {0,64}; region bounds 1024/2048 are
// tile-aligned). q/k: per row (= g*4+r), sum_d x^2 = in-lane sum over n +
// shfl_xor 1/2/4/8 (within the 16-lane li-group, g fixed); write qb/kb
// directly from fp32 (better numerics than the old bf16 roundtrip). V cols
// write Cq as before (consumed by k_vt). No conditional accumulator writes,
// no per-lane/VMEM-LDS mixing -- structurally unlike the R15 poison.
template <int NF, bool OUT_BF16, bool FUSE>
__global__ __launch_bounds__(256) void k_gemm_bt(const u16* __restrict__ A,
                                                 const u16* __restrict__ Bt,
                                                 void* __restrict__ Cv,
                                                 const float* __restrict__ gq,
                                                 const float* __restrict__ gk,
                                                 u16* __restrict__ qo,
                                                 u16* __restrict__ ko,
                                                 int M, int Ncols, int K) {
  constexpr int BN = NF * 32;
  __shared__ u16 As[128 * 32];
  __shared__ u16 Bs[BN * 32];
  const int tid = threadIdx.x;
  const int wave = tid >> 6, lane = tid & 63;
  const int g = lane >> 4, li = lane & 15;
  const int gx = gridDim.x;
  const int wg = blockIdx.y * gx + blockIdx.x;
  const int per = (gx * gridDim.y) >> 3;
  const int swz = (wg & 7) * per + (wg >> 3);
  const int tm = (swz % gx) * 128, tn = (swz / gx) * BN;
  const int wm = (wave >> 1) * 64, wn = (wave & 1) * (NF * 16);
  const int srow = wave * 16 + (lane >> 2);
  const int scol = (lane & 3) * 8;

  f32x4 acc[4][NF];
#pragma unroll
  for (int i = 0; i < 4; ++i)
#pragma unroll
    for (int j = 0; j < NF; ++j) acc[i][j] = (f32x4){0.f, 0.f, 0.f, 0.f};

  const u16* ag = A  + (size_t)(tm + srow) * K + scol;
  const u16* bg = Bt + (size_t)(tn + srow) * K + scol;

  for (int k0 = 0; k0 < K; k0 += 32) {
    __syncthreads();
#pragma unroll
    for (int p = 0; p < 2; ++p)
      lds16(ag + (size_t)p * 64 * K + k0, As + p * 2048 + wave * 512);
#pragma unroll
    for (int p = 0; p < NF / 2; ++p)
      lds16(bg + (size_t)p * 64 * K + k0, Bs + p * 2048 + wave * 512);
    __syncthreads();
    short8 af[4], bfm[NF];
#pragma unroll
    for (int m = 0; m < 4; ++m) af[m]  = ld8(As + (wm + m * 16 + li) * 32 + g * 8);
#pragma unroll
    for (int n = 0; n < NF; ++n) bfm[n] = ld8(Bs + (wn + n * 16 + li) * 32 + g * 8);
#pragma unroll
    for (int m = 0; m < 4; ++m)
#pragma unroll
      for (int n = 0; n < NF; ++n)
        acc[m][n] = mfma16(af[m], bfm[n], acc[m][n]);
  }

  if constexpr (FUSE) {
    const int colbase = tn + wn;          // multiple of 64 (wave-uniform)
    const int region = colbase >> 10;     // 0=q 1=k 2=v
    if (region < 2) {
      const int h = (colbase & 1023) >> 6;
      const float* gam = (region == 0) ? gq : gk;
      u16* dst = (region == 0) ? qo : ko;
#pragma unroll
      for (int m = 0; m < 4; ++m)
#pragma unroll
        for (int r = 0; r < 4; ++r) {
          float ss = 0.f;
#pragma unroll
          for (int n = 0; n < NF; ++n) ss += acc[m][n][r] * acc[m][n][r];
          ss += __shfl_xor(ss, 1);
          ss += __shfl_xor(ss, 2);
          ss += __shfl_xor(ss, 4);
          ss += __shfl_xor(ss, 8);
          float scale = 8.0f / fmaxf(sqrtf(ss), 1e-12f);   // sqrt(64)=8
          int row = tm + wm + m * 16 + g * 4 + r;
          int bb = row >> 11, nn = row & 2047;
          u16* drow = dst + (((size_t)(bb * H_ + h)) * N_ + nn) * 64;
#pragma unroll
          for (int n = 0; n < NF; ++n) {
            int d = n * 16 + li;
            drow[d] = f2bf(acc[m][n][r] * scale * gam[h * 64 + d]);
          }
        }
      return;
    }
    // V columns: bf16 into Cq (layout unchanged, consumed by k_vt)
#pragma unroll
    for (int m = 0; m < 4; ++m)
#pragma unroll
      for (int n = 0; n < NF; ++n) {
        int row = tm + wm + m * 16 + g * 4;
        int col = tn + wn + n * 16 + li;
#pragma unroll
        for (int r = 0; r < 4; ++r)
          ((u16*)Cv)[(size_t)(row + r) * Ncols + col] = f2bf(acc[m][n][r]);
      }
    return;
  }

#pragma unroll
  for (int m = 0; m < 4; ++m)
#pragma unroll
    for (int n = 0; n < NF; ++n) {
      int row = tm + wm + m * 16 + g * 4;
      int col = tn + wn + n * 16 + li;
#pragma unroll
      for (int r = 0; r < 4; ++r) {
        float v = acc[m][n][r];
        if (OUT_BF16) ((u16*)Cv)[(size_t)(row + r) * Ncols + col] = f2bf(v);
        else          ((float*)Cv)[(size_t)(row + r) * Ncols + col] = v;
      }
    }
}

// ------------- V relayout (identity cols): -> vT [b*h][d][n] ---------------
__global__ __launch_bounds__(256) void k_vt(const u16* __restrict__ Cq,
                                            u16* __restrict__ vT) {
  __shared__ float tile[64][65];
  int bh = blockIdx.y;
  int b = bh >> 4, h = bh & 15;
  int n0 = blockIdx.x * 64;
  int tx = threadIdx.x, ty = threadIdx.y;
  for (int i = 0; i < 64; i += 4) {
    int n = n0 + ty + i;
    tile[ty + i][tx] = bf2f(Cq[((size_t)(b * N_ + n)) * E3_ + 2048 + h * 64 + tx]);
  }
  __syncthreads();
  u16* dst = vT + (size_t)bh * 64 * N_;
  for (int i = 0; i < 64; i += 4) {
    int d = ty + i;
    dst[(size_t)d * N_ + n0 + tx] = f2bf(tile[tx][d]);
  }
}

// ------------- flash attention: R16-exact (passing, 81.7us) ----------------
__global__ __launch_bounds__(128, 2) void k_attn(const u16* __restrict__ Q,
                                                 const u16* __restrict__ K,
                                                 const u16* __restrict__ Vt,
                                                 const float* __restrict__ bias,
                                                 u16* __restrict__ Out) {
  __shared__ u16 Ks[2][4096];           // 16 KB
  __shared__ u16 Vs[2][4096];           // 16 KB
  int wg = blockIdx.x;
  int xcd = wg & 7, slot = wg >> 3;
  int bh = xcd * 4 + (slot & 3);        // bijective: 8 xcd x 4 bh x 32 qb
  int qb = (slot >> 2) * 64;
  int b = bh >> 4, h = bh & 15;
  int tid = threadIdx.x, wave = tid >> 6, lane = tid & 63;
  int g = lane >> 4, li = lane & 15;
  const u16* Qh = Q  + (size_t)bh * N_ * 64;
  const u16* Kh = K  + (size_t)bh * N_ * 64;
  const u16* Vh = Vt + (size_t)bh * 64 * N_;
  const float* bg = bias + b * N_;

  // staging addresses: 4 chunks of 16B per tile per thread
  u32 Ls[4], kS[4], vR[4], vC[4];
#pragma unroll
  for (int s = 0; s < 4; ++s) {
    Ls[s] = tid * 16 + s * 2048;
    kS[s] = swzb(Ls[s]) >> 1;
    vR[s] = Ls[s] >> 7;
    vC[s] = (swzb(Ls[s]) & 127) >> 1;
  }

  int qr0 = qb + wave * 32 + li;        // q-subgroup A
  int qr1 = qr0 + 16;                   // q-subgroup B
  short8 aqA0 = ld8(Qh + (size_t)qr0 * 64 + g * 8);
  short8 aqA1 = ld8(Qh + (size_t)qr0 * 64 + 32 + g * 8);
  short8 aqB0 = ld8(Qh + (size_t)qr1 * 64 + g * 8);
  short8 aqB1 = ld8(Qh + (size_t)qr1 * 64 + 32 + g * 8);

  f32x4 oTA[4], oTB[4];
#pragma unroll
  for (int dc = 0; dc < 4; ++dc) {
    oTA[dc] = (f32x4){0.f, 0.f, 0.f, 0.f};
    oTB[dc] = (f32x4){0.f, 0.f, 0.f, 0.f};
  }
  float mA = -3e38f, lA = 0.f, mB = -3e38f, lB = 0.f;

  const int fsw  = 8 * (g ^ (li & 7));
  const int fsw2 = fsw ^ 32;
  const int vbl = li * 64 + (g & 1) * 4;
  int vsw[4];
#pragma unroll
  for (int c = 0; c < 4; ++c)
    vsw[c] = (((2 * c + (g >> 1)) ^ (li & 7)) << 3);

  // prologue: stage tile 0 into buffer 0
#pragma unroll
  for (int s = 0; s < 4; ++s) {
    lds16(Kh + kS[s], &Ks[0][0] + (Ls[s] >> 1));
    lds16(Vh + (size_t)vR[s] * N_ + vC[s], &Vs[0][0] + (Ls[s] >> 1));
  }
  __syncthreads();

  for (int kt = 0; kt < 32; ++kt) {
    int cur = kt & 1;
    int kbase = kt * 64;
    if (kt < 31) {                       // stage next tile (async, no regs)
      int nxt = cur ^ 1;
      int nb = kbase + 64;
#pragma unroll
      for (int s = 0; s < 4; ++s) {
        lds16(Kh + (size_t)nb * 64 + kS[s], &Ks[nxt][0] + (Ls[s] >> 1));
        lds16(Vh + (size_t)vR[s] * N_ + nb + vC[s], &Vs[nxt][0] + (Ls[s] >> 1));
      }
    }
    // bias for current tile: 4x broadcast float4 from L2-resident global
    float4 bbc[4];
#pragma unroll
    for (int c = 0; c < 4; ++c)
      bbc[c] = *(const float4*)&bg[kbase + c * 16 + g * 4];
    const u16* Kb = &Ks[cur][0];
    const u16* Vb = &Vs[cur][0];
    // ---- S^T = mfma(K, Q, C=bias) for both q-groups (K-frags shared) ----
    f32x4 stA[4], stB[4];
    __builtin_amdgcn_s_setprio(1);
#pragma unroll
    for (int c = 0; c < 4; ++c) {
      int rb = (c * 16 + li) * 64;
      short8 kf0 = ld8(Kb + rb + fsw);
      short8 kf1 = ld8(Kb + rb + fsw2);
      f32x4 z = (f32x4){bbc[c].x, bbc[c].y, bbc[c].z, bbc[c].w};
      stA[c] = mfma16(kf1, aqA1, mfma16(kf0, aqA0, z));
      stB[c] = mfma16(kf1, aqB1, mfma16(kf0, aqB0, z));
    }
    __builtin_amdgcn_s_setprio(0);
    // ---- V-frags (b64 reads), shared by both q-groups -------------------
    short4v vf16[4][4];
#pragma unroll
    for (int dc = 0; dc < 4; ++dc)
#pragma unroll
      for (int c = 0; c < 4; ++c)
        vf16[dc][c] = *(const short4v*)(Vb + dc * 1024 + vbl + vsw[c]);
    // ---- softmax group A (unconditional) --------------------------------
    float cmA[4];
#pragma unroll
    for (int c = 0; c < 4; ++c)
      cmA[c] = fmaxf(fmaxf(stA[c][0], stA[c][1]), fmaxf(stA[c][2], stA[c][3]));
    float tmaxA = fmaxf(fmaxf(cmA[0], cmA[1]), fmaxf(cmA[2], cmA[3]));
    tmaxA = fmaxf(tmaxA, __shfl_xor(tmaxA, 16));
    tmaxA = fmaxf(tmaxA, __shfl_xor(tmaxA, 32));
    float mnA = fmaxf(mA, tmaxA);
    float scA = __expf(mA - mnA);
    mA = mnA;
    float pvA[4][4], csA[4];
#pragma unroll
    for (int c = 0; c < 4; ++c) {
#pragma unroll
      for (int r = 0; r < 4; ++r) pvA[c][r] = __expf(stA[c][r] - mnA);
      csA[c] = (pvA[c][0] + pvA[c][1]) + (pvA[c][2] + pvA[c][3]);
    }
    float rsA = (csA[0] + csA[1]) + (csA[2] + csA[3]);
    rsA += __shfl_xor(rsA, 16);
    rsA += __shfl_xor(rsA, 32);
    lA = lA * scA + rsA;
#pragma unroll
    for (int dc = 0; dc < 4; ++dc) oTA[dc] *= scA;
    // ---- softmax group B -------------------------------------------------
    float cmB[4];
#pragma unroll
    for (int c = 0; c < 4; ++c)
      cmB[c] = fmaxf(fmaxf(stB[c][0], stB[c][1]), fmaxf(stB[c][2], stB[c][3]));
    float tmaxB = fmaxf(fmaxf(cmB[0], cmB[1]), fmaxf(cmB[2], cmB[3]));
    tmaxB = fmaxf(tmaxB, __shfl_xor(tmaxB, 16));
    tmaxB = fmaxf(tmaxB, __shfl_xor(tmaxB, 32));
    float mnB = fmaxf(mB, tmaxB);
    float scB = __expf(mB - mnB);
    mB = mnB;
    float pvB[4][4], csB[4];
#pragma unroll
    for (int c = 0; c < 4; ++c) {
#pragma unroll
      for (int r = 0; r < 4; ++r) pvB[c][r] = __expf(stB[c][r] - mnB);
      csB[c] = (pvB[c][0] + pvB[c][1]) + (pvB[c][2] + pvB[c][3]);
    }
    float rsB = (csB[0] + csB[1]) + (csB[2] + csB[3]);
    rsB += __shfl_xor(rsB, 16);
    rsB += __shfl_xor(rsB, 32);
    lB = lB * scB + rsB;
#pragma unroll
    for (int dc = 0; dc < 4; ++dc) oTB[dc] *= scB;
    // ---- pack P (both groups) via v_cvt_pk_bf16_f32 ----------------------
    union { u32 u2[2]; short4v s4; } pbA[4], pbB[4];
#pragma unroll
    for (int c = 0; c < 4; ++c) {
      asm("v_cvt_pk_bf16_f32 %0, %1, %2" : "=v"(pbA[c].u2[0]) : "v"(pvA[c][0]), "v"(pvA[c][1]));
      asm("v_cvt_pk_bf16_f32 %0, %1, %2" : "=v"(pbA[c].u2[1]) : "v"(pvA[c][2]), "v"(pvA[c][3]));
      asm("v_cvt_pk_bf16_f32 %0, %1, %2" : "=v"(pbB[c].u2[0]) : "v"(pvB[c][0]), "v"(pvB[c][1]));
      asm("v_cvt_pk_bf16_f32 %0, %1, %2" : "=v"(pbB[c].u2[1]) : "v"(pvB[c][2]), "v"(pvB[c][3]));
    }
    // ---- PV: V-frag (A operand) shared, B operand per q-group -----------
    __builtin_amdgcn_s_setprio(1);
#pragma unroll
    for (int dc = 0; dc < 4; ++dc)
#pragma unroll
      for (int c = 0; c < 4; ++c) {
        oTA[dc] = mfma16k16(vf16[dc][c], pbA[c].s4, oTA[dc]);
        oTB[dc] = mfma16k16(vf16[dc][c], pbB[c].s4, oTB[dc]);
      }
    __builtin_amdgcn_s_setprio(0);
    __syncthreads();                    // next-tile staging complete + buf free
  }

  float invA = 1.0f / lA, invB = 1.0f / lB;
#pragma unroll
  for (int dc = 0; dc < 4; ++dc) {
    ushort4 ovA, ovB;
    ovA.x = f2bf(oTA[dc][0] * invA); ovA.y = f2bf(oTA[dc][1] * invA);
    ovA.z = f2bf(oTA[dc][2] * invA); ovA.w = f2bf(oTA[dc][3] * invA);
    ovB.x = f2bf(oTB[dc][0] * invB); ovB.y = f2bf(oTB[dc][1] * invB);
    ovB.z = f2bf(oTB[dc][2] * invB); ovB.w = f2bf(oTB[dc][3] * invB);
    *(ushort4*)&Out[((size_t)(b * N_ + qr0)) * DIM_ + h * 64 + dc * 16 + g * 4] = ovA;
    *(ushort4*)&Out[((size_t)(b * N_ + qr1)) * DIM_ + h * 64 + dc * 16 + g * 4] = ovB;
  }
}

// ---------------------------------------------------------------------------
extern "C" void kernel_launch(void* const* d_in, const int* in_sizes, int n_in,
                              void* d_out, int out_size, void* d_ws, size_t ws_size,
                              hipStream_t stream) {
  const float* x    = (const float*)d_in[0];
  const int*   mask = (const int*)d_in[1];
  const float* g_ln = (const float*)d_in[2];
  const float* g_q  = (const float*)d_in[3];
  const float* g_k  = (const float*)d_in[4];
  const float* Wq   = (const float*)d_in[5];
  const float* Wkv  = (const float*)d_in[6];
  const float* Wo   = (const float*)d_in[7];
  float* out = (float*)d_out;

  char* ws = (char*)d_ws;
  u16*   xn   = (u16*)(ws);                         // 8 MB
  u16*   Wt   = (u16*)(ws + 8388608);               // 6 MB  (Wq^T | Wkv^T) [3072][1024]
  u16*   Wot  = (u16*)(ws + 14680064);              // 2 MB  Wo^T [1024][1024]
  float* bias = (float*)(ws + 16777216);            // 16 KB
  u16*   Cq   = (u16*)(ws + 16793600);              // 24 MB [4096][3072] (V third used)
  u16*   qb   = (u16*)(ws + 41959424);              // 8 MB [b,h,n,d]
  u16*   kb   = (u16*)(ws + 41959424 + 8388608);    // 8 MB
  u16*   vT   = (u16*)(ws + 41959424 + 2*8388608);  // 8 MB [b*h][d][n]
  u16*   ao   = (u16*)(ws + 41959424 + 3*8388608);  // 8 MB [4096][1024]

  k_layernorm<<<ROWS_, 256, 0, stream>>>(x, g_ln, xn);
  k_tcast_all<<<dim3(128, 32), dim3(32, 8), 0, stream>>>(Wq, Wkv, Wo, Wt, Wot);
  k_mask<<<8, 1024, 0, stream>>>(mask, bias);
  k_gemm_bt<4, true, true><<<dim3(32, 24), 256, 0, stream>>>(
      xn, Wt, Cq, g_q, g_k, qb, kb, ROWS_, E3_, DIM_);
  k_vt<<<dim3(32, 32), dim3(64, 4), 0, stream>>>(Cq, vT);
  k_attn<<<1024, 128, 0, stream>>>(qb, kb, vT, bias, ao);
  k_gemm_bt<2, false, false><<<dim3(32, 16), 256, 0, stream>>>(
      ao, Wot, out, nullptr, nullptr, nullptr, nullptr, ROWS_, DIM_, DIM_);
}

// Round 18
// 153.523 us; speedup vs baseline: 2.1777x; 1.0212x over previous
//
#include <hip/hip_runtime.h>

using u16 = unsigned short;
using u32 = unsigned int;

#define B_   2
#define N_   2048
#define DIM_ 1024
#define H_   16
#define D_   64
#define ROWS_ (B_*N_)   // 4096
#define E3_  3072       // q|k|v concatenated

typedef __attribute__((ext_vector_type(8))) short short8;
typedef __attribute__((ext_vector_type(4))) short short4v;
typedef __attribute__((ext_vector_type(4))) float f32x4;

__device__ __forceinline__ u16 f2bf(float f) {
  u32 u = __builtin_bit_cast(u32, f);
  u32 r = (u + 0x7FFFu + ((u >> 16) & 1u)) >> 16;
  return (u16)r;
}
__device__ __forceinline__ float bf2f(u16 h) {
  u32 u = ((u32)h) << 16;
  return __builtin_bit_cast(float, u);
}
__device__ __forceinline__ short8 ld8(const u16* p) { return *(const short8*)p; }
__device__ __forceinline__ f32x4 mfma16(short8 a, short8 b, f32x4 c) {
  return __builtin_amdgcn_mfma_f32_16x16x32_bf16(a, b, c, 0, 0, 0);
}
// K=16 bf16 MFMA (R9-verified): B[k=g*4+j][col=li] == softmax's in-lane P.
__device__ __forceinline__ f32x4 mfma16k16(short4v a, short4v b, f32x4 c) {
#if !defined(__HIP_DEVICE_COMPILE__)
  (void)a; (void)b;
  return c;
#elif __has_builtin(__builtin_amdgcn_mfma_f32_16x16x16bf16_1k)
  return __builtin_amdgcn_mfma_f32_16x16x16bf16_1k(a, b, c, 0, 0, 0);
#else
  short8 a8 = (short8){a[0], a[1], a[2], a[3], 0, 0, 0, 0};
  short8 b8 = (short8){b[0], b[1], b[2], b[3], 0, 0, 0, 0};
  return __builtin_amdgcn_mfma_f32_16x16x32_bf16(a8, b8, c, 0, 0, 0);
#endif
}
__device__ __forceinline__ void lds16(const u16* g, u16* l) {
  __builtin_amdgcn_global_load_lds(
      (const __attribute__((address_space(1))) void*)g,
      (__attribute__((address_space(3))) void*)l, 16, 0, 0);
}
// byte-level XOR swizzle: flips bits 4-6 (16B chunk idx) by row&7; involution.
__device__ __forceinline__ u32 swzb(u32 L) { return L ^ (((L >> 7) & 7) << 4); }

// ---------------- LayerNorm: x fp32 [4096][1024] -> xn bf16 ----------------
__global__ __launch_bounds__(256) void k_layernorm(const float* __restrict__ x,
                                                   const float* __restrict__ gamma,
                                                   u16* __restrict__ xn) {
  int row = blockIdx.x, tid = threadIdx.x;
  const float4 xv = *(const float4*)(x + (size_t)row * DIM_ + tid * 4);
  float s = xv.x + xv.y + xv.z + xv.w;
  float q = xv.x*xv.x + xv.y*xv.y + xv.z*xv.z + xv.w*xv.w;
  for (int off = 32; off; off >>= 1) { s += __shfl_xor(s, off); q += __shfl_xor(q, off); }
  __shared__ float red[8];
  int wave = tid >> 6, lane = tid & 63;
  if (lane == 0) { red[wave] = s; red[4 + wave] = q; }
  __syncthreads();
  s = red[0] + red[1] + red[2] + red[3];
  q = red[4] + red[5] + red[6] + red[7];
  float mu  = s * (1.0f / DIM_);
  float var = q * (1.0f / DIM_) - mu * mu;
  float inv = rsqrtf(var + 1e-5f);
  const float4 gv = *(const float4*)(gamma + tid * 4);
  ushort4 ov;
  ov.x = f2bf((xv.x - mu) * inv * gv.x);
  ov.y = f2bf((xv.y - mu) * inv * gv.y);
  ov.z = f2bf((xv.z - mu) * inv * gv.z);
  ov.w = f2bf((xv.w - mu) * inv * gv.w);
  *(ushort4*)(xn + (size_t)row * DIM_ + tid * 4) = ov;
}

// ---- transpose+cast, all 3 weights in one launch --------------------------
__global__ __launch_bounds__(256) void k_tcast_all(const float* __restrict__ Wq,
                                                   const float* __restrict__ Wkv,
                                                   const float* __restrict__ Wo,
                                                   u16* __restrict__ Wt,
                                                   u16* __restrict__ Wot) {
  __shared__ float tile[32][33];
  int bx = blockIdx.x;
  const float* in; u16* out; int ncols, cb;
  if (bx < 32)      { in = Wq;  out = Wt;               ncols = 1024; cb = bx; }
  else if (bx < 96) { in = Wkv; out = Wt + 1024 * 1024; ncols = 2048; cb = bx - 32; }
  else              { in = Wo;  out = Wot;              ncols = 1024; cb = bx - 96; }
  int tx = threadIdx.x, ty = threadIdx.y;
  int col  = cb * 32 + tx;
  int row0 = blockIdx.y * 32;
  for (int j = 0; j < 32; j += 8)
    tile[ty + j][tx] = in[(size_t)(row0 + ty + j) * ncols + col];
  __syncthreads();
  int orow = cb * 32 + ty;
  int ocol = row0 + tx;
  for (int j = 0; j < 32; j += 8)
    out[(size_t)(orow + j) * DIM_ + ocol] = f2bf(tile[tx][ty + j]);
}

// ------------- mask decode with dtype auto-detect -> additive bias ---------
__global__ void k_mask(const int* __restrict__ mraw, float* __restrict__ bias) {
  __shared__ int flag;
  int tid = threadIdx.x;
  if (tid == 0) flag = 0;
  __syncthreads();
  int v = mraw[tid];                 // 1024 ints: safe under bool(4096B) or int32(16384B)
  if (v != 0 && v != 1) atomicOr(&flag, 1);
  __syncthreads();
  bool bytemode = (flag != 0);
  const unsigned char* mb = (const unsigned char*)mraw;
  if (tid < 512) {
    int j = blockIdx.x * 512 + tid;
    bool valid = bytemode ? (mb[j] != 0) : (mraw[j] != 0);
    bias[j] = valid ? 0.0f : -1e30f;
  }
}

// ------------- GEMM C = A @ Bt^T, optionally fused RMS qk-norm -------------
// (R17-verified) FUSE: wave's 64 cols = one head; q/k rows RMS-normalized in
// fp32 and written to qb/kb; V cols -> Cq for k_vt.
template <int NF, bool OUT_BF16, bool FUSE>
__global__ __launch_bounds__(256) void k_gemm_bt(const u16* __restrict__ A,
                                                 const u16* __restrict__ Bt,
                                                 void* __restrict__ Cv,
                                                 const float* __restrict__ gq,
                                                 const float* __restrict__ gk,
                                                 u16* __restrict__ qo,
                                                 u16* __restrict__ ko,
                                                 int M, int Ncols, int K) {
  constexpr int BN = NF * 32;
  __shared__ u16 As[128 * 32];
  __shared__ u16 Bs[BN * 32];
  const int tid = threadIdx.x;
  const int wave = tid >> 6, lane = tid & 63;
  const int g = lane >> 4, li = lane & 15;
  const int gx = gridDim.x;
  const int wg = blockIdx.y * gx + blockIdx.x;
  const int per = (gx * gridDim.y) >> 3;
  const int swz = (wg & 7) * per + (wg >> 3);
  const int tm = (swz % gx) * 128, tn = (swz / gx) * BN;
  const int wm = (wave >> 1) * 64, wn = (wave & 1) * (NF * 16);
  const int srow = wave * 16 + (lane >> 2);
  const int scol = (lane & 3) * 8;

  f32x4 acc[4][NF];
#pragma unroll
  for (int i = 0; i < 4; ++i)
#pragma unroll
    for (int j = 0; j < NF; ++j) acc[i][j] = (f32x4){0.f, 0.f, 0.f, 0.f};

  const u16* ag = A  + (size_t)(tm + srow) * K + scol;
  const u16* bg = Bt + (size_t)(tn + srow) * K + scol;

  for (int k0 = 0; k0 < K; k0 += 32) {
    __syncthreads();
#pragma unroll
    for (int p = 0; p < 2; ++p)
      lds16(ag + (size_t)p * 64 * K + k0, As + p * 2048 + wave * 512);
#pragma unroll
    for (int p = 0; p < NF / 2; ++p)
      lds16(bg + (size_t)p * 64 * K + k0, Bs + p * 2048 + wave * 512);
    __syncthreads();
    short8 af[4], bfm[NF];
#pragma unroll
    for (int m = 0; m < 4; ++m) af[m]  = ld8(As + (wm + m * 16 + li) * 32 + g * 8);
#pragma unroll
    for (int n = 0; n < NF; ++n) bfm[n] = ld8(Bs + (wn + n * 16 + li) * 32 + g * 8);
#pragma unroll
    for (int m = 0; m < 4; ++m)
#pragma unroll
      for (int n = 0; n < NF; ++n)
        acc[m][n] = mfma16(af[m], bfm[n], acc[m][n]);
  }

  if constexpr (FUSE) {
    const int colbase = tn + wn;          // multiple of 64 (wave-uniform)
    const int region = colbase >> 10;     // 0=q 1=k 2=v
    if (region < 2) {
      const int h = (colbase & 1023) >> 6;
      const float* gam = (region == 0) ? gq : gk;
      u16* dst = (region == 0) ? qo : ko;
#pragma unroll
      for (int m = 0; m < 4; ++m)
#pragma unroll
        for (int r = 0; r < 4; ++r) {
          float ss = 0.f;
#pragma unroll
          for (int n = 0; n < NF; ++n) ss += acc[m][n][r] * acc[m][n][r];
          ss += __shfl_xor(ss, 1);
          ss += __shfl_xor(ss, 2);
          ss += __shfl_xor(ss, 4);
          ss += __shfl_xor(ss, 8);
          float scale = 8.0f / fmaxf(sqrtf(ss), 1e-12f);   // sqrt(64)=8
          int row = tm + wm + m * 16 + g * 4 + r;
          int bb = row >> 11, nn = row & 2047;
          u16* drow = dst + (((size_t)(bb * H_ + h)) * N_ + nn) * 64;
#pragma unroll
          for (int n = 0; n < NF; ++n) {
            int d = n * 16 + li;
            drow[d] = f2bf(acc[m][n][r] * scale * gam[h * 64 + d]);
          }
        }
      return;
    }
    // V columns: bf16 into Cq (layout unchanged, consumed by k_vt)
#pragma unroll
    for (int m = 0; m < 4; ++m)
#pragma unroll
      for (int n = 0; n < NF; ++n) {
        int row = tm + wm + m * 16 + g * 4;
        int col = tn + wn + n * 16 + li;
#pragma unroll
        for (int r = 0; r < 4; ++r)
          ((u16*)Cv)[(size_t)(row + r) * Ncols + col] = f2bf(acc[m][n][r]);
      }
    return;
  }

#pragma unroll
  for (int m = 0; m < 4; ++m)
#pragma unroll
    for (int n = 0; n < NF; ++n) {
      int row = tm + wm + m * 16 + g * 4;
      int col = tn + wn + n * 16 + li;
#pragma unroll
      for (int r = 0; r < 4; ++r) {
        float v = acc[m][n][r];
        if (OUT_BF16) ((u16*)Cv)[(size_t)(row + r) * Ncols + col] = f2bf(v);
        else          ((float*)Cv)[(size_t)(row + r) * Ncols + col] = v;
      }
    }
}

// ------------- V relayout (identity cols): -> vT [b*h][d][n] ---------------
__global__ __launch_bounds__(256) void k_vt(const u16* __restrict__ Cq,
                                            u16* __restrict__ vT) {
  __shared__ float tile[64][65];
  int bh = blockIdx.y;
  int b = bh >> 4, h = bh & 15;
  int n0 = blockIdx.x * 64;
  int tx = threadIdx.x, ty = threadIdx.y;
  for (int i = 0; i < 64; i += 4) {
    int n = n0 + ty + i;
    tile[ty + i][tx] = bf2f(Cq[((size_t)(b * N_ + n)) * E3_ + 2048 + h * 64 + tx]);
  }
  __syncthreads();
  u16* dst = vT + (size_t)bh * 64 * N_;
  for (int i = 0; i < 64; i += 4) {
    int d = ty + i;
    dst[(size_t)d * N_ + n0 + tx] = f2bf(tile[tx][d]);
  }
}

// ------------- flash attention: 128 q per block (halved staging traffic) ---
// R9/R12/R16 natural experiment: all shapes with 64 q/block tie at 81-83us;
// the invariant is chip-wide K/V staging traffic (1024 blocks x 512KB =
// 512MB of global_load_lds), pointing at TA/L2 queue congestion stalling
// every block at the vmcnt-draining barrier. This round: 4 waves x 32 q =
// 128 q/block, grid 512 -> staged bytes HALVE (256MB). Per-wave loop body
// is byte-identical to R16/R17 (each wave owns 32 q as before); only
// grid/indexing and staging chunk count (2/thread, 256 threads) change --
// same transformation class as R12 (passed first try).
__global__ __launch_bounds__(256, 2) void k_attn(const u16* __restrict__ Q,
                                                 const u16* __restrict__ K,
                                                 const u16* __restrict__ Vt,
                                                 const float* __restrict__ bias,
                                                 u16* __restrict__ Out) {
  __shared__ u16 Ks[2][4096];           // 16 KB
  __shared__ u16 Vs[2][4096];           // 16 KB
  int wg = blockIdx.x;
  int xcd = wg & 7, slot = wg >> 3;     // slot 0..63
  int bh = xcd * 4 + (slot & 3);        // bijective: 8 xcd x 4 bh x 16 qchunk
  int qb = (slot >> 2) * 128;           // 16 chunks x 128 q = 2048
  int b = bh >> 4, h = bh & 15;
  int tid = threadIdx.x, wave = tid >> 6, lane = tid & 63;
  int g = lane >> 4, li = lane & 15;
  const u16* Qh = Q  + (size_t)bh * N_ * 64;
  const u16* Kh = K  + (size_t)bh * N_ * 64;
  const u16* Vh = Vt + (size_t)bh * 64 * N_;
  const float* bg = bias + b * N_;

  // staging addresses: 2 chunks of 16B per tile per thread (256 thr x 32B = 8KB)
  u32 Ls[2], kS[2], vR[2], vC[2];
#pragma unroll
  for (int s = 0; s < 2; ++s) {
    Ls[s] = tid * 16 + s * 4096;
    kS[s] = swzb(Ls[s]) >> 1;
    vR[s] = Ls[s] >> 7;
    vC[s] = (swzb(Ls[s]) & 127) >> 1;
  }

  int qr0 = qb + wave * 32 + li;        // q-subgroup A
  int qr1 = qr0 + 16;                   // q-subgroup B
  short8 aqA0 = ld8(Qh + (size_t)qr0 * 64 + g * 8);
  short8 aqA1 = ld8(Qh + (size_t)qr0 * 64 + 32 + g * 8);
  short8 aqB0 = ld8(Qh + (size_t)qr1 * 64 + g * 8);
  short8 aqB1 = ld8(Qh + (size_t)qr1 * 64 + 32 + g * 8);

  f32x4 oTA[4], oTB[4];
#pragma unroll
  for (int dc = 0; dc < 4; ++dc) {
    oTA[dc] = (f32x4){0.f, 0.f, 0.f, 0.f};
    oTB[dc] = (f32x4){0.f, 0.f, 0.f, 0.f};
  }
  float mA = -3e38f, lA = 0.f, mB = -3e38f, lB = 0.f;

  const int fsw  = 8 * (g ^ (li & 7));
  const int fsw2 = fsw ^ 32;
  const int vbl = li * 64 + (g & 1) * 4;
  int vsw[4];
#pragma unroll
  for (int c = 0; c < 4; ++c)
    vsw[c] = (((2 * c + (g >> 1)) ^ (li & 7)) << 3);

  // prologue: stage tile 0 into buffer 0
#pragma unroll
  for (int s = 0; s < 2; ++s) {
    lds16(Kh + kS[s], &Ks[0][0] + (Ls[s] >> 1));
    lds16(Vh + (size_t)vR[s] * N_ + vC[s], &Vs[0][0] + (Ls[s] >> 1));
  }
  __syncthreads();

  for (int kt = 0; kt < 32; ++kt) {
    int cur = kt & 1;
    int kbase = kt * 64;
    if (kt < 31) {                       // stage next tile (async, no regs)
      int nxt = cur ^ 1;
      int nb = kbase + 64;
#pragma unroll
      for (int s = 0; s < 2; ++s) {
        lds16(Kh + (size_t)nb * 64 + kS[s], &Ks[nxt][0] + (Ls[s] >> 1));
        lds16(Vh + (size_t)vR[s] * N_ + nb + vC[s], &Vs[nxt][0] + (Ls[s] >> 1));
      }
    }
    // bias for current tile: 4x broadcast float4 from L2-resident global
    float4 bbc[4];
#pragma unroll
    for (int c = 0; c < 4; ++c)
      bbc[c] = *(const float4*)&bg[kbase + c * 16 + g * 4];
    const u16* Kb = &Ks[cur][0];
    const u16* Vb = &Vs[cur][0];
    // ---- S^T = mfma(K, Q, C=bias) for both q-groups (K-frags shared) ----
    f32x4 stA[4], stB[4];
    __builtin_amdgcn_s_setprio(1);
#pragma unroll
    for (int c = 0; c < 4; ++c) {
      int rb = (c * 16 + li) * 64;
      short8 kf0 = ld8(Kb + rb + fsw);
      short8 kf1 = ld8(Kb + rb + fsw2);
      f32x4 z = (f32x4){bbc[c].x, bbc[c].y, bbc[c].z, bbc[c].w};
      stA[c] = mfma16(kf1, aqA1, mfma16(kf0, aqA0, z));
      stB[c] = mfma16(kf1, aqB1, mfma16(kf0, aqB0, z));
    }
    __builtin_amdgcn_s_setprio(0);
    // ---- V-frags (b64 reads), shared by both q-groups -------------------
    short4v vf16[4][4];
#pragma unroll
    for (int dc = 0; dc < 4; ++dc)
#pragma unroll
      for (int c = 0; c < 4; ++c)
        vf16[dc][c] = *(const short4v*)(Vb + dc * 1024 + vbl + vsw[c]);
    // ---- softmax group A (unconditional) --------------------------------
    float cmA[4];
#pragma unroll
    for (int c = 0; c < 4; ++c)
      cmA[c] = fmaxf(fmaxf(stA[c][0], stA[c][1]), fmaxf(stA[c][2], stA[c][3]));
    float tmaxA = fmaxf(fmaxf(cmA[0], cmA[1]), fmaxf(cmA[2], cmA[3]));
    tmaxA = fmaxf(tmaxA, __shfl_xor(tmaxA, 16));
    tmaxA = fmaxf(tmaxA, __shfl_xor(tmaxA, 32));
    float mnA = fmaxf(mA, tmaxA);
    float scA = __expf(mA - mnA);
    mA = mnA;
    float pvA[4][4], csA[4];
#pragma unroll
    for (int c = 0; c < 4; ++c) {
#pragma unroll
      for (int r = 0; r < 4; ++r) pvA[c][r] = __expf(stA[c][r] - mnA);
      csA[c] = (pvA[c][0] + pvA[c][1]) + (pvA[c][2] + pvA[c][3]);
    }
    float rsA = (csA[0] + csA[1]) + (csA[2] + csA[3]);
    rsA += __shfl_xor(rsA, 16);
    rsA += __shfl_xor(rsA, 32);
    lA = lA * scA + rsA;
#pragma unroll
    for (int dc = 0; dc < 4; ++dc) oTA[dc] *= scA;
    // ---- softmax group B -------------------------------------------------
    float cmB[4];
#pragma unroll
    for (int c = 0; c < 4; ++c)
      cmB[c] = fmaxf(fmaxf(stB[c][0], stB[c][1]), fmaxf(stB[c][2], stB[c][3]));
    float tmaxB = fmaxf(fmaxf(cmB[0], cmB[1]), fmaxf(cmB[2], cmB[3]));
    tmaxB = fmaxf(tmaxB, __shfl_xor(tmaxB, 16));
    tmaxB = fmaxf(tmaxB, __shfl_xor(tmaxB, 32));
    float mnB = fmaxf(mB, tmaxB);
    float scB = __expf(mB - mnB);
    mB = mnB;
    float pvB[4][4], csB[4];
#pragma unroll
    for (int c = 0; c < 4; ++c) {
#pragma unroll
      for (int r = 0; r < 4; ++r) pvB[c][r] = __expf(stB[c][r] - mnB);
      csB[c] = (pvB[c][0] + pvB[c][1]) + (pvB[c][2] + pvB[c][3]);
    }
    float rsB = (csB[0] + csB[1]) + (csB[2] + csB[3]);
    rsB += __shfl_xor(rsB, 16);
    rsB += __shfl_xor(rsB, 32);
    lB = lB * scB + rsB;
#pragma unroll
    for (int dc = 0; dc < 4; ++dc) oTB[dc] *= scB;
    // ---- pack P (both groups) via v_cvt_pk_bf16_f32 ----------------------
    union { u32 u2[2]; short4v s4; } pbA[4], pbB[4];
#pragma unroll
    for (int c = 0; c < 4; ++c) {
      asm("v_cvt_pk_bf16_f32 %0, %1, %2" : "=v"(pbA[c].u2[0]) : "v"(pvA[c][0]), "v"(pvA[c][1]));
      asm("v_cvt_pk_bf16_f32 %0, %1, %2" : "=v"(pbA[c].u2[1]) : "v"(pvA[c][2]), "v"(pvA[c][3]));
      asm("v_cvt_pk_bf16_f32 %0, %1, %2" : "=v"(pbB[c].u2[0]) : "v"(pvB[c][0]), "v"(pvB[c][1]));
      asm("v_cvt_pk_bf16_f32 %0, %1, %2" : "=v"(pbB[c].u2[1]) : "v"(pvB[c][2]), "v"(pvB[c][3]));
    }
    // ---- PV: V-frag (A operand) shared, B operand per q-group -----------
    __builtin_amdgcn_s_setprio(1);
#pragma unroll
    for (int dc = 0; dc < 4; ++dc)
#pragma unroll
      for (int c = 0; c < 4; ++c) {
        oTA[dc] = mfma16k16(vf16[dc][c], pbA[c].s4, oTA[dc]);
        oTB[dc] = mfma16k16(vf16[dc][c], pbB[c].s4, oTB[dc]);
      }
    __builtin_amdgcn_s_setprio(0);
    __syncthreads();                    // next-tile staging complete + buf free
  }

  float invA = 1.0f / lA, invB = 1.0f / lB;
#pragma unroll
  for (int dc = 0; dc < 4; ++dc) {
    ushort4 ovA, ovB;
    ovA.x = f2bf(oTA[dc][0] * invA); ovA.y = f2bf(oTA[dc][1] * invA);
    ovA.z = f2bf(oTA[dc][2] * invA); ovA.w = f2bf(oTA[dc][3] * invA);
    ovB.x = f2bf(oTB[dc][0] * invB); ovB.y = f2bf(oTB[dc][1] * invB);
    ovB.z = f2bf(oTB[dc][2] * invB); ovB.w = f2bf(oTB[dc][3] * invB);
    *(ushort4*)&Out[((size_t)(b * N_ + qr0)) * DIM_ + h * 64 + dc * 16 + g * 4] = ovA;
    *(ushort4*)&Out[((size_t)(b * N_ + qr1)) * DIM_ + h * 64 + dc * 16 + g * 4] = ovB;
  }
}

// ---------------------------------------------------------------------------
extern "C" void kernel_launch(void* const* d_in, const int* in_sizes, int n_in,
                              void* d_out, int out_size, void* d_ws, size_t ws_size,
                              hipStream_t stream) {
  const float* x    = (const float*)d_in[0];
  const int*   mask = (const int*)d_in[1];
  const float* g_ln = (const float*)d_in[2];
  const float* g_q  = (const float*)d_in[3];
  const float* g_k  = (const float*)d_in[4];
  const float* Wq   = (const float*)d_in[5];
  const float* Wkv  = (const float*)d_in[6];
  const float* Wo   = (const float*)d_in[7];
  float* out = (float*)d_out;

  char* ws = (char*)d_ws;
  u16*   xn   = (u16*)(ws);                         // 8 MB
  u16*   Wt   = (u16*)(ws + 8388608);               // 6 MB  (Wq^T | Wkv^T) [3072][1024]
  u16*   Wot  = (u16*)(ws + 14680064);              // 2 MB  Wo^T [1024][1024]
  float* bias = (float*)(ws + 16777216);            // 16 KB
  u16*   Cq   = (u16*)(ws + 16793600);              // 24 MB [4096][3072] (V third used)
  u16*   qb   = (u16*)(ws + 41959424);              // 8 MB [b,h,n,d]
  u16*   kb   = (u16*)(ws + 41959424 + 8388608);    // 8 MB
  u16*   vT   = (u16*)(ws + 41959424 + 2*8388608);  // 8 MB [b*h][d][n]
  u16*   ao   = (u16*)(ws + 41959424 + 3*8388608);  // 8 MB [4096][1024]

  k_layernorm<<<ROWS_, 256, 0, stream>>>(x, g_ln, xn);
  k_tcast_all<<<dim3(128, 32), dim3(32, 8), 0, stream>>>(Wq, Wkv, Wo, Wt, Wot);
  k_mask<<<8, 1024, 0, stream>>>(mask, bias);
  k_gemm_bt<4, true, true><<<dim3(32, 24), 256, 0, stream>>>(
      xn, Wt, Cq, g_q, g_k, qb, kb, ROWS_, E3_, DIM_);
  k_vt<<<dim3(32, 32), dim3(64, 4), 0, stream>>>(Cq, vT);
  k_attn<<<512, 256, 0, stream>>>(qb, kb, vT, bias, ao);
  k_gemm_bt<2, false, false><<<dim3(32, 16), 256, 0, stream>>>(
      ao, Wot, out, nullptr, nullptr, nullptr, nullptr, ROWS_, DIM_, DIM_);
}

// Round 19
// 141.010 us; speedup vs baseline: 2.3709x; 1.0887x over previous
//
#include <hip/hip_runtime.h>

using u16 = unsigned short;
using u32 = unsigned int;

#define B_   2
#define N_   2048
#define DIM_ 1024
#define H_   16
#define D_   64
#define ROWS_ (B_*N_)   // 4096
#define E3_  3072       // q|k|v concatenated

typedef __attribute__((ext_vector_type(8))) short short8;
typedef __attribute__((ext_vector_type(4))) short short4v;
typedef __attribute__((ext_vector_type(4))) float f32x4;

__device__ __forceinline__ u16 f2bf(float f) {
  u32 u = __builtin_bit_cast(u32, f);
  u32 r = (u + 0x7FFFu + ((u >> 16) & 1u)) >> 16;
  return (u16)r;
}
__device__ __forceinline__ float bf2f(u16 h) {
  u32 u = ((u32)h) << 16;
  return __builtin_bit_cast(float, u);
}
__device__ __forceinline__ short8 ld8(const u16* p) { return *(const short8*)p; }
__device__ __forceinline__ f32x4 mfma16(short8 a, short8 b, f32x4 c) {
  return __builtin_amdgcn_mfma_f32_16x16x32_bf16(a, b, c, 0, 0, 0);
}
// K=16 bf16 MFMA (R9-verified): B[k=g*4+j][col=li] == softmax's in-lane P.
__device__ __forceinline__ f32x4 mfma16k16(short4v a, short4v b, f32x4 c) {
#if !defined(__HIP_DEVICE_COMPILE__)
  (void)a; (void)b;
  return c;
#elif __has_builtin(__builtin_amdgcn_mfma_f32_16x16x16bf16_1k)
  return __builtin_amdgcn_mfma_f32_16x16x16bf16_1k(a, b, c, 0, 0, 0);
#else
  short8 a8 = (short8){a[0], a[1], a[2], a[3], 0, 0, 0, 0};
  short8 b8 = (short8){b[0], b[1], b[2], b[3], 0, 0, 0, 0};
  return __builtin_amdgcn_mfma_f32_16x16x32_bf16(a8, b8, c, 0, 0, 0);
#endif
}
__device__ __forceinline__ void lds16(const u16* g, u16* l) {
  __builtin_amdgcn_global_load_lds(
      (const __attribute__((address_space(1))) void*)g,
      (__attribute__((address_space(3))) void*)l, 16, 0, 0);
}
// byte-level XOR swizzle: flips bits 4-6 (16B chunk idx) by row&7; involution.
__device__ __forceinline__ u32 swzb(u32 L) { return L ^ (((L >> 7) & 7) << 4); }

// ---------------- LayerNorm: x fp32 [4096][1024] -> xn bf16 ----------------
__global__ __launch_bounds__(256) void k_layernorm(const float* __restrict__ x,
                                                   const float* __restrict__ gamma,
                                                   u16* __restrict__ xn) {
  int row = blockIdx.x, tid = threadIdx.x;
  const float4 xv = *(const float4*)(x + (size_t)row * DIM_ + tid * 4);
  float s = xv.x + xv.y + xv.z + xv.w;
  float q = xv.x*xv.x + xv.y*xv.y + xv.z*xv.z + xv.w*xv.w;
  for (int off = 32; off; off >>= 1) { s += __shfl_xor(s, off); q += __shfl_xor(q, off); }
  __shared__ float red[8];
  int wave = tid >> 6, lane = tid & 63;
  if (lane == 0) { red[wave] = s; red[4 + wave] = q; }
  __syncthreads();
  s = red[0] + red[1] + red[2] + red[3];
  q = red[4] + red[5] + red[6] + red[7];
  float mu  = s * (1.0f / DIM_);
  float var = q * (1.0f / DIM_) - mu * mu;
  float inv = rsqrtf(var + 1e-5f);
  const float4 gv = *(const float4*)(gamma + tid * 4);
  ushort4 ov;
  ov.x = f2bf((xv.x - mu) * inv * gv.x);
  ov.y = f2bf((xv.y - mu) * inv * gv.y);
  ov.z = f2bf((xv.z - mu) * inv * gv.z);
  ov.w = f2bf((xv.w - mu) * inv * gv.w);
  *(ushort4*)(xn + (size_t)row * DIM_ + tid * 4) = ov;
}

// ---- transpose+cast, all 3 weights in one launch --------------------------
__global__ __launch_bounds__(256) void k_tcast_all(const float* __restrict__ Wq,
                                                   const float* __restrict__ Wkv,
                                                   const float* __restrict__ Wo,
                                                   u16* __restrict__ Wt,
                                                   u16* __restrict__ Wot) {
  __shared__ float tile[32][33];
  int bx = blockIdx.x;
  const float* in; u16* out; int ncols, cb;
  if (bx < 32)      { in = Wq;  out = Wt;               ncols = 1024; cb = bx; }
  else if (bx < 96) { in = Wkv; out = Wt + 1024 * 1024; ncols = 2048; cb = bx - 32; }
  else              { in = Wo;  out = Wot;              ncols = 1024; cb = bx - 96; }
  int tx = threadIdx.x, ty = threadIdx.y;
  int col  = cb * 32 + tx;
  int row0 = blockIdx.y * 32;
  for (int j = 0; j < 32; j += 8)
    tile[ty + j][tx] = in[(size_t)(row0 + ty + j) * ncols + col];
  __syncthreads();
  int orow = cb * 32 + ty;
  int ocol = row0 + tx;
  for (int j = 0; j < 32; j += 8)
    out[(size_t)(orow + j) * DIM_ + ocol] = f2bf(tile[tx][ty + j]);
}

// ------------- mask decode with dtype auto-detect -> additive bias ---------
__global__ void k_mask(const int* __restrict__ mraw, float* __restrict__ bias) {
  __shared__ int flag;
  int tid = threadIdx.x;
  if (tid == 0) flag = 0;
  __syncthreads();
  int v = mraw[tid];                 // 1024 ints: safe under bool(4096B) or int32(16384B)
  if (v != 0 && v != 1) atomicOr(&flag, 1);
  __syncthreads();
  bool bytemode = (flag != 0);
  const unsigned char* mb = (const unsigned char*)mraw;
  if (tid < 512) {
    int j = blockIdx.x * 512 + tid;
    bool valid = bytemode ? (mb[j] != 0) : (mraw[j] != 0);
    bias[j] = valid ? 0.0f : -1e30f;
  }
}

// ------------- GEMM C = A @ Bt^T, optionally fused RMS qk-norm -------------
// (R17-verified) FUSE: wave's 64 cols = one head; q/k rows RMS-normalized in
// fp32 and written to qb/kb; V cols -> Cq for k_vt.
template <int NF, bool OUT_BF16, bool FUSE>
__global__ __launch_bounds__(256) void k_gemm_bt(const u16* __restrict__ A,
                                                 const u16* __restrict__ Bt,
                                                 void* __restrict__ Cv,
                                                 const float* __restrict__ gq,
                                                 const float* __restrict__ gk,
                                                 u16* __restrict__ qo,
                                                 u16* __restrict__ ko,
                                                 int M, int Ncols, int K) {
  constexpr int BN = NF * 32;
  __shared__ u16 As[128 * 32];
  __shared__ u16 Bs[BN * 32];
  const int tid = threadIdx.x;
  const int wave = tid >> 6, lane = tid & 63;
  const int g = lane >> 4, li = lane & 15;
  const int gx = gridDim.x;
  const int wg = blockIdx.y * gx + blockIdx.x;
  const int per = (gx * gridDim.y) >> 3;
  const int swz = (wg & 7) * per + (wg >> 3);
  const int tm = (swz % gx) * 128, tn = (swz / gx) * BN;
  const int wm = (wave >> 1) * 64, wn = (wave & 1) * (NF * 16);
  const int srow = wave * 16 + (lane >> 2);
  const int scol = (lane & 3) * 8;

  f32x4 acc[4][NF];
#pragma unroll
  for (int i = 0; i < 4; ++i)
#pragma unroll
    for (int j = 0; j < NF; ++j) acc[i][j] = (f32x4){0.f, 0.f, 0.f, 0.f};

  const u16* ag = A  + (size_t)(tm + srow) * K + scol;
  const u16* bg = Bt + (size_t)(tn + srow) * K + scol;

  for (int k0 = 0; k0 < K; k0 += 32) {
    __syncthreads();
#pragma unroll
    for (int p = 0; p < 2; ++p)
      lds16(ag + (size_t)p * 64 * K + k0, As + p * 2048 + wave * 512);
#pragma unroll
    for (int p = 0; p < NF / 2; ++p)
      lds16(bg + (size_t)p * 64 * K + k0, Bs + p * 2048 + wave * 512);
    __syncthreads();
    short8 af[4], bfm[NF];
#pragma unroll
    for (int m = 0; m < 4; ++m) af[m]  = ld8(As + (wm + m * 16 + li) * 32 + g * 8);
#pragma unroll
    for (int n = 0; n < NF; ++n) bfm[n] = ld8(Bs + (wn + n * 16 + li) * 32 + g * 8);
#pragma unroll
    for (int m = 0; m < 4; ++m)
#pragma unroll
      for (int n = 0; n < NF; ++n)
        acc[m][n] = mfma16(af[m], bfm[n], acc[m][n]);
  }

  if constexpr (FUSE) {
    const int colbase = tn + wn;          // multiple of 64 (wave-uniform)
    const int region = colbase >> 10;     // 0=q 1=k 2=v
    if (region < 2) {
      const int h = (colbase & 1023) >> 6;
      const float* gam = (region == 0) ? gq : gk;
      u16* dst = (region == 0) ? qo : ko;
#pragma unroll
      for (int m = 0; m < 4; ++m)
#pragma unroll
        for (int r = 0; r < 4; ++r) {
          float ss = 0.f;
#pragma unroll
          for (int n = 0; n < NF; ++n) ss += acc[m][n][r] * acc[m][n][r];
          ss += __shfl_xor(ss, 1);
          ss += __shfl_xor(ss, 2);
          ss += __shfl_xor(ss, 4);
          ss += __shfl_xor(ss, 8);
          float scale = 8.0f / fmaxf(sqrtf(ss), 1e-12f);   // sqrt(64)=8
          int row = tm + wm + m * 16 + g * 4 + r;
          int bb = row >> 11, nn = row & 2047;
          u16* drow = dst + (((size_t)(bb * H_ + h)) * N_ + nn) * 64;
#pragma unroll
          for (int n = 0; n < NF; ++n) {
            int d = n * 16 + li;
            drow[d] = f2bf(acc[m][n][r] * scale * gam[h * 64 + d]);
          }
        }
      return;
    }
    // V columns: bf16 into Cq (layout unchanged, consumed by k_vt)
#pragma unroll
    for (int m = 0; m < 4; ++m)
#pragma unroll
      for (int n = 0; n < NF; ++n) {
        int row = tm + wm + m * 16 + g * 4;
        int col = tn + wn + n * 16 + li;
#pragma unroll
        for (int r = 0; r < 4; ++r)
          ((u16*)Cv)[(size_t)(row + r) * Ncols + col] = f2bf(acc[m][n][r]);
      }
    return;
  }

#pragma unroll
  for (int m = 0; m < 4; ++m)
#pragma unroll
    for (int n = 0; n < NF; ++n) {
      int row = tm + wm + m * 16 + g * 4;
      int col = tn + wn + n * 16 + li;
#pragma unroll
      for (int r = 0; r < 4; ++r) {
        float v = acc[m][n][r];
        if (OUT_BF16) ((u16*)Cv)[(size_t)(row + r) * Ncols + col] = f2bf(v);
        else          ((float*)Cv)[(size_t)(row + r) * Ncols + col] = v;
      }
    }
}

// ------------- V relayout (identity cols): -> vT [b*h][d][n] ---------------
__global__ __launch_bounds__(256) void k_vt(const u16* __restrict__ Cq,
                                            u16* __restrict__ vT) {
  __shared__ float tile[64][65];
  int bh = blockIdx.y;
  int b = bh >> 4, h = bh & 15;
  int n0 = blockIdx.x * 64;
  int tx = threadIdx.x, ty = threadIdx.y;
  for (int i = 0; i < 64; i += 4) {
    int n = n0 + ty + i;
    tile[ty + i][tx] = bf2f(Cq[((size_t)(b * N_ + n)) * E3_ + 2048 + h * 64 + tx]);
  }
  __syncthreads();
  u16* dst = vT + (size_t)bh * 64 * N_;
  for (int i = 0; i < 64; i += 4) {
    int d = ty + i;
    dst[(size_t)d * N_ + n0 + tx] = f2bf(tile[tx][d]);
  }
}

// ------------- flash attention: fixed-offset softmax (no running max) ------
// RMS-normalized inputs give ||q||=||k||=8 exactly -> |S| <= 64 (Cauchy-
// Schwarz). So P = exp(S - 24) is always in fp32 range: max P <= e^40 ~
// 2.3e17, l <= 2048 e^40 ~ 5e20; masked entries exp(-1e30-24) = 0; l >=
// exp(rowmax-24) with rowmax >= -24 in practice (S~N(0,8), >=1024 valid
// keys). bf16/fp32 relative precision is scale-invariant -> same error
// structure as running-max. DELETES per q-group: 19-fmax tree, 2 shfl-max,
// running-max state, rescale exp, 16 oT rescale muls -- and removes the
// serial max-reduction from the QK^T -> PV critical path. Strictly simpler
// than R18 (everything unconditional).
__global__ __launch_bounds__(256, 2) void k_attn(const u16* __restrict__ Q,
                                                 const u16* __restrict__ K,
                                                 const u16* __restrict__ Vt,
                                                 const float* __restrict__ bias,
                                                 u16* __restrict__ Out) {
  __shared__ u16 Ks[2][4096];           // 16 KB
  __shared__ u16 Vs[2][4096];           // 16 KB
  int wg = blockIdx.x;
  int xcd = wg & 7, slot = wg >> 3;     // slot 0..63
  int bh = xcd * 4 + (slot & 3);        // bijective: 8 xcd x 4 bh x 16 qchunk
  int qb = (slot >> 2) * 128;           // 16 chunks x 128 q = 2048
  int b = bh >> 4, h = bh & 15;
  int tid = threadIdx.x, wave = tid >> 6, lane = tid & 63;
  int g = lane >> 4, li = lane & 15;
  const u16* Qh = Q  + (size_t)bh * N_ * 64;
  const u16* Kh = K  + (size_t)bh * N_ * 64;
  const u16* Vh = Vt + (size_t)bh * 64 * N_;
  const float* bg = bias + b * N_;

  // staging addresses: 2 chunks of 16B per tile per thread (256 thr x 32B = 8KB)
  u32 Ls[2], kS[2], vR[2], vC[2];
#pragma unroll
  for (int s = 0; s < 2; ++s) {
    Ls[s] = tid * 16 + s * 4096;
    kS[s] = swzb(Ls[s]) >> 1;
    vR[s] = Ls[s] >> 7;
    vC[s] = (swzb(Ls[s]) & 127) >> 1;
  }

  int qr0 = qb + wave * 32 + li;        // q-subgroup A
  int qr1 = qr0 + 16;                   // q-subgroup B
  short8 aqA0 = ld8(Qh + (size_t)qr0 * 64 + g * 8);
  short8 aqA1 = ld8(Qh + (size_t)qr0 * 64 + 32 + g * 8);
  short8 aqB0 = ld8(Qh + (size_t)qr1 * 64 + g * 8);
  short8 aqB1 = ld8(Qh + (size_t)qr1 * 64 + 32 + g * 8);

  f32x4 oTA[4], oTB[4];
#pragma unroll
  for (int dc = 0; dc < 4; ++dc) {
    oTA[dc] = (f32x4){0.f, 0.f, 0.f, 0.f};
    oTB[dc] = (f32x4){0.f, 0.f, 0.f, 0.f};
  }
  float lA = 0.f, lB = 0.f;

  const int fsw  = 8 * (g ^ (li & 7));
  const int fsw2 = fsw ^ 32;
  const int vbl = li * 64 + (g & 1) * 4;
  int vsw[4];
#pragma unroll
  for (int c = 0; c < 4; ++c)
    vsw[c] = (((2 * c + (g >> 1)) ^ (li & 7)) << 3);

  // prologue: stage tile 0 into buffer 0
#pragma unroll
  for (int s = 0; s < 2; ++s) {
    lds16(Kh + kS[s], &Ks[0][0] + (Ls[s] >> 1));
    lds16(Vh + (size_t)vR[s] * N_ + vC[s], &Vs[0][0] + (Ls[s] >> 1));
  }
  __syncthreads();

  for (int kt = 0; kt < 32; ++kt) {
    int cur = kt & 1;
    int kbase = kt * 64;
    if (kt < 31) {                       // stage next tile (async, no regs)
      int nxt = cur ^ 1;
      int nb = kbase + 64;
#pragma unroll
      for (int s = 0; s < 2; ++s) {
        lds16(Kh + (size_t)nb * 64 + kS[s], &Ks[nxt][0] + (Ls[s] >> 1));
        lds16(Vh + (size_t)vR[s] * N_ + nb + vC[s], &Vs[nxt][0] + (Ls[s] >> 1));
      }
    }
    // bias for current tile: 4x broadcast float4 from L2-resident global
    float4 bbc[4];
#pragma unroll
    for (int c = 0; c < 4; ++c)
      bbc[c] = *(const float4*)&bg[kbase + c * 16 + g * 4];
    const u16* Kb = &Ks[cur][0];
    const u16* Vb = &Vs[cur][0];
    // ---- S^T = mfma(K, Q, C=bias) for both q-groups (K-frags shared) ----
    f32x4 stA[4], stB[4];
    __builtin_amdgcn_s_setprio(1);
#pragma unroll
    for (int c = 0; c < 4; ++c) {
      int rb = (c * 16 + li) * 64;
      short8 kf0 = ld8(Kb + rb + fsw);
      short8 kf1 = ld8(Kb + rb + fsw2);
      f32x4 z = (f32x4){bbc[c].x, bbc[c].y, bbc[c].z, bbc[c].w};
      stA[c] = mfma16(kf1, aqA1, mfma16(kf0, aqA0, z));
      stB[c] = mfma16(kf1, aqB1, mfma16(kf0, aqB0, z));
    }
    __builtin_amdgcn_s_setprio(0);
    // ---- V-frags (b64 reads), shared by both q-groups -------------------
    short4v vf16[4][4];
#pragma unroll
    for (int dc = 0; dc < 4; ++dc)
#pragma unroll
      for (int c = 0; c < 4; ++c)
        vf16[dc][c] = *(const short4v*)(Vb + dc * 1024 + vbl + vsw[c]);
    // ---- softmax A: P = exp(S - 24), no max tracking --------------------
    float pvA[4][4], csA[4];
#pragma unroll
    for (int c = 0; c < 4; ++c) {
#pragma unroll
      for (int r = 0; r < 4; ++r) pvA[c][r] = __expf(stA[c][r] - 24.0f);
      csA[c] = (pvA[c][0] + pvA[c][1]) + (pvA[c][2] + pvA[c][3]);
    }
    float rsA = (csA[0] + csA[1]) + (csA[2] + csA[3]);
    rsA += __shfl_xor(rsA, 16);
    rsA += __shfl_xor(rsA, 32);
    lA += rsA;
    // ---- softmax B -------------------------------------------------------
    float pvB[4][4], csB[4];
#pragma unroll
    for (int c = 0; c < 4; ++c) {
#pragma unroll
      for (int r = 0; r < 4; ++r) pvB[c][r] = __expf(stB[c][r] - 24.0f);
      csB[c] = (pvB[c][0] + pvB[c][1]) + (pvB[c][2] + pvB[c][3]);
    }
    float rsB = (csB[0] + csB[1]) + (csB[2] + csB[3]);
    rsB += __shfl_xor(rsB, 16);
    rsB += __shfl_xor(rsB, 32);
    lB += rsB;
    // ---- pack P (both groups) via v_cvt_pk_bf16_f32 ----------------------
    union { u32 u2[2]; short4v s4; } pbA[4], pbB[4];
#pragma unroll
    for (int c = 0; c < 4; ++c) {
      asm("v_cvt_pk_bf16_f32 %0, %1, %2" : "=v"(pbA[c].u2[0]) : "v"(pvA[c][0]), "v"(pvA[c][1]));
      asm("v_cvt_pk_bf16_f32 %0, %1, %2" : "=v"(pbA[c].u2[1]) : "v"(pvA[c][2]), "v"(pvA[c][3]));
      asm("v_cvt_pk_bf16_f32 %0, %1, %2" : "=v"(pbB[c].u2[0]) : "v"(pvB[c][0]), "v"(pvB[c][1]));
      asm("v_cvt_pk_bf16_f32 %0, %1, %2" : "=v"(pbB[c].u2[1]) : "v"(pvB[c][2]), "v"(pvB[c][3]));
    }
    // ---- PV: V-frag (A operand) shared, B operand per q-group -----------
    __builtin_amdgcn_s_setprio(1);
#pragma unroll
    for (int dc = 0; dc < 4; ++dc)
#pragma unroll
      for (int c = 0; c < 4; ++c) {
        oTA[dc] = mfma16k16(vf16[dc][c], pbA[c].s4, oTA[dc]);
        oTB[dc] = mfma16k16(vf16[dc][c], pbB[c].s4, oTB[dc]);
      }
    __builtin_amdgcn_s_setprio(0);
    __syncthreads();                    // next-tile staging complete + buf free
  }

  float invA = 1.0f / lA, invB = 1.0f / lB;
#pragma unroll
  for (int dc = 0; dc < 4; ++dc) {
    ushort4 ovA, ovB;
    ovA.x = f2bf(oTA[dc][0] * invA); ovA.y = f2bf(oTA[dc][1] * invA);
    ovA.z = f2bf(oTA[dc][2] * invA); ovA.w = f2bf(oTA[dc][3] * invA);
    ovB.x = f2bf(oTB[dc][0] * invB); ovB.y = f2bf(oTB[dc][1] * invB);
    ovB.z = f2bf(oTB[dc][2] * invB); ovB.w = f2bf(oTB[dc][3] * invB);
    *(ushort4*)&Out[((size_t)(b * N_ + qr0)) * DIM_ + h * 64 + dc * 16 + g * 4] = ovA;
    *(ushort4*)&Out[((size_t)(b * N_ + qr1)) * DIM_ + h * 64 + dc * 16 + g * 4] = ovB;
  }
}

// ---------------------------------------------------------------------------
extern "C" void kernel_launch(void* const* d_in, const int* in_sizes, int n_in,
                              void* d_out, int out_size, void* d_ws, size_t ws_size,
                              hipStream_t stream) {
  const float* x    = (const float*)d_in[0];
  const int*   mask = (const int*)d_in[1];
  const float* g_ln = (const float*)d_in[2];
  const float* g_q  = (const float*)d_in[3];
  const float* g_k  = (const float*)d_in[4];
  const float* Wq   = (const float*)d_in[5];
  const float* Wkv  = (const float*)d_in[6];
  const float* Wo   = (const float*)d_in[7];
  float* out = (float*)d_out;

  char* ws = (char*)d_ws;
  u16*   xn   = (u16*)(ws);                         // 8 MB
  u16*   Wt   = (u16*)(ws + 8388608);               // 6 MB  (Wq^T | Wkv^T) [3072][1024]
  u16*   Wot  = (u16*)(ws + 14680064);              // 2 MB  Wo^T [1024][1024]
  float* bias = (float*)(ws + 16777216);            // 16 KB
  u16*   Cq   = (u16*)(ws + 16793600);              // 24 MB [4096][3072] (V third used)
  u16*   qb   = (u16*)(ws + 41959424);              // 8 MB [b,h,n,d]
  u16*   kb   = (u16*)(ws + 41959424 + 8388608);    // 8 MB
  u16*   vT   = (u16*)(ws + 41959424 + 2*8388608);  // 8 MB [b*h][d][n]
  u16*   ao   = (u16*)(ws + 41959424 + 3*8388608);  // 8 MB [4096][1024]

  k_layernorm<<<ROWS_, 256, 0, stream>>>(x, g_ln, xn);
  k_tcast_all<<<dim3(128, 32), dim3(32, 8), 0, stream>>>(Wq, Wkv, Wo, Wt, Wot);
  k_mask<<<8, 1024, 0, stream>>>(mask, bias);
  k_gemm_bt<4, true, true><<<dim3(32, 24), 256, 0, stream>>>(
      xn, Wt, Cq, g_q, g_k, qb, kb, ROWS_, E3_, DIM_);
  k_vt<<<dim3(32, 32), dim3(64, 4), 0, stream>>>(Cq, vT);
  k_attn<<<512, 256, 0, stream>>>(qb, kb, vT, bias, ao);
  k_gemm_bt<2, false, false><<<dim3(32, 16), 256, 0, stream>>>(
      ao, Wot, out, nullptr, nullptr, nullptr, nullptr, ROWS_, DIM_, DIM_);
}

// Round 20
// 134.550 us; speedup vs baseline: 2.4848x; 1.0480x over previous
//
#include <hip/hip_runtime.h>

using u16 = unsigned short;
using u32 = unsigned int;

#define B_   2
#define N_   2048
#define DIM_ 1024
#define H_   16
#define D_   64
#define ROWS_ (B_*N_)   // 4096
#define E3_  3072       // q|k|v concatenated

typedef __attribute__((ext_vector_type(8))) short short8;
typedef __attribute__((ext_vector_type(4))) short short4v;
typedef __attribute__((ext_vector_type(4))) float f32x4;

__device__ __forceinline__ u16 f2bf(float f) {
  u32 u = __builtin_bit_cast(u32, f);
  u32 r = (u + 0x7FFFu + ((u >> 16) & 1u)) >> 16;
  return (u16)r;
}
__device__ __forceinline__ float bf2f(u16 h) {
  u32 u = ((u32)h) << 16;
  return __builtin_bit_cast(float, u);
}
__device__ __forceinline__ short8 ld8(const u16* p) { return *(const short8*)p; }
__device__ __forceinline__ f32x4 mfma16(short8 a, short8 b, f32x4 c) {
  return __builtin_amdgcn_mfma_f32_16x16x32_bf16(a, b, c, 0, 0, 0);
}
// K=16 bf16 MFMA (R9-verified): B[k=g*4+j][col=li] == softmax's in-lane P.
__device__ __forceinline__ f32x4 mfma16k16(short4v a, short4v b, f32x4 c) {
#if !defined(__HIP_DEVICE_COMPILE__)
  (void)a; (void)b;
  return c;
#elif __has_builtin(__builtin_amdgcn_mfma_f32_16x16x16bf16_1k)
  return __builtin_amdgcn_mfma_f32_16x16x16bf16_1k(a, b, c, 0, 0, 0);
#else
  short8 a8 = (short8){a[0], a[1], a[2], a[3], 0, 0, 0, 0};
  short8 b8 = (short8){b[0], b[1], b[2], b[3], 0, 0, 0, 0};
  return __builtin_amdgcn_mfma_f32_16x16x32_bf16(a8, b8, c, 0, 0, 0);
#endif
}
__device__ __forceinline__ void lds16(const u16* g, u16* l) {
  __builtin_amdgcn_global_load_lds(
      (const __attribute__((address_space(1))) void*)g,
      (__attribute__((address_space(3))) void*)l, 16, 0, 0);
}
// byte-level XOR swizzle: flips bits 4-6 (16B chunk idx) by row&7; involution.
__device__ __forceinline__ u32 swzb(u32 L) { return L ^ (((L >> 7) & 7) << 4); }

// ---- merged pre-pass: layernorm | weight transpose+cast | mask decode -----
// Block ranges (uniform branch on blockIdx.x; each block runs exactly one
// part, so intra-part __syncthreads is safe):
//   [0,4096)        layernorm  row = bx
//   [4096,8192)     tcast      idx = bx-4096: cb-dim = idx&127, row0-dim = idx>>7
//   [8192,8208)     mask       16 blocks x 256 slice writes
// Mask bias values carry the softmax offset: valid -> -24 (see k_attn),
// invalid -> -1e30.
__global__ __launch_bounds__(256) void k_pre(const float* __restrict__ x,
                                             const float* __restrict__ g_ln,
                                             const float* __restrict__ Wq,
                                             const float* __restrict__ Wkv,
                                             const float* __restrict__ Wo,
                                             const int* __restrict__ mraw,
                                             u16* __restrict__ xn,
                                             u16* __restrict__ Wt,
                                             u16* __restrict__ Wot,
                                             float* __restrict__ bias) {
  int bxg = blockIdx.x, tid = threadIdx.x;
  if (bxg < 4096) {
    // ---------------- LayerNorm: x fp32 [4096][1024] -> xn bf16 ----------
    int row = bxg;
    const float4 xv = *(const float4*)(x + (size_t)row * DIM_ + tid * 4);
    float s = xv.x + xv.y + xv.z + xv.w;
    float q = xv.x*xv.x + xv.y*xv.y + xv.z*xv.z + xv.w*xv.w;
    for (int off = 32; off; off >>= 1) { s += __shfl_xor(s, off); q += __shfl_xor(q, off); }
    __shared__ float red[8];
    int wave = tid >> 6, lane = tid & 63;
    if (lane == 0) { red[wave] = s; red[4 + wave] = q; }
    __syncthreads();
    s = red[0] + red[1] + red[2] + red[3];
    q = red[4] + red[5] + red[6] + red[7];
    float mu  = s * (1.0f / DIM_);
    float var = q * (1.0f / DIM_) - mu * mu;
    float inv = rsqrtf(var + 1e-5f);
    const float4 gv = *(const float4*)(g_ln + tid * 4);
    ushort4 ov;
    ov.x = f2bf((xv.x - mu) * inv * gv.x);
    ov.y = f2bf((xv.y - mu) * inv * gv.y);
    ov.z = f2bf((xv.z - mu) * inv * gv.z);
    ov.w = f2bf((xv.w - mu) * inv * gv.w);
    *(ushort4*)(xn + (size_t)row * DIM_ + tid * 4) = ov;
  } else if (bxg < 8192) {
    // ---------- transpose+cast (all 3 weights), 32x32 tiles --------------
    __shared__ float tile[32][33];
    int idx = bxg - 4096;
    int bx = idx & 127;                 // cb-dim (was gridDim.x=128)
    int row0 = (idx >> 7) * 32;         // K-dim (was blockIdx.y*32)
    const float* in; u16* out; int ncols, cb;
    if (bx < 32)      { in = Wq;  out = Wt;               ncols = 1024; cb = bx; }
    else if (bx < 96) { in = Wkv; out = Wt + 1024 * 1024; ncols = 2048; cb = bx - 32; }
    else              { in = Wo;  out = Wot;              ncols = 1024; cb = bx - 96; }
    int tx = tid & 31, ty = tid >> 5;   // 32 x 8
    int col = cb * 32 + tx;
    for (int j = 0; j < 32; j += 8)
      tile[ty + j][tx] = in[(size_t)(row0 + ty + j) * ncols + col];
    __syncthreads();
    int orow = cb * 32 + ty;
    int ocol = row0 + tx;
    for (int j = 0; j < 32; j += 8)
      out[(size_t)(orow + j) * DIM_ + ocol] = f2bf(tile[tx][ty + j]);
  } else {
    // ---------- mask decode with dtype auto-detect -> additive bias ------
    // 256 ints scanned: bool-mode makes an int look like 0/1 with p=1/8 ->
    // misdetect p = 8^-256 ~ 0. Valid -> -24 (fixed softmax offset folded
    // here), invalid -> -1e30.
    __shared__ int flag;
    if (tid == 0) flag = 0;
    __syncthreads();
    int v = mraw[tid];
    if (v != 0 && v != 1) atomicOr(&flag, 1);
    __syncthreads();
    bool bytemode = (flag != 0);
    const unsigned char* mb = (const unsigned char*)mraw;
    int j = (bxg - 8192) * 256 + tid;   // 16 blocks x 256 = 4096
    bool valid = bytemode ? (mb[j] != 0) : (mraw[j] != 0);
    bias[j] = valid ? -24.0f : -1e30f;
  }
}

// ------------- GEMM C = A @ Bt^T, optionally fused RMS qk-norm -------------
// (R17-verified) FUSE: wave's 64 cols = one head; q/k rows RMS-normalized in
// fp32 and written to qb/kb; V cols -> Cq for k_vt.
template <int NF, bool OUT_BF16, bool FUSE>
__global__ __launch_bounds__(256) void k_gemm_bt(const u16* __restrict__ A,
                                                 const u16* __restrict__ Bt,
                                                 void* __restrict__ Cv,
                                                 const float* __restrict__ gq,
                                                 const float* __restrict__ gk,
                                                 u16* __restrict__ qo,
                                                 u16* __restrict__ ko,
                                                 int M, int Ncols, int K) {
  constexpr int BN = NF * 32;
  __shared__ u16 As[128 * 32];
  __shared__ u16 Bs[BN * 32];
  const int tid = threadIdx.x;
  const int wave = tid >> 6, lane = tid & 63;
  const int g = lane >> 4, li = lane & 15;
  const int gx = gridDim.x;
  const int wg = blockIdx.y * gx + blockIdx.x;
  const int per = (gx * gridDim.y) >> 3;
  const int swz = (wg & 7) * per + (wg >> 3);
  const int tm = (swz % gx) * 128, tn = (swz / gx) * BN;
  const int wm = (wave >> 1) * 64, wn = (wave & 1) * (NF * 16);
  const int srow = wave * 16 + (lane >> 2);
  const int scol = (lane & 3) * 8;

  f32x4 acc[4][NF];
#pragma unroll
  for (int i = 0; i < 4; ++i)
#pragma unroll
    for (int j = 0; j < NF; ++j) acc[i][j] = (f32x4){0.f, 0.f, 0.f, 0.f};

  const u16* ag = A  + (size_t)(tm + srow) * K + scol;
  const u16* bg = Bt + (size_t)(tn + srow) * K + scol;

  for (int k0 = 0; k0 < K; k0 += 32) {
    __syncthreads();
#pragma unroll
    for (int p = 0; p < 2; ++p)
      lds16(ag + (size_t)p * 64 * K + k0, As + p * 2048 + wave * 512);
#pragma unroll
    for (int p = 0; p < NF / 2; ++p)
      lds16(bg + (size_t)p * 64 * K + k0, Bs + p * 2048 + wave * 512);
    __syncthreads();
    short8 af[4], bfm[NF];
#pragma unroll
    for (int m = 0; m < 4; ++m) af[m]  = ld8(As + (wm + m * 16 + li) * 32 + g * 8);
#pragma unroll
    for (int n = 0; n < NF; ++n) bfm[n] = ld8(Bs + (wn + n * 16 + li) * 32 + g * 8);
#pragma unroll
    for (int m = 0; m < 4; ++m)
#pragma unroll
      for (int n = 0; n < NF; ++n)
        acc[m][n] = mfma16(af[m], bfm[n], acc[m][n]);
  }

  if constexpr (FUSE) {
    const int colbase = tn + wn;          // multiple of 64 (wave-uniform)
    const int region = colbase >> 10;     // 0=q 1=k 2=v
    if (region < 2) {
      const int h = (colbase & 1023) >> 6;
      const float* gam = (region == 0) ? gq : gk;
      u16* dst = (region == 0) ? qo : ko;
#pragma unroll
      for (int m = 0; m < 4; ++m)
#pragma unroll
        for (int r = 0; r < 4; ++r) {
          float ss = 0.f;
#pragma unroll
          for (int n = 0; n < NF; ++n) ss += acc[m][n][r] * acc[m][n][r];
          ss += __shfl_xor(ss, 1);
          ss += __shfl_xor(ss, 2);
          ss += __shfl_xor(ss, 4);
          ss += __shfl_xor(ss, 8);
          float scale = 8.0f / fmaxf(sqrtf(ss), 1e-12f);   // sqrt(64)=8
          int row = tm + wm + m * 16 + g * 4 + r;
          int bb = row >> 11, nn = row & 2047;
          u16* drow = dst + (((size_t)(bb * H_ + h)) * N_ + nn) * 64;
#pragma unroll
          for (int n = 0; n < NF; ++n) {
            int d = n * 16 + li;
            drow[d] = f2bf(acc[m][n][r] * scale * gam[h * 64 + d]);
          }
        }
      return;
    }
    // V columns: bf16 into Cq (layout unchanged, consumed by k_vt)
#pragma unroll
    for (int m = 0; m < 4; ++m)
#pragma unroll
      for (int n = 0; n < NF; ++n) {
        int row = tm + wm + m * 16 + g * 4;
        int col = tn + wn + n * 16 + li;
#pragma unroll
        for (int r = 0; r < 4; ++r)
          ((u16*)Cv)[(size_t)(row + r) * Ncols + col] = f2bf(acc[m][n][r]);
      }
    return;
  }

#pragma unroll
  for (int m = 0; m < 4; ++m)
#pragma unroll
    for (int n = 0; n < NF; ++n) {
      int row = tm + wm + m * 16 + g * 4;
      int col = tn + wn + n * 16 + li;
#pragma unroll
      for (int r = 0; r < 4; ++r) {
        float v = acc[m][n][r];
        if (OUT_BF16) ((u16*)Cv)[(size_t)(row + r) * Ncols + col] = f2bf(v);
        else          ((float*)Cv)[(size_t)(row + r) * Ncols + col] = v;
      }
    }
}

// ------------- V relayout (identity cols): -> vT [b*h][d][n] ---------------
__global__ __launch_bounds__(256) void k_vt(const u16* __restrict__ Cq,
                                            u16* __restrict__ vT) {
  __shared__ float tile[64][65];
  int bh = blockIdx.y;
  int b = bh >> 4, h = bh & 15;
  int n0 = blockIdx.x * 64;
  int tx = threadIdx.x, ty = threadIdx.y;
  for (int i = 0; i < 64; i += 4) {
    int n = n0 + ty + i;
    tile[ty + i][tx] = bf2f(Cq[((size_t)(b * N_ + n)) * E3_ + 2048 + h * 64 + tx]);
  }
  __syncthreads();
  u16* dst = vT + (size_t)bh * 64 * N_;
  for (int i = 0; i < 64; i += 4) {
    int d = ty + i;
    dst[(size_t)d * N_ + n0 + tx] = f2bf(tile[tx][d]);
  }
}

// ------------- flash attention: fixed-offset softmax, offset in bias -------
// R19 structure (passing, 65us) with the -24 offset moved into the bias
// values written by k_pre (valid -> -24): the MFMA C-operand absorbs it,
// deleting 32 v_sub per wave-iter. P = exp(S + bias) with bias in
// {-24, -1e30}; range analysis as R19 (||q||=||k||=8 -> |S|<=64).
__global__ __launch_bounds__(256, 2) void k_attn(const u16* __restrict__ Q,
                                                 const u16* __restrict__ K,
                                                 const u16* __restrict__ Vt,
                                                 const float* __restrict__ bias,
                                                 u16* __restrict__ Out) {
  __shared__ u16 Ks[2][4096];           // 16 KB
  __shared__ u16 Vs[2][4096];           // 16 KB
  int wg = blockIdx.x;
  int xcd = wg & 7, slot = wg >> 3;     // slot 0..63
  int bh = xcd * 4 + (slot & 3);        // bijective: 8 xcd x 4 bh x 16 qchunk
  int qb = (slot >> 2) * 128;           // 16 chunks x 128 q = 2048
  int b = bh >> 4, h = bh & 15;
  int tid = threadIdx.x, wave = tid >> 6, lane = tid & 63;
  int g = lane >> 4, li = lane & 15;
  const u16* Qh = Q  + (size_t)bh * N_ * 64;
  const u16* Kh = K  + (size_t)bh * N_ * 64;
  const u16* Vh = Vt + (size_t)bh * 64 * N_;
  const float* bg = bias + b * N_;

  // staging addresses: 2 chunks of 16B per tile per thread (256 thr x 32B = 8KB)
  u32 Ls[2], kS[2], vR[2], vC[2];
#pragma unroll
  for (int s = 0; s < 2; ++s) {
    Ls[s] = tid * 16 + s * 4096;
    kS[s] = swzb(Ls[s]) >> 1;
    vR[s] = Ls[s] >> 7;
    vC[s] = (swzb(Ls[s]) & 127) >> 1;
  }

  int qr0 = qb + wave * 32 + li;        // q-subgroup A
  int qr1 = qr0 + 16;                   // q-subgroup B
  short8 aqA0 = ld8(Qh + (size_t)qr0 * 64 + g * 8);
  short8 aqA1 = ld8(Qh + (size_t)qr0 * 64 + 32 + g * 8);
  short8 aqB0 = ld8(Qh + (size_t)qr1 * 64 + g * 8);
  short8 aqB1 = ld8(Qh + (size_t)qr1 * 64 + 32 + g * 8);

  f32x4 oTA[4], oTB[4];
#pragma unroll
  for (int dc = 0; dc < 4; ++dc) {
    oTA[dc] = (f32x4){0.f, 0.f, 0.f, 0.f};
    oTB[dc] = (f32x4){0.f, 0.f, 0.f, 0.f};
  }
  float lA = 0.f, lB = 0.f;

  const int fsw  = 8 * (g ^ (li & 7));
  const int fsw2 = fsw ^ 32;
  const int vbl = li * 64 + (g & 1) * 4;
  int vsw[4];
#pragma unroll
  for (int c = 0; c < 4; ++c)
    vsw[c] = (((2 * c + (g >> 1)) ^ (li & 7)) << 3);

  // prologue: stage tile 0 into buffer 0
#pragma unroll
  for (int s = 0; s < 2; ++s) {
    lds16(Kh + kS[s], &Ks[0][0] + (Ls[s] >> 1));
    lds16(Vh + (size_t)vR[s] * N_ + vC[s], &Vs[0][0] + (Ls[s] >> 1));
  }
  __syncthreads();

  for (int kt = 0; kt < 32; ++kt) {
    int cur = kt & 1;
    int kbase = kt * 64;
    if (kt < 31) {                       // stage next tile (async, no regs)
      int nxt = cur ^ 1;
      int nb = kbase + 64;
#pragma unroll
      for (int s = 0; s < 2; ++s) {
        lds16(Kh + (size_t)nb * 64 + kS[s], &Ks[nxt][0] + (Ls[s] >> 1));
        lds16(Vh + (size_t)vR[s] * N_ + nb + vC[s], &Vs[nxt][0] + (Ls[s] >> 1));
      }
    }
    // bias (includes -24 offset) for current tile: 4x broadcast float4
    float4 bbc[4];
#pragma unroll
    for (int c = 0; c < 4; ++c)
      bbc[c] = *(const float4*)&bg[kbase + c * 16 + g * 4];
    const u16* Kb = &Ks[cur][0];
    const u16* Vb = &Vs[cur][0];
    // ---- S^T = mfma(K, Q, C=bias-24) for both q-groups ------------------
    f32x4 stA[4], stB[4];
    __builtin_amdgcn_s_setprio(1);
#pragma unroll
    for (int c = 0; c < 4; ++c) {
      int rb = (c * 16 + li) * 64;
      short8 kf0 = ld8(Kb + rb + fsw);
      short8 kf1 = ld8(Kb + rb + fsw2);
      f32x4 z = (f32x4){bbc[c].x, bbc[c].y, bbc[c].z, bbc[c].w};
      stA[c] = mfma16(kf1, aqA1, mfma16(kf0, aqA0, z));
      stB[c] = mfma16(kf1, aqB1, mfma16(kf0, aqB0, z));
    }
    __builtin_amdgcn_s_setprio(0);
    // ---- V-frags (b64 reads), shared by both q-groups -------------------
    short4v vf16[4][4];
#pragma unroll
    for (int dc = 0; dc < 4; ++dc)
#pragma unroll
      for (int c = 0; c < 4; ++c)
        vf16[dc][c] = *(const short4v*)(Vb + dc * 1024 + vbl + vsw[c]);
    // ---- softmax A: P = exp(S + bias), offset pre-folded ----------------
    float pvA[4][4], csA[4];
#pragma unroll
    for (int c = 0; c < 4; ++c) {
#pragma unroll
      for (int r = 0; r < 4; ++r) pvA[c][r] = __expf(stA[c][r]);
      csA[c] = (pvA[c][0] + pvA[c][1]) + (pvA[c][2] + pvA[c][3]);
    }
    float rsA = (csA[0] + csA[1]) + (csA[2] + csA[3]);
    rsA += __shfl_xor(rsA, 16);
    rsA += __shfl_xor(rsA, 32);
    lA += rsA;
    // ---- softmax B -------------------------------------------------------
    float pvB[4][4], csB[4];
#pragma unroll
    for (int c = 0; c < 4; ++c) {
#pragma unroll
      for (int r = 0; r < 4; ++r) pvB[c][r] = __expf(stB[c][r]);
      csB[c] = (pvB[c][0] + pvB[c][1]) + (pvB[c][2] + pvB[c][3]);
    }
    float rsB = (csB[0] + csB[1]) + (csB[2] + csB[3]);
    rsB += __shfl_xor(rsB, 16);
    rsB += __shfl_xor(rsB, 32);
    lB += rsB;
    // ---- pack P (both groups) via v_cvt_pk_bf16_f32 ----------------------
    union { u32 u2[2]; short4v s4; } pbA[4], pbB[4];
#pragma unroll
    for (int c = 0; c < 4; ++c) {
      asm("v_cvt_pk_bf16_f32 %0, %1, %2" : "=v"(pbA[c].u2[0]) : "v"(pvA[c][0]), "v"(pvA[c][1]));
      asm("v_cvt_pk_bf16_f32 %0, %1, %2" : "=v"(pbA[c].u2[1]) : "v"(pvA[c][2]), "v"(pvA[c][3]));
      asm("v_cvt_pk_bf16_f32 %0, %1, %2" : "=v"(pbB[c].u2[0]) : "v"(pvB[c][0]), "v"(pvB[c][1]));
      asm("v_cvt_pk_bf16_f32 %0, %1, %2" : "=v"(pbB[c].u2[1]) : "v"(pvB[c][2]), "v"(pvB[c][3]));
    }
    // ---- PV: V-frag (A operand) shared, B operand per q-group -----------
    __builtin_amdgcn_s_setprio(1);
#pragma unroll
    for (int dc = 0; dc < 4; ++dc)
#pragma unroll
      for (int c = 0; c < 4; ++c) {
        oTA[dc] = mfma16k16(vf16[dc][c], pbA[c].s4, oTA[dc]);
        oTB[dc] = mfma16k16(vf16[dc][c], pbB[c].s4, oTB[dc]);
      }
    __builtin_amdgcn_s_setprio(0);
    __syncthreads();                    // next-tile staging complete + buf free
  }

  float invA = 1.0f / lA, invB = 1.0f / lB;
#pragma unroll
  for (int dc = 0; dc < 4; ++dc) {
    ushort4 ovA, ovB;
    ovA.x = f2bf(oTA[dc][0] * invA); ovA.y = f2bf(oTA[dc][1] * invA);
    ovA.z = f2bf(oTA[dc][2] * invA); ovA.w = f2bf(oTA[dc][3] * invA);
    ovB.x = f2bf(oTB[dc][0] * invB); ovB.y = f2bf(oTB[dc][1] * invB);
    ovB.z = f2bf(oTB[dc][2] * invB); ovB.w = f2bf(oTB[dc][3] * invB);
    *(ushort4*)&Out[((size_t)(b * N_ + qr0)) * DIM_ + h * 64 + dc * 16 + g * 4] = ovA;
    *(ushort4*)&Out[((size_t)(b * N_ + qr1)) * DIM_ + h * 64 + dc * 16 + g * 4] = ovB;
  }
}

// ---------------------------------------------------------------------------
extern "C" void kernel_launch(void* const* d_in, const int* in_sizes, int n_in,
                              void* d_out, int out_size, void* d_ws, size_t ws_size,
                              hipStream_t stream) {
  const float* x    = (const float*)d_in[0];
  const int*   mask = (const int*)d_in[1];
  const float* g_ln = (const float*)d_in[2];
  const float* g_q  = (const float*)d_in[3];
  const float* g_k  = (const float*)d_in[4];
  const float* Wq   = (const float*)d_in[5];
  const float* Wkv  = (const float*)d_in[6];
  const float* Wo   = (const float*)d_in[7];
  float* out = (float*)d_out;

  char* ws = (char*)d_ws;
  u16*   xn   = (u16*)(ws);                         // 8 MB
  u16*   Wt   = (u16*)(ws + 8388608);               // 6 MB  (Wq^T | Wkv^T) [3072][1024]
  u16*   Wot  = (u16*)(ws + 14680064);              // 2 MB  Wo^T [1024][1024]
  float* bias = (float*)(ws + 16777216);            // 16 KB
  u16*   Cq   = (u16*)(ws + 16793600);              // 24 MB [4096][3072] (V third used)
  u16*   qb   = (u16*)(ws + 41959424);              // 8 MB [b,h,n,d]
  u16*   kb   = (u16*)(ws + 41959424 + 8388608);    // 8 MB
  u16*   vT   = (u16*)(ws + 41959424 + 2*8388608);  // 8 MB [b*h][d][n]
  u16*   ao   = (u16*)(ws + 41959424 + 3*8388608);  // 8 MB [4096][1024]

  k_pre<<<8208, 256, 0, stream>>>(x, g_ln, Wq, Wkv, Wo, mask, xn, Wt, Wot, bias);
  k_gemm_bt<4, true, true><<<dim3(32, 24), 256, 0, stream>>>(
      xn, Wt, Cq, g_q, g_k, qb, kb, ROWS_, E3_, DIM_);
  k_vt<<<dim3(32, 32), dim3(64, 4), 0, stream>>>(Cq, vT);
  k_attn<<<512, 256, 0, stream>>>(qb, kb, vT, bias, ao);
  k_gemm_bt<2, false, false><<<dim3(32, 16), 256, 0, stream>>>(
      ao, Wot, out, nullptr, nullptr, nullptr, nullptr, ROWS_, DIM_, DIM_);
}